// Round 17
// baseline (273.442 us; speedup 1.0000x reference)
//
#include <hip/hip_runtime.h>
#include <math.h>

#define D_MODEL 1024
#define N_HEADS 16
#define D_HEAD  64
#define LSR_RANK 32
#define BATCH 2
#define SEQ 2048
#define M_TOT (BATCH*SEQ)

typedef __attribute__((ext_vector_type(8))) short short8v;
typedef __attribute__((ext_vector_type(4))) short short4v;
typedef __attribute__((ext_vector_type(4))) float f32x4;

static __device__ __forceinline__ ushort bfhi(float f) {
    union { float f; unsigned u; } c; c.f = f;
    return (ushort)(c.u >> 16);
}
static __device__ __forceinline__ float bff(ushort h) {
    union { unsigned u; float f; } c; c.u = ((unsigned)h) << 16;
    return c.f;
}
static __device__ __forceinline__ ushort f2bf_rn(float f) {
    union { float f; unsigned u; } c; c.f = f;
    unsigned r = c.u + 0x7FFF + ((c.u >> 16) & 1);
    return (ushort)(r >> 16);
}
static __device__ __forceinline__ void split8(const float4 a, const float4 b,
                                              short8v& h, short8v& l) {
    ushort h0 = bfhi(a.x), h1 = bfhi(a.y), h2 = bfhi(a.z), h3 = bfhi(a.w);
    ushort h4 = bfhi(b.x), h5 = bfhi(b.y), h6 = bfhi(b.z), h7 = bfhi(b.w);
    h[0] = (short)h0; h[1] = (short)h1; h[2] = (short)h2; h[3] = (short)h3;
    h[4] = (short)h4; h[5] = (short)h5; h[6] = (short)h6; h[7] = (short)h7;
    l[0] = (short)bfhi(a.x - bff(h0)); l[1] = (short)bfhi(a.y - bff(h1));
    l[2] = (short)bfhi(a.z - bff(h2)); l[3] = (short)bfhi(a.w - bff(h3));
    l[4] = (short)bfhi(b.x - bff(h4)); l[5] = (short)bfhi(b.y - bff(h5));
    l[6] = (short)bfhi(b.z - bff(h6)); l[7] = (short)bfhi(b.w - bff(h7));
}

// ---------------------------------------------------------------------------
// Weff_tmp[k][base+c] = sum_d W[k, h*64+d] * Wlsr[h, d, r]
// ---------------------------------------------------------------------------
__global__ __launch_bounds__(256) void eff_weight_kernel(
    const float* __restrict__ W, const float* __restrict__ Wlsr,
    float* __restrict__ Weff_tmp, int base)
{
    int idx = blockIdx.x * 256 + threadIdx.x;
    int k = idx >> 9;
    int c = idx & 511;
    int h = c >> 5;
    int r = c & 31;
    const float* wrow = W + (size_t)k * D_MODEL + h * D_HEAD;
    const float* lsr  = Wlsr + (size_t)h * D_HEAD * LSR_RANK + r;
    float acc = 0.f;
    #pragma unroll
    for (int d = 0; d < D_HEAD; ++d)
        acc = fmaf(wrow[d], lsr[d * LSR_RANK], acc);
    Weff_tmp[(size_t)k * 1024 + base + c] = acc;
}

__global__ __launch_bounds__(256) void eff_bias_kernel(
    const float* __restrict__ bq, const float* __restrict__ Wq_lsr,
    const float* __restrict__ bk, const float* __restrict__ Wk_lsr,
    const float* __restrict__ bv, float* __restrict__ bcat)
{
    int c = blockIdx.x * 256 + threadIdx.x;
    if (c < 1024) {
        const float* bias = (c < 512) ? bq : bk;
        const float* lsr  = (c < 512) ? Wq_lsr : Wk_lsr;
        int cc = c & 511;
        int h = cc >> 5, r = cc & 31;
        float acc = 0.f;
        #pragma unroll
        for (int d = 0; d < D_HEAD; ++d)
            acc = fmaf(bias[h * D_HEAD + d],
                       lsr[(size_t)h * D_HEAD * LSR_RANK + d * LSR_RANK + r], acc);
        bcat[c] = acc;
    } else {
        bcat[c] = bv[c - 1024];
    }
}

// ---------------------------------------------------------------------------
// 1024x1024 fp32 transpose (kept for Wo path)
// ---------------------------------------------------------------------------
__global__ __launch_bounds__(256) void transpose1024(
    const float* __restrict__ in, float* __restrict__ out)
{
    __shared__ float t[64][65];
    const int tid = threadIdx.x;
    const int r0 = blockIdx.y * 64, c0 = blockIdx.x * 64;
    const int tr = tid >> 4, tc = tid & 15;
    #pragma unroll
    for (int i = 0; i < 4; ++i) {
        float4 v = *(const float4*)&in[(size_t)(r0 + tr + i * 16) * 1024 + c0 + tc * 4];
        t[tr + i * 16][tc * 4 + 0] = v.x;
        t[tr + i * 16][tc * 4 + 1] = v.y;
        t[tr + i * 16][tc * 4 + 2] = v.z;
        t[tr + i * 16][tc * 4 + 3] = v.w;
    }
    __syncthreads();
    #pragma unroll
    for (int i = 0; i < 4; ++i) {
        float4 v;
        v.x = t[tc * 4 + 0][tr + i * 16];
        v.y = t[tc * 4 + 1][tr + i * 16];
        v.z = t[tc * 4 + 2][tr + i * 16];
        v.w = t[tc * 4 + 3][tr + i * 16];
        *(float4*)&out[(size_t)(c0 + tr + i * 16) * 1024 + r0 + tc * 4] = v;
    }
}

// ---------------------------------------------------------------------------
// Transpose + bf16 hi/lo split in ONE pass: in[1024][1024] fp32 ->
// oh/ol[1024][1024] bf16 (transposed). Replaces transpose1024+in-gemm split.
// ---------------------------------------------------------------------------
__global__ __launch_bounds__(256) void tsplit1024(
    const float* __restrict__ in, short* __restrict__ oh, short* __restrict__ ol)
{
    __shared__ float t[64][65];
    const int tid = threadIdx.x;
    const int r0 = blockIdx.y * 64, c0 = blockIdx.x * 64;
    const int tr = tid >> 4, tc = tid & 15;
    #pragma unroll
    for (int i = 0; i < 4; ++i) {
        float4 v = *(const float4*)&in[(size_t)(r0 + tr + i * 16) * 1024 + c0 + tc * 4];
        t[tr + i * 16][tc * 4 + 0] = v.x;
        t[tr + i * 16][tc * 4 + 1] = v.y;
        t[tr + i * 16][tc * 4 + 2] = v.z;
        t[tr + i * 16][tc * 4 + 3] = v.w;
    }
    __syncthreads();
    #pragma unroll
    for (int i = 0; i < 4; ++i) {
        float v0 = t[tc * 4 + 0][tr + i * 16];
        float v1 = t[tc * 4 + 1][tr + i * 16];
        float v2 = t[tc * 4 + 2][tr + i * 16];
        float v3 = t[tc * 4 + 3][tr + i * 16];
        ushort h0 = bfhi(v0), h1 = bfhi(v1), h2 = bfhi(v2), h3 = bfhi(v3);
        short4v hv = {(short)h0, (short)h1, (short)h2, (short)h3};
        short4v lv = {(short)bfhi(v0 - bff(h0)), (short)bfhi(v1 - bff(h1)),
                      (short)bfhi(v2 - bff(h2)), (short)bfhi(v3 - bff(h3))};
        const size_t o = (size_t)(c0 + tr + i * 16) * 1024 + r0 + tc * 4;
        *(short4v*)&oh[o] = hv;
        *(short4v*)&ol[o] = lv;
    }
}

// ---------------------------------------------------------------------------
// x -> Xh/Xl bf16 hi/lo (elementwise, 8 floats/thread)
// ---------------------------------------------------------------------------
__global__ __launch_bounds__(256) void xsplit(
    const float* __restrict__ x, short* __restrict__ Xh, short* __restrict__ Xl)
{
    const size_t idx = ((size_t)blockIdx.x * 256 + threadIdx.x) * 8;
    float4 a = *(const float4*)(x + idx);
    float4 b = *(const float4*)(x + idx + 4);
    short8v h, l;
    split8(a, b, h, l);
    *(short8v*)(Xh + idx) = h;
    *(short8v*)(Xl + idx) = l;
}

// ---------------------------------------------------------------------------
// Pre-split proj GEMM: C = X @ Wt^T + bias. Operands already bf16 hi/lo ->
// staging is pure short8 copies (half the bytes, zero split VALU).
// n0 < 1024 (QK half): 3-term split-bf16 -> Yqk.
// n0 >= 1024 (V half): 1-term plain bf16 -> Vtmp (V is re-rounded to bf16
// downstream anyway; error ~0.005 << 0.096 tolerance).
// ---------------------------------------------------------------------------
__global__ __launch_bounds__(256) void gemm_pre(
    const short* __restrict__ Xh, const short* __restrict__ Xl,   // [4096][1024]
    const short* __restrict__ Wth, const short* __restrict__ Wtl, // [2048][1024]
    const float* __restrict__ bcat,
    float* __restrict__ Yqk, float* __restrict__ Vtmp)            // [4096][1024]
{
    __shared__ __align__(16) short Ah[128 * 40], Al[128 * 40];
    __shared__ __align__(16) short Bh[128 * 40], Bl[128 * 40];

    const int tid = threadIdx.x;
    const int m0 = blockIdx.y * 128, n0 = blockIdx.x * 128;
    const bool vhalf = (n0 >= 1024);
    const int wid = tid >> 6, wr = wid >> 1, wc = wid & 1;
    const int lane = tid & 63, fr = lane & 15, fq = lane >> 4;
    const int srow = tid >> 1;
    const int skq  = (tid & 1) << 4;

    f32x4 acc[4][4];
    #pragma unroll
    for (int i = 0; i < 4; ++i)
        #pragma unroll
        for (int j = 0; j < 4; ++j)
            acc[i][j] = (f32x4){0.f, 0.f, 0.f, 0.f};

    const short* AgH = Xh + (size_t)(m0 + srow) * 1024 + skq;
    const short* AgL = Xl + (size_t)(m0 + srow) * 1024 + skq;
    const short* BgH = Wth + (size_t)(n0 + srow) * 1024 + skq;
    const short* BgL = Wtl + (size_t)(n0 + srow) * 1024 + skq;
    short* pAh = &Ah[srow * 40 + skq];
    short* pAl = &Al[srow * 40 + skq];
    short* pBh = &Bh[srow * 40 + skq];
    short* pBl = &Bl[srow * 40 + skq];

    for (int k0 = 0; k0 < 1024; k0 += 32) {
        *(short8v*)pAh       = *(const short8v*)(AgH + k0);
        *(short8v*)(pAh + 8) = *(const short8v*)(AgH + k0 + 8);
        *(short8v*)pBh       = *(const short8v*)(BgH + k0);
        *(short8v*)(pBh + 8) = *(const short8v*)(BgH + k0 + 8);
        if (!vhalf) {
            *(short8v*)pAl       = *(const short8v*)(AgL + k0);
            *(short8v*)(pAl + 8) = *(const short8v*)(AgL + k0 + 8);
            *(short8v*)pBl       = *(const short8v*)(BgL + k0);
            *(short8v*)(pBl + 8) = *(const short8v*)(BgL + k0 + 8);
        }
        __syncthreads();

        short8v afh[4], bfh[4];
        #pragma unroll
        for (int fi = 0; fi < 4; ++fi)
            afh[fi] = *(const short8v*)&Ah[(wr * 64 + fi * 16 + fr) * 40 + fq * 8];
        #pragma unroll
        for (int bj = 0; bj < 4; ++bj)
            bfh[bj] = *(const short8v*)&Bh[(wc * 64 + bj * 16 + fr) * 40 + fq * 8];

        if (vhalf) {
            #pragma unroll
            for (int fi = 0; fi < 4; ++fi)
                #pragma unroll
                for (int bj = 0; bj < 4; ++bj)
                    acc[fi][bj] = __builtin_amdgcn_mfma_f32_16x16x32_bf16(
                        afh[fi], bfh[bj], acc[fi][bj], 0, 0, 0);
        } else {
            short8v afl[4], bfl[4];
            #pragma unroll
            for (int fi = 0; fi < 4; ++fi)
                afl[fi] = *(const short8v*)&Al[(wr * 64 + fi * 16 + fr) * 40 + fq * 8];
            #pragma unroll
            for (int bj = 0; bj < 4; ++bj)
                bfl[bj] = *(const short8v*)&Bl[(wc * 64 + bj * 16 + fr) * 40 + fq * 8];
            #pragma unroll
            for (int fi = 0; fi < 4; ++fi) {
                #pragma unroll
                for (int bj = 0; bj < 4; ++bj) {
                    acc[fi][bj] = __builtin_amdgcn_mfma_f32_16x16x32_bf16(
                        afh[fi], bfh[bj], acc[fi][bj], 0, 0, 0);
                    acc[fi][bj] = __builtin_amdgcn_mfma_f32_16x16x32_bf16(
                        afh[fi], bfl[bj], acc[fi][bj], 0, 0, 0);
                    acc[fi][bj] = __builtin_amdgcn_mfma_f32_16x16x32_bf16(
                        afl[fi], bfh[bj], acc[fi][bj], 0, 0, 0);
                }
            }
        }
        __syncthreads();
    }

    float* Cw = vhalf ? Vtmp : Yqk;
    #pragma unroll
    for (int fi = 0; fi < 4; ++fi) {
        #pragma unroll
        for (int bj = 0; bj < 4; ++bj) {
            const int r = m0 + wr * 64 + fi * 16 + fq * 4;
            const int gcol = n0 + wc * 64 + bj * 16 + fr;
            const int c = vhalf ? (gcol - 1024) : gcol;
            const float bv_ = bcat[gcol];
            #pragma unroll
            for (int j = 0; j < 4; ++j)
                Cw[(size_t)(r + j) * 1024 + c] = acc[fi][bj][j] + bv_;
        }
    }
}

// ---------------------------------------------------------------------------
// Split-bf16 MFMA GEMM (r9-validated) — kept for out-projection.
// ---------------------------------------------------------------------------
__global__ __launch_bounds__(256) void gemm_bt_split(
    const float* __restrict__ A,
    const float* __restrict__ Bt,
    const float* __restrict__ bias,
    float* __restrict__ C)
{
    __shared__ __align__(16) short Ah[128 * 40], Al[128 * 40];
    __shared__ __align__(16) short Bh[128 * 40], Bl[128 * 40];

    const int tid = threadIdx.x;
    const int m0 = blockIdx.y * 128, n0 = blockIdx.x * 128;
    const int wid = tid >> 6, wr = wid >> 1, wc = wid & 1;
    const int lane = tid & 63, fr = lane & 15, fq = lane >> 4;
    const int srow = tid >> 1;
    const int skq  = (tid & 1) << 4;

    f32x4 acc[4][4];
    #pragma unroll
    for (int i = 0; i < 4; ++i)
        #pragma unroll
        for (int j = 0; j < 4; ++j)
            acc[i][j] = (f32x4){0.f, 0.f, 0.f, 0.f};

    const float* Ag = A + (size_t)(m0 + srow) * 1024 + skq;
    const float* Bg = Bt + (size_t)(n0 + srow) * 1024 + skq;
    short* pAh = &Ah[srow * 40 + skq];
    short* pAl = &Al[srow * 40 + skq];
    short* pBh = &Bh[srow * 40 + skq];
    short* pBl = &Bl[srow * 40 + skq];

    for (int k0 = 0; k0 < 1024; k0 += 32) {
        float4 a0 = *(const float4*)(Ag + k0);
        float4 a1 = *(const float4*)(Ag + k0 + 4);
        float4 a2 = *(const float4*)(Ag + k0 + 8);
        float4 a3 = *(const float4*)(Ag + k0 + 12);
        float4 b0 = *(const float4*)(Bg + k0);
        float4 b1 = *(const float4*)(Bg + k0 + 4);
        float4 b2 = *(const float4*)(Bg + k0 + 8);
        float4 b3 = *(const float4*)(Bg + k0 + 12);
        short8v h, l;
        split8(a0, a1, h, l);
        *(short8v*)pAh = h;  *(short8v*)pAl = l;
        split8(a2, a3, h, l);
        *(short8v*)(pAh + 8) = h;  *(short8v*)(pAl + 8) = l;
        split8(b0, b1, h, l);
        *(short8v*)pBh = h;  *(short8v*)pBl = l;
        split8(b2, b3, h, l);
        *(short8v*)(pBh + 8) = h;  *(short8v*)(pBl + 8) = l;
        __syncthreads();

        short8v afh[4], afl[4], bfh[4], bfl[4];
        #pragma unroll
        for (int fi = 0; fi < 4; ++fi) {
            const int ar = wr * 64 + fi * 16 + fr;
            afh[fi] = *(const short8v*)&Ah[ar * 40 + fq * 8];
            afl[fi] = *(const short8v*)&Al[ar * 40 + fq * 8];
        }
        #pragma unroll
        for (int bj = 0; bj < 4; ++bj) {
            const int br = wc * 64 + bj * 16 + fr;
            bfh[bj] = *(const short8v*)&Bh[br * 40 + fq * 8];
            bfl[bj] = *(const short8v*)&Bl[br * 40 + fq * 8];
        }
        #pragma unroll
        for (int fi = 0; fi < 4; ++fi) {
            #pragma unroll
            for (int bj = 0; bj < 4; ++bj) {
                acc[fi][bj] = __builtin_amdgcn_mfma_f32_16x16x32_bf16(
                    afh[fi], bfh[bj], acc[fi][bj], 0, 0, 0);
                acc[fi][bj] = __builtin_amdgcn_mfma_f32_16x16x32_bf16(
                    afh[fi], bfl[bj], acc[fi][bj], 0, 0, 0);
                acc[fi][bj] = __builtin_amdgcn_mfma_f32_16x16x32_bf16(
                    afl[fi], bfh[bj], acc[fi][bj], 0, 0, 0);
            }
        }
        __syncthreads();
    }

    #pragma unroll
    for (int fi = 0; fi < 4; ++fi) {
        #pragma unroll
        for (int bj = 0; bj < 4; ++bj) {
            const int r = m0 + wr * 64 + fi * 16 + fq * 4;
            const int c = n0 + wc * 64 + bj * 16 + fr;
            const float bv_ = bias[c];
            #pragma unroll
            for (int j = 0; j < 4; ++j)
                C[(size_t)(r + j) * 1024 + c] = acc[fi][bj][j] + bv_;
        }
    }
}

// ---------------------------------------------------------------------------
// K pre-split into B-frag-ready layout: Kth/Ktl [bh][2048 t][32 r] bf16.
// ---------------------------------------------------------------------------
__global__ __launch_bounds__(256) void kt_prep(
    const float* __restrict__ Yqk,
    short* __restrict__ Kth, short* __restrict__ Ktl)
{
    const int bh = blockIdx.x;
    const int b = bh >> 4, h = bh & 15;
    const int t0 = blockIdx.y * 128;
    const int tid = threadIdx.x;
    const int tl = tid >> 1, half = tid & 1;
    const float* src = Yqk + (size_t)(b * SEQ + t0 + tl) * 1024 + 512 + h * 32 + half * 16;
    short8v h0, l0, h1, l1;
    split8(((const float4*)src)[0], ((const float4*)src)[1], h0, l0);
    split8(((const float4*)src)[2], ((const float4*)src)[3], h1, l1);
    short* oh = Kth + ((size_t)bh * 2048 + t0 + tl) * 32 + half * 16;
    short* ol = Ktl + ((size_t)bh * 2048 + t0 + tl) * 32 + half * 16;
    *(short8v*)oh = h0;  *(short8v*)(oh + 8) = h1;
    *(short8v*)ol = l0;  *(short8v*)(ol + 8) = l1;
}

// ---------------------------------------------------------------------------
// V transpose + bf16-rn: Vtmp[4096][1024] -> Vbf [bh][64 d][2048 t]
// ---------------------------------------------------------------------------
__global__ __launch_bounds__(256) void vt_prep(
    const float* __restrict__ Vtmp, short* __restrict__ Vbf)
{
    __shared__ float t[64][68];
    const int bh = blockIdx.x;
    const int b = bh >> 4, h = bh & 15;
    const int t0 = blockIdx.y * 64;
    const int tid = threadIdx.x;
    {
        const int tl = tid >> 2, sg = tid & 3;
        const float* vp = Vtmp + (size_t)(b * SEQ + t0 + tl) * 1024 + h * 64 + sg * 16;
        #pragma unroll
        for (int i = 0; i < 4; ++i)
            *(float4*)&t[tl][sg * 16 + i * 4] = *(const float4*)(vp + i * 4);
    }
    __syncthreads();
    {
        const int d = tid >> 2, sg = tid & 3;
        short8v h0, h1;
        #pragma unroll
        for (int i = 0; i < 8; ++i) {
            h0[i] = (short)f2bf_rn(t[sg * 16 + i][d]);
            h1[i] = (short)f2bf_rn(t[sg * 16 + 8 + i][d]);
        }
        short* oh = Vbf + ((size_t)bh * 64 + d) * 2048 + t0 + sg * 16;
        *(short8v*)oh = h0;  *(short8v*)(oh + 8) = h1;
    }
}

// ---------------------------------------------------------------------------
// MFMA flash attention v7 (r16-measured, 110 us) — UNCHANGED.
// ---------------------------------------------------------------------------
#define P_LD  68
#define MASKVAL (-1e30f)

__global__ __launch_bounds__(512) void flash_mfma(
    const float* __restrict__ Yqk,
    const short* __restrict__ Kth, const short* __restrict__ Ktl,
    const short* __restrict__ Vbf,
    float* __restrict__ O)
{
    const float scale = 0.1767766952966369f;  // 1/sqrt(32)
    const int L = blockIdx.x;
    const int bh = L & 31;
    const int qt = 31 - (L >> 5);
    const int b = bh >> 4, h = bh & 15;
    const int tid = threadIdx.x;
    const int w = tid >> 6;
    const int g = w & 3;
    const int p = w >> 2;
    const int lane = tid & 63;
    const int fr = lane & 15, fq = lane >> 4;

    __shared__ __align__(16) short Pall[8][16 * P_LD];
    __shared__ __align__(16) float ex[4 * 64 * 28];
    short* Pw = &Pall[w][0];

    short8v aqh, aql;
    {
        const float* qp = Yqk + (size_t)(b * SEQ + qt * 64 + g * 16 + fr) * 1024
                          + h * 32 + fq * 8;
        split8(*(const float4*)qp, *(const float4*)(qp + 4), aqh, aql);
    }

    f32x4 acc0 = {0,0,0,0}, acc1 = {0,0,0,0}, acc2 = {0,0,0,0}, acc3 = {0,0,0,0};
    float m_[4], l_[4];
    #pragma unroll
    for (int r = 0; r < 4; ++r) { m_[r] = MASKVAL; l_[r] = 0.f; }

    const short* kb_h = Kth + (size_t)bh * 2048 * 32;
    const short* kb_l = Ktl + (size_t)bh * 2048 * 32;
    const short* vb   = Vbf + (size_t)bh * 64 * 2048;
    const int kidx = fr * 32 + fq * 8;
    const int vrow = fr * 2048 + fq * 8;

    for (int jt = p; jt <= qt; jt += 2) {
        const short* kp_h = kb_h + (size_t)jt * 64 * 32;
        const short* kp_l = kb_l + (size_t)jt * 64 * 32;
        short8v kh0 = *(const short8v*)&kp_h[kidx];
        short8v kh1 = *(const short8v*)&kp_h[kidx + 512];
        short8v kh2 = *(const short8v*)&kp_h[kidx + 1024];
        short8v kh3 = *(const short8v*)&kp_h[kidx + 1536];
        short8v kl0 = *(const short8v*)&kp_l[kidx];
        short8v kl1 = *(const short8v*)&kp_l[kidx + 512];
        short8v kl2 = *(const short8v*)&kp_l[kidx + 1024];
        short8v kl3 = *(const short8v*)&kp_l[kidx + 1536];
        const short* vp = vb + vrow + jt * 64;
        short8v v00 = *(const short8v*)&vp[0];
        short8v v01 = *(const short8v*)&vp[32];
        short8v v10 = *(const short8v*)&vp[16 * 2048];
        short8v v11 = *(const short8v*)&vp[16 * 2048 + 32];
        short8v v20 = *(const short8v*)&vp[32 * 2048];
        short8v v21 = *(const short8v*)&vp[32 * 2048 + 32];
        short8v v30 = *(const short8v*)&vp[48 * 2048];
        short8v v31 = *(const short8v*)&vp[48 * 2048 + 32];

        f32x4 s0 = {0,0,0,0}, s1 = {0,0,0,0}, s2 = {0,0,0,0}, s3 = {0,0,0,0};
        s0 = __builtin_amdgcn_mfma_f32_16x16x32_bf16(aqh, kh0, s0, 0, 0, 0);
        s0 = __builtin_amdgcn_mfma_f32_16x16x32_bf16(aqh, kl0, s0, 0, 0, 0);
        s0 = __builtin_amdgcn_mfma_f32_16x16x32_bf16(aql, kh0, s0, 0, 0, 0);
        s1 = __builtin_amdgcn_mfma_f32_16x16x32_bf16(aqh, kh1, s1, 0, 0, 0);
        s1 = __builtin_amdgcn_mfma_f32_16x16x32_bf16(aqh, kl1, s1, 0, 0, 0);
        s1 = __builtin_amdgcn_mfma_f32_16x16x32_bf16(aql, kh1, s1, 0, 0, 0);
        s2 = __builtin_amdgcn_mfma_f32_16x16x32_bf16(aqh, kh2, s2, 0, 0, 0);
        s2 = __builtin_amdgcn_mfma_f32_16x16x32_bf16(aqh, kl2, s2, 0, 0, 0);
        s2 = __builtin_amdgcn_mfma_f32_16x16x32_bf16(aql, kh2, s2, 0, 0, 0);
        s3 = __builtin_amdgcn_mfma_f32_16x16x32_bf16(aqh, kh3, s3, 0, 0, 0);
        s3 = __builtin_amdgcn_mfma_f32_16x16x32_bf16(aqh, kl3, s3, 0, 0, 0);
        s3 = __builtin_amdgcn_mfma_f32_16x16x32_bf16(aql, kh3, s3, 0, 0, 0);

        s0 *= scale; s1 *= scale; s2 *= scale; s3 *= scale;

        if (jt == qt) {
            #pragma unroll
            for (int r = 0; r < 4; ++r) {
                const int q_l = g * 16 + fq * 4 + r;
                s0[r] = (fr      <= q_l) ? s0[r] : MASKVAL;
                s1[r] = (16 + fr <= q_l) ? s1[r] : MASKVAL;
                s2[r] = (32 + fr <= q_l) ? s2[r] : MASKVAL;
                s3[r] = (48 + fr <= q_l) ? s3[r] : MASKVAL;
            }
        }

        float al[4];
        #pragma unroll
        for (int r = 0; r < 4; ++r) {
            float mt = fmaxf(fmaxf(s0[r], s1[r]), fmaxf(s2[r], s3[r]));
            mt = fmaxf(mt, __shfl_xor(mt, 1));
            mt = fmaxf(mt, __shfl_xor(mt, 2));
            mt = fmaxf(mt, __shfl_xor(mt, 4));
            mt = fmaxf(mt, __shfl_xor(mt, 8));
            const float mnew = fmaxf(m_[r], mt);
            al[r] = __expf(m_[r] - mnew);
            m_[r] = mnew;
            s0[r] = __expf(s0[r] - mnew);
            s1[r] = __expf(s1[r] - mnew);
            s2[r] = __expf(s2[r] - mnew);
            s3[r] = __expf(s3[r] - mnew);
            float ps = s0[r] + s1[r] + s2[r] + s3[r];
            ps += __shfl_xor(ps, 1);
            ps += __shfl_xor(ps, 2);
            ps += __shfl_xor(ps, 4);
            ps += __shfl_xor(ps, 8);
            l_[r] = l_[r] * al[r] + ps;
        }

        #pragma unroll
        for (int r = 0; r < 4; ++r) {
            const int prow = fq * 4 + r;
            Pw[prow * P_LD +      fr] = (short)f2bf_rn(s0[r]);
            Pw[prow * P_LD + 16 + fr] = (short)f2bf_rn(s1[r]);
            Pw[prow * P_LD + 32 + fr] = (short)f2bf_rn(s2[r]);
            Pw[prow * P_LD + 48 + fr] = (short)f2bf_rn(s3[r]);
        }
        #pragma unroll
        for (int r = 0; r < 4; ++r) {
            acc0[r] *= al[r]; acc1[r] *= al[r];
            acc2[r] *= al[r]; acc3[r] *= al[r];
        }
        short8v pa0 = *(const short8v*)&Pw[fr * P_LD + fq * 8];
        short8v pa1 = *(const short8v*)&Pw[fr * P_LD + 32 + fq * 8];

        acc0 = __builtin_amdgcn_mfma_f32_16x16x32_bf16(pa0, v00, acc0, 0, 0, 0);
        acc0 = __builtin_amdgcn_mfma_f32_16x16x32_bf16(pa1, v01, acc0, 0, 0, 0);
        acc1 = __builtin_amdgcn_mfma_f32_16x16x32_bf16(pa0, v10, acc1, 0, 0, 0);
        acc1 = __builtin_amdgcn_mfma_f32_16x16x32_bf16(pa1, v11, acc1, 0, 0, 0);
        acc2 = __builtin_amdgcn_mfma_f32_16x16x32_bf16(pa0, v20, acc2, 0, 0, 0);
        acc2 = __builtin_amdgcn_mfma_f32_16x16x32_bf16(pa1, v21, acc2, 0, 0, 0);
        acc3 = __builtin_amdgcn_mfma_f32_16x16x32_bf16(pa0, v30, acc3, 0, 0, 0);
        acc3 = __builtin_amdgcn_mfma_f32_16x16x32_bf16(pa1, v31, acc3, 0, 0, 0);
    }

    if (p == 1) {
        float* e = ex + ((g << 6) + lane) * 28;
        *(f32x4*)(e +  0) = acc0;
        *(f32x4*)(e +  4) = acc1;
        *(f32x4*)(e +  8) = acc2;
        *(f32x4*)(e + 12) = acc3;
        *(f32x4*)(e + 16) = (f32x4){m_[0], m_[1], m_[2], m_[3]};
        *(f32x4*)(e + 20) = (f32x4){l_[0], l_[1], l_[2], l_[3]};
    }
    __syncthreads();
    if (p == 0) {
        const float* e = ex + ((g << 6) + lane) * 28;
        f32x4 b0 = *(const f32x4*)(e +  0);
        f32x4 b1 = *(const f32x4*)(e +  4);
        f32x4 b2 = *(const f32x4*)(e +  8);
        f32x4 b3 = *(const f32x4*)(e + 12);
        f32x4 m1 = *(const f32x4*)(e + 16);
        f32x4 l1 = *(const f32x4*)(e + 20);
        #pragma unroll
        for (int r = 0; r < 4; ++r) {
            const float mm = fmaxf(m_[r], m1[r]);
            const float a0 = __expf(m_[r] - mm);
            const float a1 = __expf(m1[r] - mm);
            const float inv = 1.f / (l_[r] * a0 + l1[r] * a1);
            const int trow = qt * 64 + g * 16 + fq * 4 + r;
            float* op = O + (size_t)(b * SEQ + trow) * 1024 + h * 64;
            op[     fr] = (acc0[r] * a0 + b0[r] * a1) * inv;
            op[16 + fr] = (acc1[r] * a0 + b1[r] * a1) * inv;
            op[32 + fr] = (acc2[r] * a0 + b2[r] * a1) * inv;
            op[48 + fr] = (acc3[r] * a0 + b3[r] * a1) * inv;
        }
    }
}

// ---------------------------------------------------------------------------
extern "C" void kernel_launch(void* const* d_in, const int* in_sizes, int n_in,
                              void* d_out, int out_size, void* d_ws, size_t ws_size,
                              hipStream_t stream)
{
    const float* x      = (const float*)d_in[0];
    const float* Wq     = (const float*)d_in[1];
    const float* bq     = (const float*)d_in[2];
    const float* Wk     = (const float*)d_in[3];
    const float* bk     = (const float*)d_in[4];
    const float* Wv     = (const float*)d_in[5];
    const float* bv     = (const float*)d_in[6];
    const float* Wo     = (const float*)d_in[7];
    const float* bo     = (const float*)d_in[8];
    const float* Wq_lsr = (const float*)d_in[9];
    const float* Wk_lsr = (const float*)d_in[10];
    float* out = (float*)d_out;

    // workspace (~56 MB), region plan:
    //  A: Wth/Wtl [2048][1024] shorts (8 MB) -> Wo_t (fp32, 4 MB) after proj
    //  B: Xh/Xl [4096][1024] shorts (16 MB)  -> Vbf(8) | Kth(4) | Ktl(4) after proj
    //  bcat (8 KB), Yqk (16 MB), Vtmp (16 MB; also Weff_tmp pre-proj, Oacc post-vt)
    float* ws    = (float*)d_ws;
    short* Wth   = (short*)ws;                              // 2M shorts
    short* Wtl   = Wth + (size_t)2048 * 1024;               // 2M shorts
    float* bcat  = ws + (size_t)2 * 1024 * 1024;            // after A (2M floats)
    short* Xh    = (short*)(bcat + 2048);                   // 4M shorts
    short* Xl    = Xh + (size_t)M_TOT * 1024;               // 4M shorts
    float* Yqk   = (float*)(Xl + (size_t)M_TOT * 1024);     // 4M floats
    float* Vtmp  = Yqk + (size_t)M_TOT * 1024;              // 4M floats
    float* Weff_tmp = Vtmp;          // alias: dead before gemm_pre writes Vtmp
    float* Oacc  = Vtmp;             // alias: fp32 V dead after vt_prep
    short* Vbf   = Xh;               // alias: Xh/Xl dead after gemm_pre
    short* Kth   = Xl;               // 2M shorts
    short* Ktl   = Kth + (size_t)32 * 2048 * 32;            // 2M shorts
    float* Wo_t  = (float*)Wth;      // alias: Wth/Wtl dead after gemm_pre

    eff_weight_kernel<<<2048, 256, 0, stream>>>(Wq, Wq_lsr, Weff_tmp, 0);
    eff_weight_kernel<<<2048, 256, 0, stream>>>(Wk, Wk_lsr, Weff_tmp, 512);
    eff_bias_kernel<<<8, 256, 0, stream>>>(bq, Wq_lsr, bk, Wk_lsr, bv, bcat);

    // transpose+split weights; split x
    tsplit1024<<<dim3(16, 16), 256, 0, stream>>>(Weff_tmp, Wth, Wtl);
    tsplit1024<<<dim3(16, 16), 256, 0, stream>>>(
        Wv, Wth + (size_t)1024 * 1024, Wtl + (size_t)1024 * 1024);
    xsplit<<<2048, 256, 0, stream>>>(x, Xh, Xl);

    // [Yqk | Vtmp] = x @ [Wq_eff|Wk_eff|Wv] + bcat   (pre-split operands)
    gemm_pre<<<dim3(16, 32), 256, 0, stream>>>(
        Xh, Xl, Wth, Wtl, bcat, Yqk, Vtmp);

    vt_prep<<<dim3(32, 32), 256, 0, stream>>>(Vtmp, Vbf);
    kt_prep<<<dim3(32, 16), 256, 0, stream>>>(Yqk, Kth, Ktl);

    transpose1024<<<dim3(16, 16), 256, 0, stream>>>(Wo, Wo_t);

    flash_mfma<<<1024, 512, 0, stream>>>(Yqk, Kth, Ktl, Vbf, Oacc);

    // out = Oacc @ Wo + bo
    gemm_bt_split<<<dim3(8, 32), 256, 0, stream>>>(Oacc, Wo_t, bo, out);
}

// Round 19
// 246.792 us; speedup vs baseline: 1.1080x; 1.1080x over previous
//
#include <hip/hip_runtime.h>
#include <math.h>

#define D_MODEL 1024
#define N_HEADS 16
#define D_HEAD  64
#define LSR_RANK 32
#define BATCH 2
#define SEQ 2048
#define M_TOT (BATCH*SEQ)

typedef __attribute__((ext_vector_type(8))) short short8v;
typedef __attribute__((ext_vector_type(4))) short short4v;
typedef __attribute__((ext_vector_type(4))) float f32x4;

static __device__ __forceinline__ ushort bfhi(float f) {
    union { float f; unsigned u; } c; c.f = f;
    return (ushort)(c.u >> 16);
}
static __device__ __forceinline__ float bff(ushort h) {
    union { unsigned u; float f; } c; c.u = ((unsigned)h) << 16;
    return c.f;
}
static __device__ __forceinline__ ushort f2bf_rn(float f) {
    union { float f; unsigned u; } c; c.f = f;
    unsigned r = c.u + 0x7FFF + ((c.u >> 16) & 1);
    return (ushort)(r >> 16);
}
static __device__ __forceinline__ void split8(const float4 a, const float4 b,
                                              short8v& h, short8v& l) {
    ushort h0 = bfhi(a.x), h1 = bfhi(a.y), h2 = bfhi(a.z), h3 = bfhi(a.w);
    ushort h4 = bfhi(b.x), h5 = bfhi(b.y), h6 = bfhi(b.z), h7 = bfhi(b.w);
    h[0] = (short)h0; h[1] = (short)h1; h[2] = (short)h2; h[3] = (short)h3;
    h[4] = (short)h4; h[5] = (short)h5; h[6] = (short)h6; h[7] = (short)h7;
    l[0] = (short)bfhi(a.x - bff(h0)); l[1] = (short)bfhi(a.y - bff(h1));
    l[2] = (short)bfhi(a.z - bff(h2)); l[3] = (short)bfhi(a.w - bff(h3));
    l[4] = (short)bfhi(b.x - bff(h4)); l[5] = (short)bfhi(b.y - bff(h5));
    l[6] = (short)bfhi(b.z - bff(h6)); l[7] = (short)bfhi(b.w - bff(h7));
}

// ---------------------------------------------------------------------------
// Weff_tmp[k][base+c] = sum_d W[k, h*64+d] * Wlsr[h, d, r]
// ---------------------------------------------------------------------------
__global__ __launch_bounds__(256) void eff_weight_kernel(
    const float* __restrict__ W, const float* __restrict__ Wlsr,
    float* __restrict__ Weff_tmp, int base)
{
    int idx = blockIdx.x * 256 + threadIdx.x;
    int k = idx >> 9;
    int c = idx & 511;
    int h = c >> 5;
    int r = c & 31;
    const float* wrow = W + (size_t)k * D_MODEL + h * D_HEAD;
    const float* lsr  = Wlsr + (size_t)h * D_HEAD * LSR_RANK + r;
    float acc = 0.f;
    #pragma unroll
    for (int d = 0; d < D_HEAD; ++d)
        acc = fmaf(wrow[d], lsr[d * LSR_RANK], acc);
    Weff_tmp[(size_t)k * 1024 + base + c] = acc;
}

__global__ __launch_bounds__(256) void eff_bias_kernel(
    const float* __restrict__ bq, const float* __restrict__ Wq_lsr,
    const float* __restrict__ bk, const float* __restrict__ Wk_lsr,
    const float* __restrict__ bv, float* __restrict__ bcat)
{
    int c = blockIdx.x * 256 + threadIdx.x;
    if (c < 1024) {
        const float* bias = (c < 512) ? bq : bk;
        const float* lsr  = (c < 512) ? Wq_lsr : Wk_lsr;
        int cc = c & 511;
        int h = cc >> 5, r = cc & 31;
        float acc = 0.f;
        #pragma unroll
        for (int d = 0; d < D_HEAD; ++d)
            acc = fmaf(bias[h * D_HEAD + d],
                       lsr[(size_t)h * D_HEAD * LSR_RANK + d * LSR_RANK + r], acc);
        bcat[c] = acc;
    } else {
        bcat[c] = bv[c - 1024];
    }
}

// ---------------------------------------------------------------------------
// Transpose + bf16 hi/lo split: in[1024][1024] fp32 -> oh/ol transposed bf16.
// ---------------------------------------------------------------------------
__global__ __launch_bounds__(256) void tsplit1024(
    const float* __restrict__ in, short* __restrict__ oh, short* __restrict__ ol)
{
    __shared__ float t[64][65];
    const int tid = threadIdx.x;
    const int r0 = blockIdx.y * 64, c0 = blockIdx.x * 64;
    const int tr = tid >> 4, tc = tid & 15;
    #pragma unroll
    for (int i = 0; i < 4; ++i) {
        float4 v = *(const float4*)&in[(size_t)(r0 + tr + i * 16) * 1024 + c0 + tc * 4];
        t[tr + i * 16][tc * 4 + 0] = v.x;
        t[tr + i * 16][tc * 4 + 1] = v.y;
        t[tr + i * 16][tc * 4 + 2] = v.z;
        t[tr + i * 16][tc * 4 + 3] = v.w;
    }
    __syncthreads();
    #pragma unroll
    for (int i = 0; i < 4; ++i) {
        float v0 = t[tc * 4 + 0][tr + i * 16];
        float v1 = t[tc * 4 + 1][tr + i * 16];
        float v2 = t[tc * 4 + 2][tr + i * 16];
        float v3 = t[tc * 4 + 3][tr + i * 16];
        ushort h0 = bfhi(v0), h1 = bfhi(v1), h2 = bfhi(v2), h3 = bfhi(v3);
        short4v hv = {(short)h0, (short)h1, (short)h2, (short)h3};
        short4v lv = {(short)bfhi(v0 - bff(h0)), (short)bfhi(v1 - bff(h1)),
                      (short)bfhi(v2 - bff(h2)), (short)bfhi(v3 - bff(h3))};
        const size_t o = (size_t)(c0 + tr + i * 16) * 1024 + r0 + tc * 4;
        *(short4v*)&oh[o] = hv;
        *(short4v*)&ol[o] = lv;
    }
}

// ---------------------------------------------------------------------------
// Transpose + bf16-rn (single term): in[1024][1024] fp32 -> out transposed.
// ---------------------------------------------------------------------------
__global__ __launch_bounds__(256) void tsplit_rn1024(
    const float* __restrict__ in, ushort* __restrict__ out)
{
    __shared__ float t[64][65];
    const int tid = threadIdx.x;
    const int r0 = blockIdx.y * 64, c0 = blockIdx.x * 64;
    const int tr = tid >> 4, tc = tid & 15;
    #pragma unroll
    for (int i = 0; i < 4; ++i) {
        float4 v = *(const float4*)&in[(size_t)(r0 + tr + i * 16) * 1024 + c0 + tc * 4];
        t[tr + i * 16][tc * 4 + 0] = v.x;
        t[tr + i * 16][tc * 4 + 1] = v.y;
        t[tr + i * 16][tc * 4 + 2] = v.z;
        t[tr + i * 16][tc * 4 + 3] = v.w;
    }
    __syncthreads();
    #pragma unroll
    for (int i = 0; i < 4; ++i) {
        short4v hv = {(short)f2bf_rn(t[tc * 4 + 0][tr + i * 16]),
                      (short)f2bf_rn(t[tc * 4 + 1][tr + i * 16]),
                      (short)f2bf_rn(t[tc * 4 + 2][tr + i * 16]),
                      (short)f2bf_rn(t[tc * 4 + 3][tr + i * 16])};
        *(short4v*)&out[(size_t)(c0 + tr + i * 16) * 1024 + r0 + tc * 4] = hv;
    }
}

// ---------------------------------------------------------------------------
// x -> Xh/Xl bf16 hi/lo
// ---------------------------------------------------------------------------
__global__ __launch_bounds__(256) void xsplit(
    const float* __restrict__ x, short* __restrict__ Xh, short* __restrict__ Xl)
{
    const size_t idx = ((size_t)blockIdx.x * 256 + threadIdx.x) * 8;
    float4 a = *(const float4*)(x + idx);
    float4 b = *(const float4*)(x + idx + 4);
    short8v h, l;
    split8(a, b, h, l);
    *(short8v*)(Xh + idx) = h;
    *(short8v*)(Xl + idx) = l;
}

// ---------------------------------------------------------------------------
// Pre-split proj GEMM (r17): QK half 3-term -> Yqk; V half 1-term -> Vtmp.
// ---------------------------------------------------------------------------
__global__ __launch_bounds__(256) void gemm_pre(
    const short* __restrict__ Xh, const short* __restrict__ Xl,
    const short* __restrict__ Wth, const short* __restrict__ Wtl,
    const float* __restrict__ bcat,
    float* __restrict__ Yqk, float* __restrict__ Vtmp)
{
    __shared__ __align__(16) short Ah[128 * 40], Al[128 * 40];
    __shared__ __align__(16) short Bh[128 * 40], Bl[128 * 40];

    const int tid = threadIdx.x;
    const int m0 = blockIdx.y * 128, n0 = blockIdx.x * 128;
    const bool vhalf = (n0 >= 1024);
    const int wid = tid >> 6, wr = wid >> 1, wc = wid & 1;
    const int lane = tid & 63, fr = lane & 15, fq = lane >> 4;
    const int srow = tid >> 1;
    const int skq  = (tid & 1) << 4;

    f32x4 acc[4][4];
    #pragma unroll
    for (int i = 0; i < 4; ++i)
        #pragma unroll
        for (int j = 0; j < 4; ++j)
            acc[i][j] = (f32x4){0.f, 0.f, 0.f, 0.f};

    const short* AgH = Xh + (size_t)(m0 + srow) * 1024 + skq;
    const short* AgL = Xl + (size_t)(m0 + srow) * 1024 + skq;
    const short* BgH = Wth + (size_t)(n0 + srow) * 1024 + skq;
    const short* BgL = Wtl + (size_t)(n0 + srow) * 1024 + skq;
    short* pAh = &Ah[srow * 40 + skq];
    short* pAl = &Al[srow * 40 + skq];
    short* pBh = &Bh[srow * 40 + skq];
    short* pBl = &Bl[srow * 40 + skq];

    for (int k0 = 0; k0 < 1024; k0 += 32) {
        *(short8v*)pAh       = *(const short8v*)(AgH + k0);
        *(short8v*)(pAh + 8) = *(const short8v*)(AgH + k0 + 8);
        *(short8v*)pBh       = *(const short8v*)(BgH + k0);
        *(short8v*)(pBh + 8) = *(const short8v*)(BgH + k0 + 8);
        if (!vhalf) {
            *(short8v*)pAl       = *(const short8v*)(AgL + k0);
            *(short8v*)(pAl + 8) = *(const short8v*)(AgL + k0 + 8);
            *(short8v*)pBl       = *(const short8v*)(BgL + k0);
            *(short8v*)(pBl + 8) = *(const short8v*)(BgL + k0 + 8);
        }
        __syncthreads();

        short8v afh[4], bfh[4];
        #pragma unroll
        for (int fi = 0; fi < 4; ++fi)
            afh[fi] = *(const short8v*)&Ah[(wr * 64 + fi * 16 + fr) * 40 + fq * 8];
        #pragma unroll
        for (int bj = 0; bj < 4; ++bj)
            bfh[bj] = *(const short8v*)&Bh[(wc * 64 + bj * 16 + fr) * 40 + fq * 8];

        if (vhalf) {
            #pragma unroll
            for (int fi = 0; fi < 4; ++fi)
                #pragma unroll
                for (int bj = 0; bj < 4; ++bj)
                    acc[fi][bj] = __builtin_amdgcn_mfma_f32_16x16x32_bf16(
                        afh[fi], bfh[bj], acc[fi][bj], 0, 0, 0);
        } else {
            short8v afl[4], bfl[4];
            #pragma unroll
            for (int fi = 0; fi < 4; ++fi)
                afl[fi] = *(const short8v*)&Al[(wr * 64 + fi * 16 + fr) * 40 + fq * 8];
            #pragma unroll
            for (int bj = 0; bj < 4; ++bj)
                bfl[bj] = *(const short8v*)&Bl[(wc * 64 + bj * 16 + fr) * 40 + fq * 8];
            #pragma unroll
            for (int fi = 0; fi < 4; ++fi) {
                #pragma unroll
                for (int bj = 0; bj < 4; ++bj) {
                    acc[fi][bj] = __builtin_amdgcn_mfma_f32_16x16x32_bf16(
                        afh[fi], bfh[bj], acc[fi][bj], 0, 0, 0);
                    acc[fi][bj] = __builtin_amdgcn_mfma_f32_16x16x32_bf16(
                        afh[fi], bfl[bj], acc[fi][bj], 0, 0, 0);
                    acc[fi][bj] = __builtin_amdgcn_mfma_f32_16x16x32_bf16(
                        afl[fi], bfh[bj], acc[fi][bj], 0, 0, 0);
                }
            }
        }
        __syncthreads();
    }

    float* Cw = vhalf ? Vtmp : Yqk;
    #pragma unroll
    for (int fi = 0; fi < 4; ++fi) {
        #pragma unroll
        for (int bj = 0; bj < 4; ++bj) {
            const int r = m0 + wr * 64 + fi * 16 + fq * 4;
            const int gcol = n0 + wc * 64 + bj * 16 + fr;
            const int c = vhalf ? (gcol - 1024) : gcol;
            const float bv_ = bcat[gcol];
            #pragma unroll
            for (int j = 0; j < 4; ++j)
                Cw[(size_t)(r + j) * 1024 + c] = acc[fi][bj][j] + bv_;
        }
    }
}

// ---------------------------------------------------------------------------
// Out-proj GEMM, 1-term bf16 with pre-rounded operands:
// out = Obf(bf16) @ Wot(bf16)^T + bo.  16 MFMA/K-step, copy staging.
// ---------------------------------------------------------------------------
__global__ __launch_bounds__(256) void gemm_out_bf(
    const ushort* __restrict__ Obf,   // [4096][1024] bf16-rn
    const ushort* __restrict__ Wot,   // [1024][1024] bf16-rn (Wo^T)
    const float* __restrict__ bo,
    float* __restrict__ out)
{
    __shared__ __align__(16) short Ah[128 * 40];
    __shared__ __align__(16) short Bh[128 * 40];

    const int tid = threadIdx.x;
    const int m0 = blockIdx.y * 128, n0 = blockIdx.x * 128;
    const int wid = tid >> 6, wr = wid >> 1, wc = wid & 1;
    const int lane = tid & 63, fr = lane & 15, fq = lane >> 4;
    const int srow = tid >> 1;
    const int skq  = (tid & 1) << 4;

    f32x4 acc[4][4];
    #pragma unroll
    for (int i = 0; i < 4; ++i)
        #pragma unroll
        for (int j = 0; j < 4; ++j)
            acc[i][j] = (f32x4){0.f, 0.f, 0.f, 0.f};

    const ushort* AgH = Obf + (size_t)(m0 + srow) * 1024 + skq;
    const ushort* BgH = Wot + (size_t)(n0 + srow) * 1024 + skq;
    short* pAh = &Ah[srow * 40 + skq];
    short* pBh = &Bh[srow * 40 + skq];

    for (int k0 = 0; k0 < 1024; k0 += 32) {
        *(short8v*)pAh       = *(const short8v*)(AgH + k0);
        *(short8v*)(pAh + 8) = *(const short8v*)(AgH + k0 + 8);
        *(short8v*)pBh       = *(const short8v*)(BgH + k0);
        *(short8v*)(pBh + 8) = *(const short8v*)(BgH + k0 + 8);
        __syncthreads();

        short8v afh[4], bfh[4];
        #pragma unroll
        for (int fi = 0; fi < 4; ++fi)
            afh[fi] = *(const short8v*)&Ah[(wr * 64 + fi * 16 + fr) * 40 + fq * 8];
        #pragma unroll
        for (int bj = 0; bj < 4; ++bj)
            bfh[bj] = *(const short8v*)&Bh[(wc * 64 + bj * 16 + fr) * 40 + fq * 8];
        #pragma unroll
        for (int fi = 0; fi < 4; ++fi)
            #pragma unroll
            for (int bj = 0; bj < 4; ++bj)
                acc[fi][bj] = __builtin_amdgcn_mfma_f32_16x16x32_bf16(
                    afh[fi], bfh[bj], acc[fi][bj], 0, 0, 0);
        __syncthreads();
    }

    #pragma unroll
    for (int fi = 0; fi < 4; ++fi) {
        #pragma unroll
        for (int bj = 0; bj < 4; ++bj) {
            const int r = m0 + wr * 64 + fi * 16 + fq * 4;
            const int c = n0 + wc * 64 + bj * 16 + fr;
            const float bv_ = bo[c];
            #pragma unroll
            for (int j = 0; j < 4; ++j)
                out[(size_t)(r + j) * 1024 + c] = acc[fi][bj][j] + bv_;
        }
    }
}

// ---------------------------------------------------------------------------
// K pre-split: Kth/Ktl [bh][2048 t][32 r] bf16.
// ---------------------------------------------------------------------------
__global__ __launch_bounds__(256) void kt_prep(
    const float* __restrict__ Yqk,
    short* __restrict__ Kth, short* __restrict__ Ktl)
{
    const int bh = blockIdx.x;
    const int b = bh >> 4, h = bh & 15;
    const int t0 = blockIdx.y * 128;
    const int tid = threadIdx.x;
    const int tl = tid >> 1, half = tid & 1;
    const float* src = Yqk + (size_t)(b * SEQ + t0 + tl) * 1024 + 512 + h * 32 + half * 16;
    short8v h0, l0, h1, l1;
    split8(((const float4*)src)[0], ((const float4*)src)[1], h0, l0);
    split8(((const float4*)src)[2], ((const float4*)src)[3], h1, l1);
    short* oh = Kth + ((size_t)bh * 2048 + t0 + tl) * 32 + half * 16;
    short* ol = Ktl + ((size_t)bh * 2048 + t0 + tl) * 32 + half * 16;
    *(short8v*)oh = h0;  *(short8v*)(oh + 8) = h1;
    *(short8v*)ol = l0;  *(short8v*)(ol + 8) = l1;
}

// ---------------------------------------------------------------------------
// V transpose + bf16-rn: Vtmp[4096][1024] -> Vbf [bh][64 d][2048 t]
// ---------------------------------------------------------------------------
__global__ __launch_bounds__(256) void vt_prep(
    const float* __restrict__ Vtmp, short* __restrict__ Vbf)
{
    __shared__ float t[64][68];
    const int bh = blockIdx.x;
    const int b = bh >> 4, h = bh & 15;
    const int t0 = blockIdx.y * 64;
    const int tid = threadIdx.x;
    {
        const int tl = tid >> 2, sg = tid & 3;
        const float* vp = Vtmp + (size_t)(b * SEQ + t0 + tl) * 1024 + h * 64 + sg * 16;
        #pragma unroll
        for (int i = 0; i < 4; ++i)
            *(float4*)&t[tl][sg * 16 + i * 4] = *(const float4*)(vp + i * 4);
    }
    __syncthreads();
    {
        const int d = tid >> 2, sg = tid & 3;
        short8v h0, h1;
        #pragma unroll
        for (int i = 0; i < 8; ++i) {
            h0[i] = (short)f2bf_rn(t[sg * 16 + i][d]);
            h1[i] = (short)f2bf_rn(t[sg * 16 + 8 + i][d]);
        }
        short* oh = Vbf + ((size_t)bh * 64 + d) * 2048 + t0 + sg * 16;
        *(short8v*)oh = h0;  *(short8v*)(oh + 8) = h1;
    }
}

// ---------------------------------------------------------------------------
// MFMA flash attention v7b = r16 loop UNCHANGED; epilogue writes bf16-rn
// (halves output traffic; feeds 1-term out-proj directly).
// ---------------------------------------------------------------------------
#define P_LD  68
#define MASKVAL (-1e30f)

__global__ __launch_bounds__(512) void flash_mfma(
    const float* __restrict__ Yqk,
    const short* __restrict__ Kth, const short* __restrict__ Ktl,
    const short* __restrict__ Vbf,
    ushort* __restrict__ Obf)        // [4096][1024] bf16-rn
{
    const float scale = 0.1767766952966369f;  // 1/sqrt(32)
    const int L = blockIdx.x;
    const int bh = L & 31;
    const int qt = 31 - (L >> 5);
    const int b = bh >> 4, h = bh & 15;
    const int tid = threadIdx.x;
    const int w = tid >> 6;
    const int g = w & 3;
    const int p = w >> 2;
    const int lane = tid & 63;
    const int fr = lane & 15, fq = lane >> 4;

    __shared__ __align__(16) short Pall[8][16 * P_LD];
    __shared__ __align__(16) float ex[4 * 64 * 28];
    short* Pw = &Pall[w][0];

    short8v aqh, aql;
    {
        const float* qp = Yqk + (size_t)(b * SEQ + qt * 64 + g * 16 + fr) * 1024
                          + h * 32 + fq * 8;
        split8(*(const float4*)qp, *(const float4*)(qp + 4), aqh, aql);
    }

    f32x4 acc0 = {0,0,0,0}, acc1 = {0,0,0,0}, acc2 = {0,0,0,0}, acc3 = {0,0,0,0};
    float m_[4], l_[4];
    #pragma unroll
    for (int r = 0; r < 4; ++r) { m_[r] = MASKVAL; l_[r] = 0.f; }

    const short* kb_h = Kth + (size_t)bh * 2048 * 32;
    const short* kb_l = Ktl + (size_t)bh * 2048 * 32;
    const short* vb   = Vbf + (size_t)bh * 64 * 2048;
    const int kidx = fr * 32 + fq * 8;
    const int vrow = fr * 2048 + fq * 8;

    for (int jt = p; jt <= qt; jt += 2) {
        const short* kp_h = kb_h + (size_t)jt * 64 * 32;
        const short* kp_l = kb_l + (size_t)jt * 64 * 32;
        short8v kh0 = *(const short8v*)&kp_h[kidx];
        short8v kh1 = *(const short8v*)&kp_h[kidx + 512];
        short8v kh2 = *(const short8v*)&kp_h[kidx + 1024];
        short8v kh3 = *(const short8v*)&kp_h[kidx + 1536];
        short8v kl0 = *(const short8v*)&kp_l[kidx];
        short8v kl1 = *(const short8v*)&kp_l[kidx + 512];
        short8v kl2 = *(const short8v*)&kp_l[kidx + 1024];
        short8v kl3 = *(const short8v*)&kp_l[kidx + 1536];
        const short* vp = vb + vrow + jt * 64;
        short8v v00 = *(const short8v*)&vp[0];
        short8v v01 = *(const short8v*)&vp[32];
        short8v v10 = *(const short8v*)&vp[16 * 2048];
        short8v v11 = *(const short8v*)&vp[16 * 2048 + 32];
        short8v v20 = *(const short8v*)&vp[32 * 2048];
        short8v v21 = *(const short8v*)&vp[32 * 2048 + 32];
        short8v v30 = *(const short8v*)&vp[48 * 2048];
        short8v v31 = *(const short8v*)&vp[48 * 2048 + 32];

        f32x4 s0 = {0,0,0,0}, s1 = {0,0,0,0}, s2 = {0,0,0,0}, s3 = {0,0,0,0};
        s0 = __builtin_amdgcn_mfma_f32_16x16x32_bf16(aqh, kh0, s0, 0, 0, 0);
        s0 = __builtin_amdgcn_mfma_f32_16x16x32_bf16(aqh, kl0, s0, 0, 0, 0);
        s0 = __builtin_amdgcn_mfma_f32_16x16x32_bf16(aql, kh0, s0, 0, 0, 0);
        s1 = __builtin_amdgcn_mfma_f32_16x16x32_bf16(aqh, kh1, s1, 0, 0, 0);
        s1 = __builtin_amdgcn_mfma_f32_16x16x32_bf16(aqh, kl1, s1, 0, 0, 0);
        s1 = __builtin_amdgcn_mfma_f32_16x16x32_bf16(aql, kh1, s1, 0, 0, 0);
        s2 = __builtin_amdgcn_mfma_f32_16x16x32_bf16(aqh, kh2, s2, 0, 0, 0);
        s2 = __builtin_amdgcn_mfma_f32_16x16x32_bf16(aqh, kl2, s2, 0, 0, 0);
        s2 = __builtin_amdgcn_mfma_f32_16x16x32_bf16(aql, kh2, s2, 0, 0, 0);
        s3 = __builtin_amdgcn_mfma_f32_16x16x32_bf16(aqh, kh3, s3, 0, 0, 0);
        s3 = __builtin_amdgcn_mfma_f32_16x16x32_bf16(aqh, kl3, s3, 0, 0, 0);
        s3 = __builtin_amdgcn_mfma_f32_16x16x32_bf16(aql, kh3, s3, 0, 0, 0);

        s0 *= scale; s1 *= scale; s2 *= scale; s3 *= scale;

        if (jt == qt) {
            #pragma unroll
            for (int r = 0; r < 4; ++r) {
                const int q_l = g * 16 + fq * 4 + r;
                s0[r] = (fr      <= q_l) ? s0[r] : MASKVAL;
                s1[r] = (16 + fr <= q_l) ? s1[r] : MASKVAL;
                s2[r] = (32 + fr <= q_l) ? s2[r] : MASKVAL;
                s3[r] = (48 + fr <= q_l) ? s3[r] : MASKVAL;
            }
        }

        float al[4];
        #pragma unroll
        for (int r = 0; r < 4; ++r) {
            float mt = fmaxf(fmaxf(s0[r], s1[r]), fmaxf(s2[r], s3[r]));
            mt = fmaxf(mt, __shfl_xor(mt, 1));
            mt = fmaxf(mt, __shfl_xor(mt, 2));
            mt = fmaxf(mt, __shfl_xor(mt, 4));
            mt = fmaxf(mt, __shfl_xor(mt, 8));
            const float mnew = fmaxf(m_[r], mt);
            al[r] = __expf(m_[r] - mnew);
            m_[r] = mnew;
            s0[r] = __expf(s0[r] - mnew);
            s1[r] = __expf(s1[r] - mnew);
            s2[r] = __expf(s2[r] - mnew);
            s3[r] = __expf(s3[r] - mnew);
            float ps = s0[r] + s1[r] + s2[r] + s3[r];
            ps += __shfl_xor(ps, 1);
            ps += __shfl_xor(ps, 2);
            ps += __shfl_xor(ps, 4);
            ps += __shfl_xor(ps, 8);
            l_[r] = l_[r] * al[r] + ps;
        }

        #pragma unroll
        for (int r = 0; r < 4; ++r) {
            const int prow = fq * 4 + r;
            Pw[prow * P_LD +      fr] = (short)f2bf_rn(s0[r]);
            Pw[prow * P_LD + 16 + fr] = (short)f2bf_rn(s1[r]);
            Pw[prow * P_LD + 32 + fr] = (short)f2bf_rn(s2[r]);
            Pw[prow * P_LD + 48 + fr] = (short)f2bf_rn(s3[r]);
        }
        #pragma unroll
        for (int r = 0; r < 4; ++r) {
            acc0[r] *= al[r]; acc1[r] *= al[r];
            acc2[r] *= al[r]; acc3[r] *= al[r];
        }
        short8v pa0 = *(const short8v*)&Pw[fr * P_LD + fq * 8];
        short8v pa1 = *(const short8v*)&Pw[fr * P_LD + 32 + fq * 8];

        acc0 = __builtin_amdgcn_mfma_f32_16x16x32_bf16(pa0, v00, acc0, 0, 0, 0);
        acc0 = __builtin_amdgcn_mfma_f32_16x16x32_bf16(pa1, v01, acc0, 0, 0, 0);
        acc1 = __builtin_amdgcn_mfma_f32_16x16x32_bf16(pa0, v10, acc1, 0, 0, 0);
        acc1 = __builtin_amdgcn_mfma_f32_16x16x32_bf16(pa1, v11, acc1, 0, 0, 0);
        acc2 = __builtin_amdgcn_mfma_f32_16x16x32_bf16(pa0, v20, acc2, 0, 0, 0);
        acc2 = __builtin_amdgcn_mfma_f32_16x16x32_bf16(pa1, v21, acc2, 0, 0, 0);
        acc3 = __builtin_amdgcn_mfma_f32_16x16x32_bf16(pa0, v30, acc3, 0, 0, 0);
        acc3 = __builtin_amdgcn_mfma_f32_16x16x32_bf16(pa1, v31, acc3, 0, 0, 0);
    }

    if (p == 1) {
        float* e = ex + ((g << 6) + lane) * 28;
        *(f32x4*)(e +  0) = acc0;
        *(f32x4*)(e +  4) = acc1;
        *(f32x4*)(e +  8) = acc2;
        *(f32x4*)(e + 12) = acc3;
        *(f32x4*)(e + 16) = (f32x4){m_[0], m_[1], m_[2], m_[3]};
        *(f32x4*)(e + 20) = (f32x4){l_[0], l_[1], l_[2], l_[3]};
    }
    __syncthreads();
    if (p == 0) {
        const float* e = ex + ((g << 6) + lane) * 28;
        f32x4 b0 = *(const f32x4*)(e +  0);
        f32x4 b1 = *(const f32x4*)(e +  4);
        f32x4 b2 = *(const f32x4*)(e +  8);
        f32x4 b3 = *(const f32x4*)(e + 12);
        f32x4 m1 = *(const f32x4*)(e + 16);
        f32x4 l1 = *(const f32x4*)(e + 20);
        #pragma unroll
        for (int r = 0; r < 4; ++r) {
            const float mm = fmaxf(m_[r], m1[r]);
            const float a0 = __expf(m_[r] - mm);
            const float a1 = __expf(m1[r] - mm);
            const float inv = 1.f / (l_[r] * a0 + l1[r] * a1);
            const int trow = qt * 64 + g * 16 + fq * 4 + r;
            ushort* op = Obf + (size_t)(b * SEQ + trow) * 1024 + h * 64;
            op[     fr] = f2bf_rn((acc0[r] * a0 + b0[r] * a1) * inv);
            op[16 + fr] = f2bf_rn((acc1[r] * a0 + b1[r] * a1) * inv);
            op[32 + fr] = f2bf_rn((acc2[r] * a0 + b2[r] * a1) * inv);
            op[48 + fr] = f2bf_rn((acc3[r] * a0 + b3[r] * a1) * inv);
        }
    }
}

// ---------------------------------------------------------------------------
extern "C" void kernel_launch(void* const* d_in, const int* in_sizes, int n_in,
                              void* d_out, int out_size, void* d_ws, size_t ws_size,
                              hipStream_t stream)
{
    const float* x      = (const float*)d_in[0];
    const float* Wq     = (const float*)d_in[1];
    const float* bq     = (const float*)d_in[2];
    const float* Wk     = (const float*)d_in[3];
    const float* bk     = (const float*)d_in[4];
    const float* Wv     = (const float*)d_in[5];
    const float* bv     = (const float*)d_in[6];
    const float* Wo     = (const float*)d_in[7];
    const float* bo     = (const float*)d_in[8];
    const float* Wq_lsr = (const float*)d_in[9];
    const float* Wk_lsr = (const float*)d_in[10];
    float* out = (float*)d_out;

    // workspace (~56 MB):
    //  A: Wth/Wtl (8 MB shorts) -> Wot (2 MB ushorts) after gemm_pre
    //  B: Xh/Xl (16 MB shorts)  -> Vbf | Kth | Ktl after gemm_pre
    //  bcat; Yqk (16 MB); Vtmp (16 MB; Weff_tmp pre-proj; Obf post-vt_prep)
    float* ws    = (float*)d_ws;
    short* Wth   = (short*)ws;
    short* Wtl   = Wth + (size_t)2048 * 1024;
    float* bcat  = ws + (size_t)2 * 1024 * 1024;
    short* Xh    = (short*)(bcat + 2048);
    short* Xl    = Xh + (size_t)M_TOT * 1024;
    float* Yqk   = (float*)(Xl + (size_t)M_TOT * 1024);
    float* Vtmp  = Yqk + (size_t)M_TOT * 1024;
    float* Weff_tmp = Vtmp;            // alias: dead before gemm_pre writes Vtmp
    ushort* Obf  = (ushort*)Vtmp;      // alias: fp32 V dead after vt_prep
    short* Vbf   = Xh;                 // alias: Xh/Xl dead after gemm_pre
    short* Kth   = Xl;
    short* Ktl   = Kth + (size_t)32 * 2048 * 32;
    ushort* Wot  = (ushort*)Wth;       // alias: Wth/Wtl dead after gemm_pre

    eff_weight_kernel<<<2048, 256, 0, stream>>>(Wq, Wq_lsr, Weff_tmp, 0);
    eff_weight_kernel<<<2048, 256, 0, stream>>>(Wk, Wk_lsr, Weff_tmp, 512);
    eff_bias_kernel<<<8, 256, 0, stream>>>(bq, Wq_lsr, bk, Wk_lsr, bv, bcat);

    tsplit1024<<<dim3(16, 16), 256, 0, stream>>>(Weff_tmp, Wth, Wtl);
    tsplit1024<<<dim3(16, 16), 256, 0, stream>>>(
        Wv, Wth + (size_t)1024 * 1024, Wtl + (size_t)1024 * 1024);
    xsplit<<<2048, 256, 0, stream>>>(x, Xh, Xl);

    // [Yqk | Vtmp] = x @ [Wq_eff|Wk_eff|Wv] + bcat
    gemm_pre<<<dim3(16, 32), 256, 0, stream>>>(
        Xh, Xl, Wth, Wtl, bcat, Yqk, Vtmp);

    vt_prep<<<dim3(32, 32), 256, 0, stream>>>(Vtmp, Vbf);
    kt_prep<<<dim3(32, 16), 256, 0, stream>>>(Yqk, Kth, Ktl);

    // Wo^T as bf16-rn (Wth/Wtl region is dead after gemm_pre)
    tsplit_rn1024<<<dim3(16, 16), 256, 0, stream>>>(Wo, Wot);

    flash_mfma<<<1024, 512, 0, stream>>>(Yqk, Kth, Ktl, Vbf, Obf);

    // out = Obf @ Wo + bo (1-term bf16)
    gemm_out_bf<<<dim3(8, 32), 256, 0, stream>>>(Obf, Wot, bo, out);
}

// Round 22
// 221.403 us; speedup vs baseline: 1.2350x; 1.1147x over previous
//
#include <hip/hip_runtime.h>
#include <math.h>

#define D_MODEL 1024
#define N_HEADS 16
#define D_HEAD  64
#define LSR_RANK 32
#define BATCH 2
#define SEQ 2048
#define M_TOT (BATCH*SEQ)

typedef __attribute__((ext_vector_type(8))) short short8v;
typedef __attribute__((ext_vector_type(4))) short short4v;
typedef __attribute__((ext_vector_type(4))) float f32x4;

static __device__ __forceinline__ ushort bfhi(float f) {
    union { float f; unsigned u; } c; c.f = f;
    return (ushort)(c.u >> 16);
}
static __device__ __forceinline__ float bff(ushort h) {
    union { unsigned u; float f; } c; c.u = ((unsigned)h) << 16;
    return c.f;
}
static __device__ __forceinline__ ushort f2bf_rn(float f) {
    union { float f; unsigned u; } c; c.f = f;
    unsigned r = c.u + 0x7FFF + ((c.u >> 16) & 1);
    return (ushort)(r >> 16);
}
static __device__ __forceinline__ void split8(const float4 a, const float4 b,
                                              short8v& h, short8v& l) {
    ushort h0 = bfhi(a.x), h1 = bfhi(a.y), h2 = bfhi(a.z), h3 = bfhi(a.w);
    ushort h4 = bfhi(b.x), h5 = bfhi(b.y), h6 = bfhi(b.z), h7 = bfhi(b.w);
    h[0] = (short)h0; h[1] = (short)h1; h[2] = (short)h2; h[3] = (short)h3;
    h[4] = (short)h4; h[5] = (short)h5; h[6] = (short)h6; h[7] = (short)h7;
    l[0] = (short)bfhi(a.x - bff(h0)); l[1] = (short)bfhi(a.y - bff(h1));
    l[2] = (short)bfhi(a.z - bff(h2)); l[3] = (short)bfhi(a.w - bff(h3));
    l[4] = (short)bfhi(b.x - bff(h4)); l[5] = (short)bfhi(b.y - bff(h5));
    l[6] = (short)bfhi(b.z - bff(h6)); l[7] = (short)bfhi(b.w - bff(h7));
}
static __device__ __forceinline__ void trunc8(const float4 a, const float4 b,
                                              short8v& h) {
    h[0] = (short)bfhi(a.x); h[1] = (short)bfhi(a.y);
    h[2] = (short)bfhi(a.z); h[3] = (short)bfhi(a.w);
    h[4] = (short)bfhi(b.x); h[5] = (short)bfhi(b.y);
    h[6] = (short)bfhi(b.z); h[7] = (short)bfhi(b.w);
}

// ---------------------------------------------------------------------------
// Weff_tmp[k][z*512+c] = sum_d W[k, h*64+d] * Wlsr[h, d, r]  (z=0:Wq, 1:Wk)
// ---------------------------------------------------------------------------
__global__ __launch_bounds__(256) void eff_weight2(
    const float* __restrict__ Wq, const float* __restrict__ Wq_lsr,
    const float* __restrict__ Wk, const float* __restrict__ Wk_lsr,
    float* __restrict__ Weff_tmp)
{
    const int z = blockIdx.y;
    const float* W    = z ? Wk : Wq;
    const float* Wlsr = z ? Wk_lsr : Wq_lsr;
    const int base = z << 9;
    int idx = blockIdx.x * 256 + threadIdx.x;
    int k = idx >> 9;
    int c = idx & 511;
    int h = c >> 5;
    int r = c & 31;
    const float* wrow = W + (size_t)k * D_MODEL + h * D_HEAD;
    const float* lsr  = Wlsr + (size_t)h * D_HEAD * LSR_RANK + r;
    float acc = 0.f;
    #pragma unroll
    for (int d = 0; d < D_HEAD; ++d)
        acc = fmaf(wrow[d], lsr[d * LSR_RANK], acc);
    Weff_tmp[(size_t)k * 1024 + base + c] = acc;
}

__global__ __launch_bounds__(256) void eff_bias_kernel(
    const float* __restrict__ bq, const float* __restrict__ Wq_lsr,
    const float* __restrict__ bk, const float* __restrict__ Wk_lsr,
    const float* __restrict__ bv, float* __restrict__ bcat)
{
    int c = blockIdx.x * 256 + threadIdx.x;
    if (c < 1024) {
        const float* bias = (c < 512) ? bq : bk;
        const float* lsr  = (c < 512) ? Wq_lsr : Wk_lsr;
        int cc = c & 511;
        int h = cc >> 5, r = cc & 31;
        float acc = 0.f;
        #pragma unroll
        for (int d = 0; d < D_HEAD; ++d)
            acc = fmaf(bias[h * D_HEAD + d],
                       lsr[(size_t)h * D_HEAD * LSR_RANK + d * LSR_RANK + r], acc);
        bcat[c] = acc;
    } else {
        bcat[c] = bv[c - 1024];
    }
}

// ---------------------------------------------------------------------------
// Dual 1024x1024 fp32 transpose: z=0: in0->out0, z=1: in1->out1.
// ---------------------------------------------------------------------------
__global__ __launch_bounds__(256) void transpose2(
    const float* __restrict__ in0, float* __restrict__ out0,
    const float* __restrict__ in1, float* __restrict__ out1)
{
    const float* in  = blockIdx.z ? in1 : in0;
    float* out       = blockIdx.z ? out1 : out0;
    __shared__ float t[64][65];
    const int tid = threadIdx.x;
    const int r0 = blockIdx.y * 64, c0 = blockIdx.x * 64;
    const int tr = tid >> 4, tc = tid & 15;
    #pragma unroll
    for (int i = 0; i < 4; ++i) {
        float4 v = *(const float4*)&in[(size_t)(r0 + tr + i * 16) * 1024 + c0 + tc * 4];
        t[tr + i * 16][tc * 4 + 0] = v.x;
        t[tr + i * 16][tc * 4 + 1] = v.y;
        t[tr + i * 16][tc * 4 + 2] = v.z;
        t[tr + i * 16][tc * 4 + 3] = v.w;
    }
    __syncthreads();
    #pragma unroll
    for (int i = 0; i < 4; ++i) {
        float4 v;
        v.x = t[tc * 4 + 0][tr + i * 16];
        v.y = t[tc * 4 + 1][tr + i * 16];
        v.z = t[tc * 4 + 2][tr + i * 16];
        v.w = t[tc * 4 + 3][tr + i * 16];
        *(float4*)&out[(size_t)(c0 + tr + i * 16) * 1024 + r0 + tc * 4] = v;
    }
}

// ---------------------------------------------------------------------------
// Transpose + bf16-rn: Wo[1024][1024] fp32 -> Wot transposed bf16.
// ---------------------------------------------------------------------------
__global__ __launch_bounds__(256) void tsplit_rn1024(
    const float* __restrict__ in, ushort* __restrict__ out)
{
    __shared__ float t[64][65];
    const int tid = threadIdx.x;
    const int r0 = blockIdx.y * 64, c0 = blockIdx.x * 64;
    const int tr = tid >> 4, tc = tid & 15;
    #pragma unroll
    for (int i = 0; i < 4; ++i) {
        float4 v = *(const float4*)&in[(size_t)(r0 + tr + i * 16) * 1024 + c0 + tc * 4];
        t[tr + i * 16][tc * 4 + 0] = v.x;
        t[tr + i * 16][tc * 4 + 1] = v.y;
        t[tr + i * 16][tc * 4 + 2] = v.z;
        t[tr + i * 16][tc * 4 + 3] = v.w;
    }
    __syncthreads();
    #pragma unroll
    for (int i = 0; i < 4; ++i) {
        short4v hv = {(short)f2bf_rn(t[tc * 4 + 0][tr + i * 16]),
                      (short)f2bf_rn(t[tc * 4 + 1][tr + i * 16]),
                      (short)f2bf_rn(t[tc * 4 + 2][tr + i * 16]),
                      (short)f2bf_rn(t[tc * 4 + 3][tr + i * 16])};
        *(short4v*)&out[(size_t)(c0 + tr + i * 16) * 1024 + r0 + tc * 4] = hv;
    }
}

// ---------------------------------------------------------------------------
// Fused projection GEMM (fp32 inputs, in-kernel split; r16 structure) with
// routed epilogue: bx 0-3 (Q)  -> Yqk fp32;
//                  bx 4-7 (K)  -> Kth/Ktl split-bf16 [bh][t][32];
//                  bx 8-15 (V) -> Vbf bf16-rn transposed [bh][d][t].
// Q/K halves 3-term split; V half 1-term (truncated-hi operands, as r19).
// Deletes kt_prep, vt_prep, Vtmp (identical numerics, no global round trip).
// ---------------------------------------------------------------------------
__global__ __launch_bounds__(256) void gemm_proj_fused(
    const float* __restrict__ x,      // [4096][1024]
    const float* __restrict__ Wcat_t, // [2048][1024] fp32 (weights^T)
    const float* __restrict__ bcat,   // [2048]
    float* __restrict__ Yqk,          // [4096][1024] (cols 0-511 used)
    short* __restrict__ Kth, short* __restrict__ Ktl,  // [32][2048][32]
    short* __restrict__ Vbf)          // [32][64][2048]
{
    __shared__ __align__(16) short Ah[128 * 40], Al[128 * 40];
    __shared__ __align__(16) short Bh[128 * 40], Bl[128 * 40];

    const int tid = threadIdx.x;
    const int bx = blockIdx.x;
    const int m0 = blockIdx.y * 128, n0 = bx * 128;
    const bool vhalf = (bx >= 8);
    const int wid = tid >> 6, wr = wid >> 1, wc = wid & 1;
    const int lane = tid & 63, fr = lane & 15, fq = lane >> 4;
    const int srow = tid >> 1;
    const int skq  = (tid & 1) << 4;

    f32x4 acc[4][4];
    #pragma unroll
    for (int i = 0; i < 4; ++i)
        #pragma unroll
        for (int j = 0; j < 4; ++j)
            acc[i][j] = (f32x4){0.f, 0.f, 0.f, 0.f};

    const float* Ag = x + (size_t)(m0 + srow) * 1024 + skq;
    const float* Bg = Wcat_t + (size_t)(n0 + srow) * 1024 + skq;
    short* pAh = &Ah[srow * 40 + skq];
    short* pAl = &Al[srow * 40 + skq];
    short* pBh = &Bh[srow * 40 + skq];
    short* pBl = &Bl[srow * 40 + skq];

    for (int k0 = 0; k0 < 1024; k0 += 32) {
        float4 a0 = *(const float4*)(Ag + k0);
        float4 a1 = *(const float4*)(Ag + k0 + 4);
        float4 a2 = *(const float4*)(Ag + k0 + 8);
        float4 a3 = *(const float4*)(Ag + k0 + 12);
        float4 b0 = *(const float4*)(Bg + k0);
        float4 b1 = *(const float4*)(Bg + k0 + 4);
        float4 b2 = *(const float4*)(Bg + k0 + 8);
        float4 b3 = *(const float4*)(Bg + k0 + 12);
        if (vhalf) {   // 1-term: truncated-hi only (matches r19 numerics)
            short8v h;
            trunc8(a0, a1, h); *(short8v*)pAh = h;
            trunc8(a2, a3, h); *(short8v*)(pAh + 8) = h;
            trunc8(b0, b1, h); *(short8v*)pBh = h;
            trunc8(b2, b3, h); *(short8v*)(pBh + 8) = h;
        } else {
            short8v h, l;
            split8(a0, a1, h, l);
            *(short8v*)pAh = h;  *(short8v*)pAl = l;
            split8(a2, a3, h, l);
            *(short8v*)(pAh + 8) = h;  *(short8v*)(pAl + 8) = l;
            split8(b0, b1, h, l);
            *(short8v*)pBh = h;  *(short8v*)pBl = l;
            split8(b2, b3, h, l);
            *(short8v*)(pBh + 8) = h;  *(short8v*)(pBl + 8) = l;
        }
        __syncthreads();

        short8v afh[4], bfh[4];
        #pragma unroll
        for (int fi = 0; fi < 4; ++fi)
            afh[fi] = *(const short8v*)&Ah[(wr * 64 + fi * 16 + fr) * 40 + fq * 8];
        #pragma unroll
        for (int bj = 0; bj < 4; ++bj)
            bfh[bj] = *(const short8v*)&Bh[(wc * 64 + bj * 16 + fr) * 40 + fq * 8];

        if (vhalf) {
            #pragma unroll
            for (int fi = 0; fi < 4; ++fi)
                #pragma unroll
                for (int bj = 0; bj < 4; ++bj)
                    acc[fi][bj] = __builtin_amdgcn_mfma_f32_16x16x32_bf16(
                        afh[fi], bfh[bj], acc[fi][bj], 0, 0, 0);
        } else {
            short8v afl[4], bfl[4];
            #pragma unroll
            for (int fi = 0; fi < 4; ++fi)
                afl[fi] = *(const short8v*)&Al[(wr * 64 + fi * 16 + fr) * 40 + fq * 8];
            #pragma unroll
            for (int bj = 0; bj < 4; ++bj)
                bfl[bj] = *(const short8v*)&Bl[(wc * 64 + bj * 16 + fr) * 40 + fq * 8];
            #pragma unroll
            for (int fi = 0; fi < 4; ++fi) {
                #pragma unroll
                for (int bj = 0; bj < 4; ++bj) {
                    acc[fi][bj] = __builtin_amdgcn_mfma_f32_16x16x32_bf16(
                        afh[fi], bfh[bj], acc[fi][bj], 0, 0, 0);
                    acc[fi][bj] = __builtin_amdgcn_mfma_f32_16x16x32_bf16(
                        afh[fi], bfl[bj], acc[fi][bj], 0, 0, 0);
                    acc[fi][bj] = __builtin_amdgcn_mfma_f32_16x16x32_bf16(
                        afl[fi], bfh[bj], acc[fi][bj], 0, 0, 0);
                }
            }
        }
        __syncthreads();
    }

    // routed epilogue
    const int b = m0 >> 11;            // batch of this row-block
    #pragma unroll
    for (int fi = 0; fi < 4; ++fi) {
        #pragma unroll
        for (int bj = 0; bj < 4; ++bj) {
            const int r = m0 + wr * 64 + fi * 16 + fq * 4;
            const int gcol = n0 + wc * 64 + bj * 16 + fr;
            const float bv_ = bcat[gcol];
            if (bx < 4) {                       // Q -> Yqk fp32
                #pragma unroll
                for (int j = 0; j < 4; ++j)
                    Yqk[(size_t)(r + j) * 1024 + gcol] = acc[fi][bj][j] + bv_;
            } else if (bx < 8) {                // K -> split bf16
                const int kc = gcol - 512;
                const int h = kc >> 5, rr = kc & 31;
                short* oh = Kth + (((size_t)(b * 16 + h) * 2048) + (r & 2047)) * 32 + rr;
                short* ol = Ktl + (((size_t)(b * 16 + h) * 2048) + (r & 2047)) * 32 + rr;
                #pragma unroll
                for (int j = 0; j < 4; ++j) {
                    const float v = acc[fi][bj][j] + bv_;
                    const ushort vh = bfhi(v);
                    oh[j * 32] = (short)vh;
                    ol[j * 32] = (short)bfhi(v - bff(vh));
                }
            } else {                            // V -> bf16-rn transposed
                const int vc = gcol - 1024;
                const int h = vc >> 6, d = vc & 63;
                short4v o = {(short)f2bf_rn(acc[fi][bj][0] + bv_),
                             (short)f2bf_rn(acc[fi][bj][1] + bv_),
                             (short)f2bf_rn(acc[fi][bj][2] + bv_),
                             (short)f2bf_rn(acc[fi][bj][3] + bv_)};
                *(short4v*)&Vbf[((size_t)(b * 16 + h) * 64 + d) * 2048 + (r & 2047)] = o;
            }
        }
    }
}

// ---------------------------------------------------------------------------
// Out-proj GEMM, 1-term bf16 (r19-validated).
// ---------------------------------------------------------------------------
__global__ __launch_bounds__(256) void gemm_out_bf(
    const ushort* __restrict__ Obf,
    const ushort* __restrict__ Wot,
    const float* __restrict__ bo,
    float* __restrict__ out)
{
    __shared__ __align__(16) short Ah[128 * 40];
    __shared__ __align__(16) short Bh[128 * 40];

    const int tid = threadIdx.x;
    const int m0 = blockIdx.y * 128, n0 = blockIdx.x * 128;
    const int wid = tid >> 6, wr = wid >> 1, wc = wid & 1;
    const int lane = tid & 63, fr = lane & 15, fq = lane >> 4;
    const int srow = tid >> 1;
    const int skq  = (tid & 1) << 4;

    f32x4 acc[4][4];
    #pragma unroll
    for (int i = 0; i < 4; ++i)
        #pragma unroll
        for (int j = 0; j < 4; ++j)
            acc[i][j] = (f32x4){0.f, 0.f, 0.f, 0.f};

    const ushort* AgH = Obf + (size_t)(m0 + srow) * 1024 + skq;
    const ushort* BgH = Wot + (size_t)(n0 + srow) * 1024 + skq;
    short* pAh = &Ah[srow * 40 + skq];
    short* pBh = &Bh[srow * 40 + skq];

    for (int k0 = 0; k0 < 1024; k0 += 32) {
        *(short8v*)pAh       = *(const short8v*)(AgH + k0);
        *(short8v*)(pAh + 8) = *(const short8v*)(AgH + k0 + 8);
        *(short8v*)pBh       = *(const short8v*)(BgH + k0);
        *(short8v*)(pBh + 8) = *(const short8v*)(BgH + k0 + 8);
        __syncthreads();

        short8v afh[4], bfh[4];
        #pragma unroll
        for (int fi = 0; fi < 4; ++fi)
            afh[fi] = *(const short8v*)&Ah[(wr * 64 + fi * 16 + fr) * 40 + fq * 8];
        #pragma unroll
        for (int bj = 0; bj < 4; ++bj)
            bfh[bj] = *(const short8v*)&Bh[(wc * 64 + bj * 16 + fr) * 40 + fq * 8];
        #pragma unroll
        for (int fi = 0; fi < 4; ++fi)
            #pragma unroll
            for (int bj = 0; bj < 4; ++bj)
                acc[fi][bj] = __builtin_amdgcn_mfma_f32_16x16x32_bf16(
                    afh[fi], bfh[bj], acc[fi][bj], 0, 0, 0);
        __syncthreads();
    }

    #pragma unroll
    for (int fi = 0; fi < 4; ++fi) {
        #pragma unroll
        for (int bj = 0; bj < 4; ++bj) {
            const int r = m0 + wr * 64 + fi * 16 + fq * 4;
            const int c = n0 + wc * 64 + bj * 16 + fr;
            const float bv_ = bo[c];
            #pragma unroll
            for (int j = 0; j < 4; ++j)
                out[(size_t)(r + j) * 1024 + c] = acc[fi][bj][j] + bv_;
        }
    }
}

// ---------------------------------------------------------------------------
// MFMA flash attention v7b (r19-measured: 110 us, WRITE 8 MB) — UNCHANGED.
// ---------------------------------------------------------------------------
#define P_LD  68
#define MASKVAL (-1e30f)

__global__ __launch_bounds__(512) void flash_mfma(
    const float* __restrict__ Yqk,
    const short* __restrict__ Kth, const short* __restrict__ Ktl,
    const short* __restrict__ Vbf,
    ushort* __restrict__ Obf)
{
    const float scale = 0.1767766952966369f;  // 1/sqrt(32)
    const int L = blockIdx.x;
    const int bh = L & 31;
    const int qt = 31 - (L >> 5);
    const int b = bh >> 4, h = bh & 15;
    const int tid = threadIdx.x;
    const int w = tid >> 6;
    const int g = w & 3;
    const int p = w >> 2;
    const int lane = tid & 63;
    const int fr = lane & 15, fq = lane >> 4;

    __shared__ __align__(16) short Pall[8][16 * P_LD];
    __shared__ __align__(16) float ex[4 * 64 * 28];
    short* Pw = &Pall[w][0];

    short8v aqh, aql;
    {
        const float* qp = Yqk + (size_t)(b * SEQ + qt * 64 + g * 16 + fr) * 1024
                          + h * 32 + fq * 8;
        split8(*(const float4*)qp, *(const float4*)(qp + 4), aqh, aql);
    }

    f32x4 acc0 = {0,0,0,0}, acc1 = {0,0,0,0}, acc2 = {0,0,0,0}, acc3 = {0,0,0,0};
    float m_[4], l_[4];
    #pragma unroll
    for (int r = 0; r < 4; ++r) { m_[r] = MASKVAL; l_[r] = 0.f; }

    const short* kb_h = Kth + (size_t)bh * 2048 * 32;
    const short* kb_l = Ktl + (size_t)bh * 2048 * 32;
    const short* vb   = Vbf + (size_t)bh * 64 * 2048;
    const int kidx = fr * 32 + fq * 8;
    const int vrow = fr * 2048 + fq * 8;

    for (int jt = p; jt <= qt; jt += 2) {
        const short* kp_h = kb_h + (size_t)jt * 64 * 32;
        const short* kp_l = kb_l + (size_t)jt * 64 * 32;
        short8v kh0 = *(const short8v*)&kp_h[kidx];
        short8v kh1 = *(const short8v*)&kp_h[kidx + 512];
        short8v kh2 = *(const short8v*)&kp_h[kidx + 1024];
        short8v kh3 = *(const short8v*)&kp_h[kidx + 1536];
        short8v kl0 = *(const short8v*)&kp_l[kidx];
        short8v kl1 = *(const short8v*)&kp_l[kidx + 512];
        short8v kl2 = *(const short8v*)&kp_l[kidx + 1024];
        short8v kl3 = *(const short8v*)&kp_l[kidx + 1536];
        const short* vp = vb + vrow + jt * 64;
        short8v v00 = *(const short8v*)&vp[0];
        short8v v01 = *(const short8v*)&vp[32];
        short8v v10 = *(const short8v*)&vp[16 * 2048];
        short8v v11 = *(const short8v*)&vp[16 * 2048 + 32];
        short8v v20 = *(const short8v*)&vp[32 * 2048];
        short8v v21 = *(const short8v*)&vp[32 * 2048 + 32];
        short8v v30 = *(const short8v*)&vp[48 * 2048];
        short8v v31 = *(const short8v*)&vp[48 * 2048 + 32];

        f32x4 s0 = {0,0,0,0}, s1 = {0,0,0,0}, s2 = {0,0,0,0}, s3 = {0,0,0,0};
        s0 = __builtin_amdgcn_mfma_f32_16x16x32_bf16(aqh, kh0, s0, 0, 0, 0);
        s0 = __builtin_amdgcn_mfma_f32_16x16x32_bf16(aqh, kl0, s0, 0, 0, 0);
        s0 = __builtin_amdgcn_mfma_f32_16x16x32_bf16(aql, kh0, s0, 0, 0, 0);
        s1 = __builtin_amdgcn_mfma_f32_16x16x32_bf16(aqh, kh1, s1, 0, 0, 0);
        s1 = __builtin_amdgcn_mfma_f32_16x16x32_bf16(aqh, kl1, s1, 0, 0, 0);
        s1 = __builtin_amdgcn_mfma_f32_16x16x32_bf16(aql, kh1, s1, 0, 0, 0);
        s2 = __builtin_amdgcn_mfma_f32_16x16x32_bf16(aqh, kh2, s2, 0, 0, 0);
        s2 = __builtin_amdgcn_mfma_f32_16x16x32_bf16(aqh, kl2, s2, 0, 0, 0);
        s2 = __builtin_amdgcn_mfma_f32_16x16x32_bf16(aql, kh2, s2, 0, 0, 0);
        s3 = __builtin_amdgcn_mfma_f32_16x16x32_bf16(aqh, kh3, s3, 0, 0, 0);
        s3 = __builtin_amdgcn_mfma_f32_16x16x32_bf16(aqh, kl3, s3, 0, 0, 0);
        s3 = __builtin_amdgcn_mfma_f32_16x16x32_bf16(aql, kh3, s3, 0, 0, 0);

        s0 *= scale; s1 *= scale; s2 *= scale; s3 *= scale;

        if (jt == qt) {
            #pragma unroll
            for (int r = 0; r < 4; ++r) {
                const int q_l = g * 16 + fq * 4 + r;
                s0[r] = (fr      <= q_l) ? s0[r] : MASKVAL;
                s1[r] = (16 + fr <= q_l) ? s1[r] : MASKVAL;
                s2[r] = (32 + fr <= q_l) ? s2[r] : MASKVAL;
                s3[r] = (48 + fr <= q_l) ? s3[r] : MASKVAL;
            }
        }

        float al[4];
        #pragma unroll
        for (int r = 0; r < 4; ++r) {
            float mt = fmaxf(fmaxf(s0[r], s1[r]), fmaxf(s2[r], s3[r]));
            mt = fmaxf(mt, __shfl_xor(mt, 1));
            mt = fmaxf(mt, __shfl_xor(mt, 2));
            mt = fmaxf(mt, __shfl_xor(mt, 4));
            mt = fmaxf(mt, __shfl_xor(mt, 8));
            const float mnew = fmaxf(m_[r], mt);
            al[r] = __expf(m_[r] - mnew);
            m_[r] = mnew;
            s0[r] = __expf(s0[r] - mnew);
            s1[r] = __expf(s1[r] - mnew);
            s2[r] = __expf(s2[r] - mnew);
            s3[r] = __expf(s3[r] - mnew);
            float ps = s0[r] + s1[r] + s2[r] + s3[r];
            ps += __shfl_xor(ps, 1);
            ps += __shfl_xor(ps, 2);
            ps += __shfl_xor(ps, 4);
            ps += __shfl_xor(ps, 8);
            l_[r] = l_[r] * al[r] + ps;
        }

        #pragma unroll
        for (int r = 0; r < 4; ++r) {
            const int prow = fq * 4 + r;
            Pw[prow * P_LD +      fr] = (short)f2bf_rn(s0[r]);
            Pw[prow * P_LD + 16 + fr] = (short)f2bf_rn(s1[r]);
            Pw[prow * P_LD + 32 + fr] = (short)f2bf_rn(s2[r]);
            Pw[prow * P_LD + 48 + fr] = (short)f2bf_rn(s3[r]);
        }
        #pragma unroll
        for (int r = 0; r < 4; ++r) {
            acc0[r] *= al[r]; acc1[r] *= al[r];
            acc2[r] *= al[r]; acc3[r] *= al[r];
        }
        short8v pa0 = *(const short8v*)&Pw[fr * P_LD + fq * 8];
        short8v pa1 = *(const short8v*)&Pw[fr * P_LD + 32 + fq * 8];

        acc0 = __builtin_amdgcn_mfma_f32_16x16x32_bf16(pa0, v00, acc0, 0, 0, 0);
        acc0 = __builtin_amdgcn_mfma_f32_16x16x32_bf16(pa1, v01, acc0, 0, 0, 0);
        acc1 = __builtin_amdgcn_mfma_f32_16x16x32_bf16(pa0, v10, acc1, 0, 0, 0);
        acc1 = __builtin_amdgcn_mfma_f32_16x16x32_bf16(pa1, v11, acc1, 0, 0, 0);
        acc2 = __builtin_amdgcn_mfma_f32_16x16x32_bf16(pa0, v20, acc2, 0, 0, 0);
        acc2 = __builtin_amdgcn_mfma_f32_16x16x32_bf16(pa1, v21, acc2, 0, 0, 0);
        acc3 = __builtin_amdgcn_mfma_f32_16x16x32_bf16(pa0, v30, acc3, 0, 0, 0);
        acc3 = __builtin_amdgcn_mfma_f32_16x16x32_bf16(pa1, v31, acc3, 0, 0, 0);
    }

    if (p == 1) {
        float* e = ex + ((g << 6) + lane) * 28;
        *(f32x4*)(e +  0) = acc0;
        *(f32x4*)(e +  4) = acc1;
        *(f32x4*)(e +  8) = acc2;
        *(f32x4*)(e + 12) = acc3;
        *(f32x4*)(e + 16) = (f32x4){m_[0], m_[1], m_[2], m_[3]};
        *(f32x4*)(e + 20) = (f32x4){l_[0], l_[1], l_[2], l_[3]};
    }
    __syncthreads();
    if (p == 0) {
        const float* e = ex + ((g << 6) + lane) * 28;
        f32x4 b0 = *(const f32x4*)(e +  0);
        f32x4 b1 = *(const f32x4*)(e +  4);
        f32x4 b2 = *(const f32x4*)(e +  8);
        f32x4 b3 = *(const f32x4*)(e + 12);
        f32x4 m1 = *(const f32x4*)(e + 16);
        f32x4 l1 = *(const f32x4*)(e + 20);
        #pragma unroll
        for (int r = 0; r < 4; ++r) {
            const float mm = fmaxf(m_[r], m1[r]);
            const float a0 = __expf(m_[r] - mm);
            const float a1 = __expf(m1[r] - mm);
            const float inv = 1.f / (l_[r] * a0 + l1[r] * a1);
            const int trow = qt * 64 + g * 16 + fq * 4 + r;
            ushort* op = Obf + (size_t)(b * SEQ + trow) * 1024 + h * 64;
            op[     fr] = f2bf_rn((acc0[r] * a0 + b0[r] * a1) * inv);
            op[16 + fr] = f2bf_rn((acc1[r] * a0 + b1[r] * a1) * inv);
            op[32 + fr] = f2bf_rn((acc2[r] * a0 + b2[r] * a1) * inv);
            op[48 + fr] = f2bf_rn((acc3[r] * a0 + b3[r] * a1) * inv);
        }
    }
}

// ---------------------------------------------------------------------------
extern "C" void kernel_launch(void* const* d_in, const int* in_sizes, int n_in,
                              void* d_out, int out_size, void* d_ws, size_t ws_size,
                              hipStream_t stream)
{
    const float* x      = (const float*)d_in[0];
    const float* Wq     = (const float*)d_in[1];
    const float* bq     = (const float*)d_in[2];
    const float* Wk     = (const float*)d_in[3];
    const float* bk     = (const float*)d_in[4];
    const float* Wv     = (const float*)d_in[5];
    const float* bv     = (const float*)d_in[6];
    const float* Wo     = (const float*)d_in[7];
    const float* bo     = (const float*)d_in[8];
    const float* Wq_lsr = (const float*)d_in[9];
    const float* Wk_lsr = (const float*)d_in[10];
    float* out = (float*)d_out;

    // workspace (~48 MB):
    //  Wcat_t 8 MB (front 2 MB -> Wot after gemm_proj); bcat;
    //  Yqk 16 MB (front 4 MB = Weff_tmp, dead after transpose);
    //  Kth 4 | Ktl 4 | Vbf 8 | Obf 8 MB
    float* ws     = (float*)d_ws;
    float* Wcat_t = ws;                                    // 2M f
    float* bcat   = Wcat_t + (size_t)2048 * 1024;          // 2048 f
    float* Yqk    = bcat + 2048;                           // 4M f
    float* Weff_tmp = Yqk;           // alias (1M f): dead after transpose2
    short* Kth    = (short*)(Yqk + (size_t)M_TOT * 1024);  // 2M s
    short* Ktl    = Kth + (size_t)32 * 2048 * 32;          // 2M s
    short* Vbf    = Ktl + (size_t)32 * 2048 * 32;          // 4M s
    ushort* Obf   = (ushort*)(Vbf + (size_t)32 * 64 * 2048); // 4M us
    ushort* Wot   = (ushort*)Wcat_t; // alias: Wcat_t dead after gemm_proj

    eff_weight2<<<dim3(2048, 2), 256, 0, stream>>>(Wq, Wq_lsr, Wk, Wk_lsr, Weff_tmp);
    eff_bias_kernel<<<8, 256, 0, stream>>>(bq, Wq_lsr, bk, Wk_lsr, bv, bcat);

    transpose2<<<dim3(16, 16, 2), 256, 0, stream>>>(
        Weff_tmp, Wcat_t, Wv, Wcat_t + (size_t)1024 * 1024);

    gemm_proj_fused<<<dim3(16, 32), 256, 0, stream>>>(
        x, Wcat_t, bcat, Yqk, Kth, Ktl, Vbf);

    tsplit_rn1024<<<dim3(16, 16), 256, 0, stream>>>(Wo, Wot);

    flash_mfma<<<1024, 512, 0, stream>>>(Yqk, Kth, Ktl, Vbf, Obf);

    gemm_out_bf<<<dim3(8, 32), 256, 0, stream>>>(Obf, Wot, bo, out);
}

// Round 23
// 215.655 us; speedup vs baseline: 1.2680x; 1.0267x over previous
//
#include <hip/hip_runtime.h>
#include <math.h>

#define D_MODEL 1024
#define N_HEADS 16
#define D_HEAD  64
#define LSR_RANK 32
#define BATCH 2
#define SEQ 2048
#define M_TOT (BATCH*SEQ)

typedef __attribute__((ext_vector_type(8))) short short8v;
typedef __attribute__((ext_vector_type(4))) short short4v;
typedef __attribute__((ext_vector_type(4))) float f32x4;

static __device__ __forceinline__ ushort bfhi(float f) {
    union { float f; unsigned u; } c; c.f = f;
    return (ushort)(c.u >> 16);
}
static __device__ __forceinline__ float bff(ushort h) {
    union { unsigned u; float f; } c; c.u = ((unsigned)h) << 16;
    return c.f;
}
static __device__ __forceinline__ ushort f2bf_rn(float f) {
    union { float f; unsigned u; } c; c.f = f;
    unsigned r = c.u + 0x7FFF + ((c.u >> 16) & 1);
    return (ushort)(r >> 16);
}
static __device__ __forceinline__ void split8(const float4 a, const float4 b,
                                              short8v& h, short8v& l) {
    ushort h0 = bfhi(a.x), h1 = bfhi(a.y), h2 = bfhi(a.z), h3 = bfhi(a.w);
    ushort h4 = bfhi(b.x), h5 = bfhi(b.y), h6 = bfhi(b.z), h7 = bfhi(b.w);
    h[0] = (short)h0; h[1] = (short)h1; h[2] = (short)h2; h[3] = (short)h3;
    h[4] = (short)h4; h[5] = (short)h5; h[6] = (short)h6; h[7] = (short)h7;
    l[0] = (short)bfhi(a.x - bff(h0)); l[1] = (short)bfhi(a.y - bff(h1));
    l[2] = (short)bfhi(a.z - bff(h2)); l[3] = (short)bfhi(a.w - bff(h3));
    l[4] = (short)bfhi(b.x - bff(h4)); l[5] = (short)bfhi(b.y - bff(h5));
    l[6] = (short)bfhi(b.z - bff(h6)); l[7] = (short)bfhi(b.w - bff(h7));
}
static __device__ __forceinline__ void trunc8(const float4 a, const float4 b,
                                              short8v& h) {
    h[0] = (short)bfhi(a.x); h[1] = (short)bfhi(a.y);
    h[2] = (short)bfhi(a.z); h[3] = (short)bfhi(a.w);
    h[4] = (short)bfhi(b.x); h[5] = (short)bfhi(b.y);
    h[6] = (short)bfhi(b.z); h[7] = (short)bfhi(b.w);
}

// ---------------------------------------------------------------------------
// Weff_tmp[k][z*512+c] = sum_d W[k, h*64+d] * Wlsr[h, d, r]  (z=0:Wq, 1:Wk)
// ---------------------------------------------------------------------------
__global__ __launch_bounds__(256) void eff_weight2(
    const float* __restrict__ Wq, const float* __restrict__ Wq_lsr,
    const float* __restrict__ Wk, const float* __restrict__ Wk_lsr,
    float* __restrict__ Weff_tmp)
{
    const int z = blockIdx.y;
    const float* W    = z ? Wk : Wq;
    const float* Wlsr = z ? Wk_lsr : Wq_lsr;
    const int base = z << 9;
    int idx = blockIdx.x * 256 + threadIdx.x;
    int k = idx >> 9;
    int c = idx & 511;
    int h = c >> 5;
    int r = c & 31;
    const float* wrow = W + (size_t)k * D_MODEL + h * D_HEAD;
    const float* lsr  = Wlsr + (size_t)h * D_HEAD * LSR_RANK + r;
    float acc = 0.f;
    #pragma unroll
    for (int d = 0; d < D_HEAD; ++d)
        acc = fmaf(wrow[d], lsr[d * LSR_RANK], acc);
    Weff_tmp[(size_t)k * 1024 + base + c] = acc;
}

__global__ __launch_bounds__(256) void eff_bias_kernel(
    const float* __restrict__ bq, const float* __restrict__ Wq_lsr,
    const float* __restrict__ bk, const float* __restrict__ Wk_lsr,
    const float* __restrict__ bv, float* __restrict__ bcat)
{
    int c = blockIdx.x * 256 + threadIdx.x;
    if (c < 1024) {
        const float* bias = (c < 512) ? bq : bk;
        const float* lsr  = (c < 512) ? Wq_lsr : Wk_lsr;
        int cc = c & 511;
        int h = cc >> 5, r = cc & 31;
        float acc = 0.f;
        #pragma unroll
        for (int d = 0; d < D_HEAD; ++d)
            acc = fmaf(bias[h * D_HEAD + d],
                       lsr[(size_t)h * D_HEAD * LSR_RANK + d * LSR_RANK + r], acc);
        bcat[c] = acc;
    } else {
        bcat[c] = bv[c - 1024];
    }
}

// ---------------------------------------------------------------------------
// Dual 1024x1024 fp32 transpose: z=0: in0->out0, z=1: in1->out1.
// ---------------------------------------------------------------------------
__global__ __launch_bounds__(256) void transpose2(
    const float* __restrict__ in0, float* __restrict__ out0,
    const float* __restrict__ in1, float* __restrict__ out1)
{
    const float* in  = blockIdx.z ? in1 : in0;
    float* out       = blockIdx.z ? out1 : out0;
    __shared__ float t[64][65];
    const int tid = threadIdx.x;
    const int r0 = blockIdx.y * 64, c0 = blockIdx.x * 64;
    const int tr = tid >> 4, tc = tid & 15;
    #pragma unroll
    for (int i = 0; i < 4; ++i) {
        float4 v = *(const float4*)&in[(size_t)(r0 + tr + i * 16) * 1024 + c0 + tc * 4];
        t[tr + i * 16][tc * 4 + 0] = v.x;
        t[tr + i * 16][tc * 4 + 1] = v.y;
        t[tr + i * 16][tc * 4 + 2] = v.z;
        t[tr + i * 16][tc * 4 + 3] = v.w;
    }
    __syncthreads();
    #pragma unroll
    for (int i = 0; i < 4; ++i) {
        float4 v;
        v.x = t[tc * 4 + 0][tr + i * 16];
        v.y = t[tc * 4 + 1][tr + i * 16];
        v.z = t[tc * 4 + 2][tr + i * 16];
        v.w = t[tc * 4 + 3][tr + i * 16];
        *(float4*)&out[(size_t)(c0 + tr + i * 16) * 1024 + r0 + tc * 4] = v;
    }
}

// ---------------------------------------------------------------------------
// Transpose + bf16-rn: Wo[1024][1024] fp32 -> Wot transposed bf16.
// ---------------------------------------------------------------------------
__global__ __launch_bounds__(256) void tsplit_rn1024(
    const float* __restrict__ in, ushort* __restrict__ out)
{
    __shared__ float t[64][65];
    const int tid = threadIdx.x;
    const int r0 = blockIdx.y * 64, c0 = blockIdx.x * 64;
    const int tr = tid >> 4, tc = tid & 15;
    #pragma unroll
    for (int i = 0; i < 4; ++i) {
        float4 v = *(const float4*)&in[(size_t)(r0 + tr + i * 16) * 1024 + c0 + tc * 4];
        t[tr + i * 16][tc * 4 + 0] = v.x;
        t[tr + i * 16][tc * 4 + 1] = v.y;
        t[tr + i * 16][tc * 4 + 2] = v.z;
        t[tr + i * 16][tc * 4 + 3] = v.w;
    }
    __syncthreads();
    #pragma unroll
    for (int i = 0; i < 4; ++i) {
        short4v hv = {(short)f2bf_rn(t[tc * 4 + 0][tr + i * 16]),
                      (short)f2bf_rn(t[tc * 4 + 1][tr + i * 16]),
                      (short)f2bf_rn(t[tc * 4 + 2][tr + i * 16]),
                      (short)f2bf_rn(t[tc * 4 + 3][tr + i * 16])};
        *(short4v*)&out[(size_t)(c0 + tr + i * 16) * 1024 + r0 + tc * 4] = hv;
    }
}

// ---------------------------------------------------------------------------
// Fused projection GEMM (r22-measured-good) — UNCHANGED.
// ---------------------------------------------------------------------------
__global__ __launch_bounds__(256) void gemm_proj_fused(
    const float* __restrict__ x,
    const float* __restrict__ Wcat_t,
    const float* __restrict__ bcat,
    float* __restrict__ Yqk,
    short* __restrict__ Kth, short* __restrict__ Ktl,
    short* __restrict__ Vbf)
{
    __shared__ __align__(16) short Ah[128 * 40], Al[128 * 40];
    __shared__ __align__(16) short Bh[128 * 40], Bl[128 * 40];

    const int tid = threadIdx.x;
    const int bx = blockIdx.x;
    const int m0 = blockIdx.y * 128, n0 = bx * 128;
    const bool vhalf = (bx >= 8);
    const int wid = tid >> 6, wr = wid >> 1, wc = wid & 1;
    const int lane = tid & 63, fr = lane & 15, fq = lane >> 4;
    const int srow = tid >> 1;
    const int skq  = (tid & 1) << 4;

    f32x4 acc[4][4];
    #pragma unroll
    for (int i = 0; i < 4; ++i)
        #pragma unroll
        for (int j = 0; j < 4; ++j)
            acc[i][j] = (f32x4){0.f, 0.f, 0.f, 0.f};

    const float* Ag = x + (size_t)(m0 + srow) * 1024 + skq;
    const float* Bg = Wcat_t + (size_t)(n0 + srow) * 1024 + skq;
    short* pAh = &Ah[srow * 40 + skq];
    short* pAl = &Al[srow * 40 + skq];
    short* pBh = &Bh[srow * 40 + skq];
    short* pBl = &Bl[srow * 40 + skq];

    for (int k0 = 0; k0 < 1024; k0 += 32) {
        float4 a0 = *(const float4*)(Ag + k0);
        float4 a1 = *(const float4*)(Ag + k0 + 4);
        float4 a2 = *(const float4*)(Ag + k0 + 8);
        float4 a3 = *(const float4*)(Ag + k0 + 12);
        float4 b0 = *(const float4*)(Bg + k0);
        float4 b1 = *(const float4*)(Bg + k0 + 4);
        float4 b2 = *(const float4*)(Bg + k0 + 8);
        float4 b3 = *(const float4*)(Bg + k0 + 12);
        if (vhalf) {
            short8v h;
            trunc8(a0, a1, h); *(short8v*)pAh = h;
            trunc8(a2, a3, h); *(short8v*)(pAh + 8) = h;
            trunc8(b0, b1, h); *(short8v*)pBh = h;
            trunc8(b2, b3, h); *(short8v*)(pBh + 8) = h;
        } else {
            short8v h, l;
            split8(a0, a1, h, l);
            *(short8v*)pAh = h;  *(short8v*)pAl = l;
            split8(a2, a3, h, l);
            *(short8v*)(pAh + 8) = h;  *(short8v*)(pAl + 8) = l;
            split8(b0, b1, h, l);
            *(short8v*)pBh = h;  *(short8v*)pBl = l;
            split8(b2, b3, h, l);
            *(short8v*)(pBh + 8) = h;  *(short8v*)(pBl + 8) = l;
        }
        __syncthreads();

        short8v afh[4], bfh[4];
        #pragma unroll
        for (int fi = 0; fi < 4; ++fi)
            afh[fi] = *(const short8v*)&Ah[(wr * 64 + fi * 16 + fr) * 40 + fq * 8];
        #pragma unroll
        for (int bj = 0; bj < 4; ++bj)
            bfh[bj] = *(const short8v*)&Bh[(wc * 64 + bj * 16 + fr) * 40 + fq * 8];

        if (vhalf) {
            #pragma unroll
            for (int fi = 0; fi < 4; ++fi)
                #pragma unroll
                for (int bj = 0; bj < 4; ++bj)
                    acc[fi][bj] = __builtin_amdgcn_mfma_f32_16x16x32_bf16(
                        afh[fi], bfh[bj], acc[fi][bj], 0, 0, 0);
        } else {
            short8v afl[4], bfl[4];
            #pragma unroll
            for (int fi = 0; fi < 4; ++fi)
                afl[fi] = *(const short8v*)&Al[(wr * 64 + fi * 16 + fr) * 40 + fq * 8];
            #pragma unroll
            for (int bj = 0; bj < 4; ++bj)
                bfl[bj] = *(const short8v*)&Bl[(wc * 64 + bj * 16 + fr) * 40 + fq * 8];
            #pragma unroll
            for (int fi = 0; fi < 4; ++fi) {
                #pragma unroll
                for (int bj = 0; bj < 4; ++bj) {
                    acc[fi][bj] = __builtin_amdgcn_mfma_f32_16x16x32_bf16(
                        afh[fi], bfh[bj], acc[fi][bj], 0, 0, 0);
                    acc[fi][bj] = __builtin_amdgcn_mfma_f32_16x16x32_bf16(
                        afh[fi], bfl[bj], acc[fi][bj], 0, 0, 0);
                    acc[fi][bj] = __builtin_amdgcn_mfma_f32_16x16x32_bf16(
                        afl[fi], bfh[bj], acc[fi][bj], 0, 0, 0);
                }
            }
        }
        __syncthreads();
    }

    const int b = m0 >> 11;
    #pragma unroll
    for (int fi = 0; fi < 4; ++fi) {
        #pragma unroll
        for (int bj = 0; bj < 4; ++bj) {
            const int r = m0 + wr * 64 + fi * 16 + fq * 4;
            const int gcol = n0 + wc * 64 + bj * 16 + fr;
            const float bv_ = bcat[gcol];
            if (bx < 4) {
                #pragma unroll
                for (int j = 0; j < 4; ++j)
                    Yqk[(size_t)(r + j) * 1024 + gcol] = acc[fi][bj][j] + bv_;
            } else if (bx < 8) {
                const int kc = gcol - 512;
                const int h = kc >> 5, rr = kc & 31;
                short* oh = Kth + (((size_t)(b * 16 + h) * 2048) + (r & 2047)) * 32 + rr;
                short* ol = Ktl + (((size_t)(b * 16 + h) * 2048) + (r & 2047)) * 32 + rr;
                #pragma unroll
                for (int j = 0; j < 4; ++j) {
                    const float v = acc[fi][bj][j] + bv_;
                    const ushort vh = bfhi(v);
                    oh[j * 32] = (short)vh;
                    ol[j * 32] = (short)bfhi(v - bff(vh));
                }
            } else {
                const int vc = gcol - 1024;
                const int h = vc >> 6, d = vc & 63;
                short4v o = {(short)f2bf_rn(acc[fi][bj][0] + bv_),
                             (short)f2bf_rn(acc[fi][bj][1] + bv_),
                             (short)f2bf_rn(acc[fi][bj][2] + bv_),
                             (short)f2bf_rn(acc[fi][bj][3] + bv_)};
                *(short4v*)&Vbf[((size_t)(b * 16 + h) * 64 + d) * 2048 + (r & 2047)] = o;
            }
        }
    }
}

// ---------------------------------------------------------------------------
// Out-proj GEMM, 1-term bf16 (r19-validated) — UNCHANGED.
// ---------------------------------------------------------------------------
__global__ __launch_bounds__(256) void gemm_out_bf(
    const ushort* __restrict__ Obf,
    const ushort* __restrict__ Wot,
    const float* __restrict__ bo,
    float* __restrict__ out)
{
    __shared__ __align__(16) short Ah[128 * 40];
    __shared__ __align__(16) short Bh[128 * 40];

    const int tid = threadIdx.x;
    const int m0 = blockIdx.y * 128, n0 = blockIdx.x * 128;
    const int wid = tid >> 6, wr = wid >> 1, wc = wid & 1;
    const int lane = tid & 63, fr = lane & 15, fq = lane >> 4;
    const int srow = tid >> 1;
    const int skq  = (tid & 1) << 4;

    f32x4 acc[4][4];
    #pragma unroll
    for (int i = 0; i < 4; ++i)
        #pragma unroll
        for (int j = 0; j < 4; ++j)
            acc[i][j] = (f32x4){0.f, 0.f, 0.f, 0.f};

    const ushort* AgH = Obf + (size_t)(m0 + srow) * 1024 + skq;
    const ushort* BgH = Wot + (size_t)(n0 + srow) * 1024 + skq;
    short* pAh = &Ah[srow * 40 + skq];
    short* pBh = &Bh[srow * 40 + skq];

    for (int k0 = 0; k0 < 1024; k0 += 32) {
        *(short8v*)pAh       = *(const short8v*)(AgH + k0);
        *(short8v*)(pAh + 8) = *(const short8v*)(AgH + k0 + 8);
        *(short8v*)pBh       = *(const short8v*)(BgH + k0);
        *(short8v*)(pBh + 8) = *(const short8v*)(BgH + k0 + 8);
        __syncthreads();

        short8v afh[4], bfh[4];
        #pragma unroll
        for (int fi = 0; fi < 4; ++fi)
            afh[fi] = *(const short8v*)&Ah[(wr * 64 + fi * 16 + fr) * 40 + fq * 8];
        #pragma unroll
        for (int bj = 0; bj < 4; ++bj)
            bfh[bj] = *(const short8v*)&Bh[(wc * 64 + bj * 16 + fr) * 40 + fq * 8];
        #pragma unroll
        for (int fi = 0; fi < 4; ++fi)
            #pragma unroll
            for (int bj = 0; bj < 4; ++bj)
                acc[fi][bj] = __builtin_amdgcn_mfma_f32_16x16x32_bf16(
                    afh[fi], bfh[bj], acc[fi][bj], 0, 0, 0);
        __syncthreads();
    }

    #pragma unroll
    for (int fi = 0; fi < 4; ++fi) {
        #pragma unroll
        for (int bj = 0; bj < 4; ++bj) {
            const int r = m0 + wr * 64 + fi * 16 + fq * 4;
            const int c = n0 + wc * 64 + bj * 16 + fr;
            const float bv_ = bo[c];
            #pragma unroll
            for (int j = 0; j < 4; ++j)
                out[(size_t)(r + j) * 1024 + c] = acc[fi][bj][j] + bv_;
        }
    }
}

// ---------------------------------------------------------------------------
// MFMA flash attention v8 = v7b with COMPACT bf16 exchange buffer.
// r22 diagnosis: Occupancy 39% != the 75% that 46080B LDS should allow ->
// runtime LDS granularity caps residency at ~2 blocks/CU. Fix: store the
// p=1 partial accumulators in the exchange as bf16 (output is bf16 anyway;
// adds <0.4% on half the contribution). ex: 28672 -> 20480B; total LDS
// 46080 -> 37888B -> 4 blocks/CU x 8 waves = 32 waves/CU cap, and grid
// 1024 = exactly 4 x 256 CUs (zero drain). Loop body unchanged.
// ---------------------------------------------------------------------------
#define P_LD  68
#define MASKVAL (-1e30f)

__global__ __launch_bounds__(512) void flash_mfma(
    const float* __restrict__ Yqk,
    const short* __restrict__ Kth, const short* __restrict__ Ktl,
    const short* __restrict__ Vbf,
    ushort* __restrict__ Obf)
{
    const float scale = 0.1767766952966369f;  // 1/sqrt(32)
    const int L = blockIdx.x;
    const int bh = L & 31;
    const int qt = 31 - (L >> 5);
    const int b = bh >> 4, h = bh & 15;
    const int tid = threadIdx.x;
    const int w = tid >> 6;
    const int g = w & 3;
    const int p = w >> 2;
    const int lane = tid & 63;
    const int fr = lane & 15, fq = lane >> 4;

    __shared__ __align__(16) short Pall[8][16 * P_LD];        // 17408 B
    __shared__ __align__(16) char exraw[4 * 64 * 80];         // 20480 B
    short* Pw = &Pall[w][0];

    short8v aqh, aql;
    {
        const float* qp = Yqk + (size_t)(b * SEQ + qt * 64 + g * 16 + fr) * 1024
                          + h * 32 + fq * 8;
        split8(*(const float4*)qp, *(const float4*)(qp + 4), aqh, aql);
    }

    f32x4 acc0 = {0,0,0,0}, acc1 = {0,0,0,0}, acc2 = {0,0,0,0}, acc3 = {0,0,0,0};
    float m_[4], l_[4];
    #pragma unroll
    for (int r = 0; r < 4; ++r) { m_[r] = MASKVAL; l_[r] = 0.f; }

    const short* kb_h = Kth + (size_t)bh * 2048 * 32;
    const short* kb_l = Ktl + (size_t)bh * 2048 * 32;
    const short* vb   = Vbf + (size_t)bh * 64 * 2048;
    const int kidx = fr * 32 + fq * 8;
    const int vrow = fr * 2048 + fq * 8;

    for (int jt = p; jt <= qt; jt += 2) {
        const short* kp_h = kb_h + (size_t)jt * 64 * 32;
        const short* kp_l = kb_l + (size_t)jt * 64 * 32;
        short8v kh0 = *(const short8v*)&kp_h[kidx];
        short8v kh1 = *(const short8v*)&kp_h[kidx + 512];
        short8v kh2 = *(const short8v*)&kp_h[kidx + 1024];
        short8v kh3 = *(const short8v*)&kp_h[kidx + 1536];
        short8v kl0 = *(const short8v*)&kp_l[kidx];
        short8v kl1 = *(const short8v*)&kp_l[kidx + 512];
        short8v kl2 = *(const short8v*)&kp_l[kidx + 1024];
        short8v kl3 = *(const short8v*)&kp_l[kidx + 1536];
        const short* vp = vb + vrow + jt * 64;
        short8v v00 = *(const short8v*)&vp[0];
        short8v v01 = *(const short8v*)&vp[32];
        short8v v10 = *(const short8v*)&vp[16 * 2048];
        short8v v11 = *(const short8v*)&vp[16 * 2048 + 32];
        short8v v20 = *(const short8v*)&vp[32 * 2048];
        short8v v21 = *(const short8v*)&vp[32 * 2048 + 32];
        short8v v30 = *(const short8v*)&vp[48 * 2048];
        short8v v31 = *(const short8v*)&vp[48 * 2048 + 32];

        f32x4 s0 = {0,0,0,0}, s1 = {0,0,0,0}, s2 = {0,0,0,0}, s3 = {0,0,0,0};
        s0 = __builtin_amdgcn_mfma_f32_16x16x32_bf16(aqh, kh0, s0, 0, 0, 0);
        s0 = __builtin_amdgcn_mfma_f32_16x16x32_bf16(aqh, kl0, s0, 0, 0, 0);
        s0 = __builtin_amdgcn_mfma_f32_16x16x32_bf16(aql, kh0, s0, 0, 0, 0);
        s1 = __builtin_amdgcn_mfma_f32_16x16x32_bf16(aqh, kh1, s1, 0, 0, 0);
        s1 = __builtin_amdgcn_mfma_f32_16x16x32_bf16(aqh, kl1, s1, 0, 0, 0);
        s1 = __builtin_amdgcn_mfma_f32_16x16x32_bf16(aql, kh1, s1, 0, 0, 0);
        s2 = __builtin_amdgcn_mfma_f32_16x16x32_bf16(aqh, kh2, s2, 0, 0, 0);
        s2 = __builtin_amdgcn_mfma_f32_16x16x32_bf16(aqh, kl2, s2, 0, 0, 0);
        s2 = __builtin_amdgcn_mfma_f32_16x16x32_bf16(aql, kh2, s2, 0, 0, 0);
        s3 = __builtin_amdgcn_mfma_f32_16x16x32_bf16(aqh, kh3, s3, 0, 0, 0);
        s3 = __builtin_amdgcn_mfma_f32_16x16x32_bf16(aqh, kl3, s3, 0, 0, 0);
        s3 = __builtin_amdgcn_mfma_f32_16x16x32_bf16(aql, kh3, s3, 0, 0, 0);

        s0 *= scale; s1 *= scale; s2 *= scale; s3 *= scale;

        if (jt == qt) {
            #pragma unroll
            for (int r = 0; r < 4; ++r) {
                const int q_l = g * 16 + fq * 4 + r;
                s0[r] = (fr      <= q_l) ? s0[r] : MASKVAL;
                s1[r] = (16 + fr <= q_l) ? s1[r] : MASKVAL;
                s2[r] = (32 + fr <= q_l) ? s2[r] : MASKVAL;
                s3[r] = (48 + fr <= q_l) ? s3[r] : MASKVAL;
            }
        }

        float al[4];
        #pragma unroll
        for (int r = 0; r < 4; ++r) {
            float mt = fmaxf(fmaxf(s0[r], s1[r]), fmaxf(s2[r], s3[r]));
            mt = fmaxf(mt, __shfl_xor(mt, 1));
            mt = fmaxf(mt, __shfl_xor(mt, 2));
            mt = fmaxf(mt, __shfl_xor(mt, 4));
            mt = fmaxf(mt, __shfl_xor(mt, 8));
            const float mnew = fmaxf(m_[r], mt);
            al[r] = __expf(m_[r] - mnew);
            m_[r] = mnew;
            s0[r] = __expf(s0[r] - mnew);
            s1[r] = __expf(s1[r] - mnew);
            s2[r] = __expf(s2[r] - mnew);
            s3[r] = __expf(s3[r] - mnew);
            float ps = s0[r] + s1[r] + s2[r] + s3[r];
            ps += __shfl_xor(ps, 1);
            ps += __shfl_xor(ps, 2);
            ps += __shfl_xor(ps, 4);
            ps += __shfl_xor(ps, 8);
            l_[r] = l_[r] * al[r] + ps;
        }

        #pragma unroll
        for (int r = 0; r < 4; ++r) {
            const int prow = fq * 4 + r;
            Pw[prow * P_LD +      fr] = (short)f2bf_rn(s0[r]);
            Pw[prow * P_LD + 16 + fr] = (short)f2bf_rn(s1[r]);
            Pw[prow * P_LD + 32 + fr] = (short)f2bf_rn(s2[r]);
            Pw[prow * P_LD + 48 + fr] = (short)f2bf_rn(s3[r]);
        }
        #pragma unroll
        for (int r = 0; r < 4; ++r) {
            acc0[r] *= al[r]; acc1[r] *= al[r];
            acc2[r] *= al[r]; acc3[r] *= al[r];
        }
        short8v pa0 = *(const short8v*)&Pw[fr * P_LD + fq * 8];
        short8v pa1 = *(const short8v*)&Pw[fr * P_LD + 32 + fq * 8];

        acc0 = __builtin_amdgcn_mfma_f32_16x16x32_bf16(pa0, v00, acc0, 0, 0, 0);
        acc0 = __builtin_amdgcn_mfma_f32_16x16x32_bf16(pa1, v01, acc0, 0, 0, 0);
        acc1 = __builtin_amdgcn_mfma_f32_16x16x32_bf16(pa0, v10, acc1, 0, 0, 0);
        acc1 = __builtin_amdgcn_mfma_f32_16x16x32_bf16(pa1, v11, acc1, 0, 0, 0);
        acc2 = __builtin_amdgcn_mfma_f32_16x16x32_bf16(pa0, v20, acc2, 0, 0, 0);
        acc2 = __builtin_amdgcn_mfma_f32_16x16x32_bf16(pa1, v21, acc2, 0, 0, 0);
        acc3 = __builtin_amdgcn_mfma_f32_16x16x32_bf16(pa0, v30, acc3, 0, 0, 0);
        acc3 = __builtin_amdgcn_mfma_f32_16x16x32_bf16(pa1, v31, acc3, 0, 0, 0);
    }

    // ---- parity merge: p=1 publishes (accs as bf16), p=0 combines ----
    char* e = exraw + (size_t)(((g << 6) + lane) * 80);
    if (p == 1) {
        short8v a01, a23;
        a01[0] = (short)f2bf_rn(acc0[0]); a01[1] = (short)f2bf_rn(acc0[1]);
        a01[2] = (short)f2bf_rn(acc0[2]); a01[3] = (short)f2bf_rn(acc0[3]);
        a01[4] = (short)f2bf_rn(acc1[0]); a01[5] = (short)f2bf_rn(acc1[1]);
        a01[6] = (short)f2bf_rn(acc1[2]); a01[7] = (short)f2bf_rn(acc1[3]);
        a23[0] = (short)f2bf_rn(acc2[0]); a23[1] = (short)f2bf_rn(acc2[1]);
        a23[2] = (short)f2bf_rn(acc2[2]); a23[3] = (short)f2bf_rn(acc2[3]);
        a23[4] = (short)f2bf_rn(acc3[0]); a23[5] = (short)f2bf_rn(acc3[1]);
        a23[6] = (short)f2bf_rn(acc3[2]); a23[7] = (short)f2bf_rn(acc3[3]);
        *(short8v*)(e)      = a01;
        *(short8v*)(e + 16) = a23;
        *(f32x4*)(e + 32) = (f32x4){m_[0], m_[1], m_[2], m_[3]};
        *(f32x4*)(e + 48) = (f32x4){l_[0], l_[1], l_[2], l_[3]};
    }
    __syncthreads();
    if (p == 0) {
        short8v a01 = *(const short8v*)(e);
        short8v a23 = *(const short8v*)(e + 16);
        f32x4 m1 = *(const f32x4*)(e + 32);
        f32x4 l1 = *(const f32x4*)(e + 48);
        #pragma unroll
        for (int r = 0; r < 4; ++r) {
            const float mm = fmaxf(m_[r], m1[r]);
            const float a0 = __expf(m_[r] - mm);
            const float a1 = __expf(m1[r] - mm);
            const float inv = 1.f / (l_[r] * a0 + l1[r] * a1);
            const float b0 = bff((ushort)a01[r]);
            const float b1 = bff((ushort)a01[4 + r]);
            const float b2 = bff((ushort)a23[r]);
            const float b3 = bff((ushort)a23[4 + r]);
            const int trow = qt * 64 + g * 16 + fq * 4 + r;
            ushort* op = Obf + (size_t)(b * SEQ + trow) * 1024 + h * 64;
            op[     fr] = f2bf_rn((acc0[r] * a0 + b0 * a1) * inv);
            op[16 + fr] = f2bf_rn((acc1[r] * a0 + b1 * a1) * inv);
            op[32 + fr] = f2bf_rn((acc2[r] * a0 + b2 * a1) * inv);
            op[48 + fr] = f2bf_rn((acc3[r] * a0 + b3 * a1) * inv);
        }
    }
}

// ---------------------------------------------------------------------------
extern "C" void kernel_launch(void* const* d_in, const int* in_sizes, int n_in,
                              void* d_out, int out_size, void* d_ws, size_t ws_size,
                              hipStream_t stream)
{
    const float* x      = (const float*)d_in[0];
    const float* Wq     = (const float*)d_in[1];
    const float* bq     = (const float*)d_in[2];
    const float* Wk     = (const float*)d_in[3];
    const float* bk     = (const float*)d_in[4];
    const float* Wv     = (const float*)d_in[5];
    const float* bv     = (const float*)d_in[6];
    const float* Wo     = (const float*)d_in[7];
    const float* bo     = (const float*)d_in[8];
    const float* Wq_lsr = (const float*)d_in[9];
    const float* Wk_lsr = (const float*)d_in[10];
    float* out = (float*)d_out;

    float* ws     = (float*)d_ws;
    float* Wcat_t = ws;
    float* bcat   = Wcat_t + (size_t)2048 * 1024;
    float* Yqk    = bcat + 2048;
    float* Weff_tmp = Yqk;
    short* Kth    = (short*)(Yqk + (size_t)M_TOT * 1024);
    short* Ktl    = Kth + (size_t)32 * 2048 * 32;
    short* Vbf    = Ktl + (size_t)32 * 2048 * 32;
    ushort* Obf   = (ushort*)(Vbf + (size_t)32 * 64 * 2048);
    ushort* Wot   = (ushort*)Wcat_t;

    eff_weight2<<<dim3(2048, 2), 256, 0, stream>>>(Wq, Wq_lsr, Wk, Wk_lsr, Weff_tmp);
    eff_bias_kernel<<<8, 256, 0, stream>>>(bq, Wq_lsr, bk, Wk_lsr, bv, bcat);

    transpose2<<<dim3(16, 16, 2), 256, 0, stream>>>(
        Weff_tmp, Wcat_t, Wv, Wcat_t + (size_t)1024 * 1024);

    gemm_proj_fused<<<dim3(16, 32), 256, 0, stream>>>(
        x, Wcat_t, bcat, Yqk, Kth, Ktl, Vbf);

    tsplit_rn1024<<<dim3(16, 16), 256, 0, stream>>>(Wo, Wot);

    flash_mfma<<<1024, 512, 0, stream>>>(Yqk, Kth, Ktl, Vbf, Obf);

    gemm_out_bf<<<dim3(8, 32), 256, 0, stream>>>(Obf, Wot, bo, out);
}

// Round 24
// 215.631 us; speedup vs baseline: 1.2681x; 1.0001x over previous
//
#include <hip/hip_runtime.h>
#include <math.h>

#define D_MODEL 1024
#define N_HEADS 16
#define D_HEAD  64
#define LSR_RANK 32
#define BATCH 2
#define SEQ 2048
#define M_TOT (BATCH*SEQ)

typedef __attribute__((ext_vector_type(8))) short short8v;
typedef __attribute__((ext_vector_type(4))) short short4v;
typedef __attribute__((ext_vector_type(4))) float f32x4;

static __device__ __forceinline__ ushort bfhi(float f) {
    union { float f; unsigned u; } c; c.f = f;
    return (ushort)(c.u >> 16);
}
static __device__ __forceinline__ float bff(ushort h) {
    union { unsigned u; float f; } c; c.u = ((unsigned)h) << 16;
    return c.f;
}
static __device__ __forceinline__ ushort f2bf_rn(float f) {
    union { float f; unsigned u; } c; c.f = f;
    unsigned r = c.u + 0x7FFF + ((c.u >> 16) & 1);
    return (ushort)(r >> 16);
}
static __device__ __forceinline__ void split8(const float4 a, const float4 b,
                                              short8v& h, short8v& l) {
    ushort h0 = bfhi(a.x), h1 = bfhi(a.y), h2 = bfhi(a.z), h3 = bfhi(a.w);
    ushort h4 = bfhi(b.x), h5 = bfhi(b.y), h6 = bfhi(b.z), h7 = bfhi(b.w);
    h[0] = (short)h0; h[1] = (short)h1; h[2] = (short)h2; h[3] = (short)h3;
    h[4] = (short)h4; h[5] = (short)h5; h[6] = (short)h6; h[7] = (short)h7;
    l[0] = (short)bfhi(a.x - bff(h0)); l[1] = (short)bfhi(a.y - bff(h1));
    l[2] = (short)bfhi(a.z - bff(h2)); l[3] = (short)bfhi(a.w - bff(h3));
    l[4] = (short)bfhi(b.x - bff(h4)); l[5] = (short)bfhi(b.y - bff(h5));
    l[6] = (short)bfhi(b.z - bff(h6)); l[7] = (short)bfhi(b.w - bff(h7));
}
static __device__ __forceinline__ void trunc8(const float4 a, const float4 b,
                                              short8v& h) {
    h[0] = (short)bfhi(a.x); h[1] = (short)bfhi(a.y);
    h[2] = (short)bfhi(a.z); h[3] = (short)bfhi(a.w);
    h[4] = (short)bfhi(b.x); h[5] = (short)bfhi(b.y);
    h[6] = (short)bfhi(b.z); h[7] = (short)bfhi(b.w);
}

// ---------------------------------------------------------------------------
// Weff_tmp[k][z*512+c] = sum_d W[k, h*64+d] * Wlsr[h, d, r]  (z=0:Wq, 1:Wk)
// ---------------------------------------------------------------------------
__global__ __launch_bounds__(256) void eff_weight2(
    const float* __restrict__ Wq, const float* __restrict__ Wq_lsr,
    const float* __restrict__ Wk, const float* __restrict__ Wk_lsr,
    float* __restrict__ Weff_tmp)
{
    const int z = blockIdx.y;
    const float* W    = z ? Wk : Wq;
    const float* Wlsr = z ? Wk_lsr : Wq_lsr;
    const int base = z << 9;
    int idx = blockIdx.x * 256 + threadIdx.x;
    int k = idx >> 9;
    int c = idx & 511;
    int h = c >> 5;
    int r = c & 31;
    const float* wrow = W + (size_t)k * D_MODEL + h * D_HEAD;
    const float* lsr  = Wlsr + (size_t)h * D_HEAD * LSR_RANK + r;
    float acc = 0.f;
    #pragma unroll
    for (int d = 0; d < D_HEAD; ++d)
        acc = fmaf(wrow[d], lsr[d * LSR_RANK], acc);
    Weff_tmp[(size_t)k * 1024 + base + c] = acc;
}

__global__ __launch_bounds__(256) void eff_bias_kernel(
    const float* __restrict__ bq, const float* __restrict__ Wq_lsr,
    const float* __restrict__ bk, const float* __restrict__ Wk_lsr,
    const float* __restrict__ bv, float* __restrict__ bcat)
{
    int c = blockIdx.x * 256 + threadIdx.x;
    if (c < 1024) {
        const float* bias = (c < 512) ? bq : bk;
        const float* lsr  = (c < 512) ? Wq_lsr : Wk_lsr;
        int cc = c & 511;
        int h = cc >> 5, r = cc & 31;
        float acc = 0.f;
        #pragma unroll
        for (int d = 0; d < D_HEAD; ++d)
            acc = fmaf(bias[h * D_HEAD + d],
                       lsr[(size_t)h * D_HEAD * LSR_RANK + d * LSR_RANK + r], acc);
        bcat[c] = acc;
    } else {
        bcat[c] = bv[c - 1024];
    }
}

// ---------------------------------------------------------------------------
// Dual 1024x1024 fp32 transpose: z=0: in0->out0, z=1: in1->out1.
// ---------------------------------------------------------------------------
__global__ __launch_bounds__(256) void transpose2(
    const float* __restrict__ in0, float* __restrict__ out0,
    const float* __restrict__ in1, float* __restrict__ out1)
{
    const float* in  = blockIdx.z ? in1 : in0;
    float* out       = blockIdx.z ? out1 : out0;
    __shared__ float t[64][65];
    const int tid = threadIdx.x;
    const int r0 = blockIdx.y * 64, c0 = blockIdx.x * 64;
    const int tr = tid >> 4, tc = tid & 15;
    #pragma unroll
    for (int i = 0; i < 4; ++i) {
        float4 v = *(const float4*)&in[(size_t)(r0 + tr + i * 16) * 1024 + c0 + tc * 4];
        t[tr + i * 16][tc * 4 + 0] = v.x;
        t[tr + i * 16][tc * 4 + 1] = v.y;
        t[tr + i * 16][tc * 4 + 2] = v.z;
        t[tr + i * 16][tc * 4 + 3] = v.w;
    }
    __syncthreads();
    #pragma unroll
    for (int i = 0; i < 4; ++i) {
        float4 v;
        v.x = t[tc * 4 + 0][tr + i * 16];
        v.y = t[tc * 4 + 1][tr + i * 16];
        v.z = t[tc * 4 + 2][tr + i * 16];
        v.w = t[tc * 4 + 3][tr + i * 16];
        *(float4*)&out[(size_t)(c0 + tr + i * 16) * 1024 + r0 + tc * 4] = v;
    }
}

// ---------------------------------------------------------------------------
// Transpose + bf16-rn: Wo[1024][1024] fp32 -> Wot transposed bf16.
// ---------------------------------------------------------------------------
__global__ __launch_bounds__(256) void tsplit_rn1024(
    const float* __restrict__ in, ushort* __restrict__ out)
{
    __shared__ float t[64][65];
    const int tid = threadIdx.x;
    const int r0 = blockIdx.y * 64, c0 = blockIdx.x * 64;
    const int tr = tid >> 4, tc = tid & 15;
    #pragma unroll
    for (int i = 0; i < 4; ++i) {
        float4 v = *(const float4*)&in[(size_t)(r0 + tr + i * 16) * 1024 + c0 + tc * 4];
        t[tr + i * 16][tc * 4 + 0] = v.x;
        t[tr + i * 16][tc * 4 + 1] = v.y;
        t[tr + i * 16][tc * 4 + 2] = v.z;
        t[tr + i * 16][tc * 4 + 3] = v.w;
    }
    __syncthreads();
    #pragma unroll
    for (int i = 0; i < 4; ++i) {
        short4v hv = {(short)f2bf_rn(t[tc * 4 + 0][tr + i * 16]),
                      (short)f2bf_rn(t[tc * 4 + 1][tr + i * 16]),
                      (short)f2bf_rn(t[tc * 4 + 2][tr + i * 16]),
                      (short)f2bf_rn(t[tc * 4 + 3][tr + i * 16])};
        *(short4v*)&out[(size_t)(c0 + tr + i * 16) * 1024 + r0 + tc * 4] = hv;
    }
}

// ---------------------------------------------------------------------------
// Fused projection GEMM (r22-measured-good) — UNCHANGED.
// ---------------------------------------------------------------------------
__global__ __launch_bounds__(256) void gemm_proj_fused(
    const float* __restrict__ x,
    const float* __restrict__ Wcat_t,
    const float* __restrict__ bcat,
    float* __restrict__ Yqk,
    short* __restrict__ Kth, short* __restrict__ Ktl,
    short* __restrict__ Vbf)
{
    __shared__ __align__(16) short Ah[128 * 40], Al[128 * 40];
    __shared__ __align__(16) short Bh[128 * 40], Bl[128 * 40];

    const int tid = threadIdx.x;
    const int bx = blockIdx.x;
    const int m0 = blockIdx.y * 128, n0 = bx * 128;
    const bool vhalf = (bx >= 8);
    const int wid = tid >> 6, wr = wid >> 1, wc = wid & 1;
    const int lane = tid & 63, fr = lane & 15, fq = lane >> 4;
    const int srow = tid >> 1;
    const int skq  = (tid & 1) << 4;

    f32x4 acc[4][4];
    #pragma unroll
    for (int i = 0; i < 4; ++i)
        #pragma unroll
        for (int j = 0; j < 4; ++j)
            acc[i][j] = (f32x4){0.f, 0.f, 0.f, 0.f};

    const float* Ag = x + (size_t)(m0 + srow) * 1024 + skq;
    const float* Bg = Wcat_t + (size_t)(n0 + srow) * 1024 + skq;
    short* pAh = &Ah[srow * 40 + skq];
    short* pAl = &Al[srow * 40 + skq];
    short* pBh = &Bh[srow * 40 + skq];
    short* pBl = &Bl[srow * 40 + skq];

    for (int k0 = 0; k0 < 1024; k0 += 32) {
        float4 a0 = *(const float4*)(Ag + k0);
        float4 a1 = *(const float4*)(Ag + k0 + 4);
        float4 a2 = *(const float4*)(Ag + k0 + 8);
        float4 a3 = *(const float4*)(Ag + k0 + 12);
        float4 b0 = *(const float4*)(Bg + k0);
        float4 b1 = *(const float4*)(Bg + k0 + 4);
        float4 b2 = *(const float4*)(Bg + k0 + 8);
        float4 b3 = *(const float4*)(Bg + k0 + 12);
        if (vhalf) {
            short8v h;
            trunc8(a0, a1, h); *(short8v*)pAh = h;
            trunc8(a2, a3, h); *(short8v*)(pAh + 8) = h;
            trunc8(b0, b1, h); *(short8v*)pBh = h;
            trunc8(b2, b3, h); *(short8v*)(pBh + 8) = h;
        } else {
            short8v h, l;
            split8(a0, a1, h, l);
            *(short8v*)pAh = h;  *(short8v*)pAl = l;
            split8(a2, a3, h, l);
            *(short8v*)(pAh + 8) = h;  *(short8v*)(pAl + 8) = l;
            split8(b0, b1, h, l);
            *(short8v*)pBh = h;  *(short8v*)pBl = l;
            split8(b2, b3, h, l);
            *(short8v*)(pBh + 8) = h;  *(short8v*)(pBl + 8) = l;
        }
        __syncthreads();

        short8v afh[4], bfh[4];
        #pragma unroll
        for (int fi = 0; fi < 4; ++fi)
            afh[fi] = *(const short8v*)&Ah[(wr * 64 + fi * 16 + fr) * 40 + fq * 8];
        #pragma unroll
        for (int bj = 0; bj < 4; ++bj)
            bfh[bj] = *(const short8v*)&Bh[(wc * 64 + bj * 16 + fr) * 40 + fq * 8];

        if (vhalf) {
            #pragma unroll
            for (int fi = 0; fi < 4; ++fi)
                #pragma unroll
                for (int bj = 0; bj < 4; ++bj)
                    acc[fi][bj] = __builtin_amdgcn_mfma_f32_16x16x32_bf16(
                        afh[fi], bfh[bj], acc[fi][bj], 0, 0, 0);
        } else {
            short8v afl[4], bfl[4];
            #pragma unroll
            for (int fi = 0; fi < 4; ++fi)
                afl[fi] = *(const short8v*)&Al[(wr * 64 + fi * 16 + fr) * 40 + fq * 8];
            #pragma unroll
            for (int bj = 0; bj < 4; ++bj)
                bfl[bj] = *(const short8v*)&Bl[(wc * 64 + bj * 16 + fr) * 40 + fq * 8];
            #pragma unroll
            for (int fi = 0; fi < 4; ++fi) {
                #pragma unroll
                for (int bj = 0; bj < 4; ++bj) {
                    acc[fi][bj] = __builtin_amdgcn_mfma_f32_16x16x32_bf16(
                        afh[fi], bfh[bj], acc[fi][bj], 0, 0, 0);
                    acc[fi][bj] = __builtin_amdgcn_mfma_f32_16x16x32_bf16(
                        afh[fi], bfl[bj], acc[fi][bj], 0, 0, 0);
                    acc[fi][bj] = __builtin_amdgcn_mfma_f32_16x16x32_bf16(
                        afl[fi], bfh[bj], acc[fi][bj], 0, 0, 0);
                }
            }
        }
        __syncthreads();
    }

    const int b = m0 >> 11;
    #pragma unroll
    for (int fi = 0; fi < 4; ++fi) {
        #pragma unroll
        for (int bj = 0; bj < 4; ++bj) {
            const int r = m0 + wr * 64 + fi * 16 + fq * 4;
            const int gcol = n0 + wc * 64 + bj * 16 + fr;
            const float bv_ = bcat[gcol];
            if (bx < 4) {
                #pragma unroll
                for (int j = 0; j < 4; ++j)
                    Yqk[(size_t)(r + j) * 1024 + gcol] = acc[fi][bj][j] + bv_;
            } else if (bx < 8) {
                const int kc = gcol - 512;
                const int h = kc >> 5, rr = kc & 31;
                short* oh = Kth + (((size_t)(b * 16 + h) * 2048) + (r & 2047)) * 32 + rr;
                short* ol = Ktl + (((size_t)(b * 16 + h) * 2048) + (r & 2047)) * 32 + rr;
                #pragma unroll
                for (int j = 0; j < 4; ++j) {
                    const float v = acc[fi][bj][j] + bv_;
                    const ushort vh = bfhi(v);
                    oh[j * 32] = (short)vh;
                    ol[j * 32] = (short)bfhi(v - bff(vh));
                }
            } else {
                const int vc = gcol - 1024;
                const int h = vc >> 6, d = vc & 63;
                short4v o = {(short)f2bf_rn(acc[fi][bj][0] + bv_),
                             (short)f2bf_rn(acc[fi][bj][1] + bv_),
                             (short)f2bf_rn(acc[fi][bj][2] + bv_),
                             (short)f2bf_rn(acc[fi][bj][3] + bv_)};
                *(short4v*)&Vbf[((size_t)(b * 16 + h) * 64 + d) * 2048 + (r & 2047)] = o;
            }
        }
    }
}

// ---------------------------------------------------------------------------
// Out-proj GEMM, 1-term bf16 (r19-validated) — UNCHANGED.
// ---------------------------------------------------------------------------
__global__ __launch_bounds__(256) void gemm_out_bf(
    const ushort* __restrict__ Obf,
    const ushort* __restrict__ Wot,
    const float* __restrict__ bo,
    float* __restrict__ out)
{
    __shared__ __align__(16) short Ah[128 * 40];
    __shared__ __align__(16) short Bh[128 * 40];

    const int tid = threadIdx.x;
    const int m0 = blockIdx.y * 128, n0 = blockIdx.x * 128;
    const int wid = tid >> 6, wr = wid >> 1, wc = wid & 1;
    const int lane = tid & 63, fr = lane & 15, fq = lane >> 4;
    const int srow = tid >> 1;
    const int skq  = (tid & 1) << 4;

    f32x4 acc[4][4];
    #pragma unroll
    for (int i = 0; i < 4; ++i)
        #pragma unroll
        for (int j = 0; j < 4; ++j)
            acc[i][j] = (f32x4){0.f, 0.f, 0.f, 0.f};

    const ushort* AgH = Obf + (size_t)(m0 + srow) * 1024 + skq;
    const ushort* BgH = Wot + (size_t)(n0 + srow) * 1024 + skq;
    short* pAh = &Ah[srow * 40 + skq];
    short* pBh = &Bh[srow * 40 + skq];

    for (int k0 = 0; k0 < 1024; k0 += 32) {
        *(short8v*)pAh       = *(const short8v*)(AgH + k0);
        *(short8v*)(pAh + 8) = *(const short8v*)(AgH + k0 + 8);
        *(short8v*)pBh       = *(const short8v*)(BgH + k0);
        *(short8v*)(pBh + 8) = *(const short8v*)(BgH + k0 + 8);
        __syncthreads();

        short8v afh[4], bfh[4];
        #pragma unroll
        for (int fi = 0; fi < 4; ++fi)
            afh[fi] = *(const short8v*)&Ah[(wr * 64 + fi * 16 + fr) * 40 + fq * 8];
        #pragma unroll
        for (int bj = 0; bj < 4; ++bj)
            bfh[bj] = *(const short8v*)&Bh[(wc * 64 + bj * 16 + fr) * 40 + fq * 8];
        #pragma unroll
        for (int fi = 0; fi < 4; ++fi)
            #pragma unroll
            for (int bj = 0; bj < 4; ++bj)
                acc[fi][bj] = __builtin_amdgcn_mfma_f32_16x16x32_bf16(
                    afh[fi], bfh[bj], acc[fi][bj], 0, 0, 0);
        __syncthreads();
    }

    #pragma unroll
    for (int fi = 0; fi < 4; ++fi) {
        #pragma unroll
        for (int bj = 0; bj < 4; ++bj) {
            const int r = m0 + wr * 64 + fi * 16 + fq * 4;
            const int c = n0 + wc * 64 + bj * 16 + fr;
            const float bv_ = bo[c];
            #pragma unroll
            for (int j = 0; j < 4; ++j)
                out[(size_t)(r + j) * 1024 + c] = acc[fi][bj][j] + bv_;
        }
    }
}

// ---------------------------------------------------------------------------
// MFMA flash attention v9 = v8 with relaxed register budget.
// r23 diagnosis: VGPR=60 is exactly the 8-waves/SIMD tier -- the allocator
// targets max occupancy and recycles registers, SERIALIZING the 16 in-flight
// loads (chain ~6000cy = 16 x ~400cy L2 latency; VALUBusy 28% matches).
// __launch_bounds__(512, 1) relaxes the occupancy target so all 16 fragment
// loads can be simultaneously live (~120-150 VGPR, 3-4 waves/SIMD tier):
// loads issue back-to-back, one wait per iteration. Loop body unchanged.
// ---------------------------------------------------------------------------
#define P_LD  68
#define MASKVAL (-1e30f)

__global__ __launch_bounds__(512, 1) void flash_mfma(
    const float* __restrict__ Yqk,
    const short* __restrict__ Kth, const short* __restrict__ Ktl,
    const short* __restrict__ Vbf,
    ushort* __restrict__ Obf)
{
    const float scale = 0.1767766952966369f;  // 1/sqrt(32)
    const int L = blockIdx.x;
    const int bh = L & 31;
    const int qt = 31 - (L >> 5);
    const int b = bh >> 4, h = bh & 15;
    const int tid = threadIdx.x;
    const int w = tid >> 6;
    const int g = w & 3;
    const int p = w >> 2;
    const int lane = tid & 63;
    const int fr = lane & 15, fq = lane >> 4;

    __shared__ __align__(16) short Pall[8][16 * P_LD];        // 17408 B
    __shared__ __align__(16) char exraw[4 * 64 * 80];         // 20480 B
    short* Pw = &Pall[w][0];

    short8v aqh, aql;
    {
        const float* qp = Yqk + (size_t)(b * SEQ + qt * 64 + g * 16 + fr) * 1024
                          + h * 32 + fq * 8;
        split8(*(const float4*)qp, *(const float4*)(qp + 4), aqh, aql);
    }

    f32x4 acc0 = {0,0,0,0}, acc1 = {0,0,0,0}, acc2 = {0,0,0,0}, acc3 = {0,0,0,0};
    float m_[4], l_[4];
    #pragma unroll
    for (int r = 0; r < 4; ++r) { m_[r] = MASKVAL; l_[r] = 0.f; }

    const short* kb_h = Kth + (size_t)bh * 2048 * 32;
    const short* kb_l = Ktl + (size_t)bh * 2048 * 32;
    const short* vb   = Vbf + (size_t)bh * 64 * 2048;
    const int kidx = fr * 32 + fq * 8;
    const int vrow = fr * 2048 + fq * 8;

    for (int jt = p; jt <= qt; jt += 2) {
        const short* kp_h = kb_h + (size_t)jt * 64 * 32;
        const short* kp_l = kb_l + (size_t)jt * 64 * 32;
        short8v kh0 = *(const short8v*)&kp_h[kidx];
        short8v kh1 = *(const short8v*)&kp_h[kidx + 512];
        short8v kh2 = *(const short8v*)&kp_h[kidx + 1024];
        short8v kh3 = *(const short8v*)&kp_h[kidx + 1536];
        short8v kl0 = *(const short8v*)&kp_l[kidx];
        short8v kl1 = *(const short8v*)&kp_l[kidx + 512];
        short8v kl2 = *(const short8v*)&kp_l[kidx + 1024];
        short8v kl3 = *(const short8v*)&kp_l[kidx + 1536];
        const short* vp = vb + vrow + jt * 64;
        short8v v00 = *(const short8v*)&vp[0];
        short8v v01 = *(const short8v*)&vp[32];
        short8v v10 = *(const short8v*)&vp[16 * 2048];
        short8v v11 = *(const short8v*)&vp[16 * 2048 + 32];
        short8v v20 = *(const short8v*)&vp[32 * 2048];
        short8v v21 = *(const short8v*)&vp[32 * 2048 + 32];
        short8v v30 = *(const short8v*)&vp[48 * 2048];
        short8v v31 = *(const short8v*)&vp[48 * 2048 + 32];

        f32x4 s0 = {0,0,0,0}, s1 = {0,0,0,0}, s2 = {0,0,0,0}, s3 = {0,0,0,0};
        s0 = __builtin_amdgcn_mfma_f32_16x16x32_bf16(aqh, kh0, s0, 0, 0, 0);
        s0 = __builtin_amdgcn_mfma_f32_16x16x32_bf16(aqh, kl0, s0, 0, 0, 0);
        s0 = __builtin_amdgcn_mfma_f32_16x16x32_bf16(aql, kh0, s0, 0, 0, 0);
        s1 = __builtin_amdgcn_mfma_f32_16x16x32_bf16(aqh, kh1, s1, 0, 0, 0);
        s1 = __builtin_amdgcn_mfma_f32_16x16x32_bf16(aqh, kl1, s1, 0, 0, 0);
        s1 = __builtin_amdgcn_mfma_f32_16x16x32_bf16(aql, kh1, s1, 0, 0, 0);
        s2 = __builtin_amdgcn_mfma_f32_16x16x32_bf16(aqh, kh2, s2, 0, 0, 0);
        s2 = __builtin_amdgcn_mfma_f32_16x16x32_bf16(aqh, kl2, s2, 0, 0, 0);
        s2 = __builtin_amdgcn_mfma_f32_16x16x32_bf16(aql, kh2, s2, 0, 0, 0);
        s3 = __builtin_amdgcn_mfma_f32_16x16x32_bf16(aqh, kh3, s3, 0, 0, 0);
        s3 = __builtin_amdgcn_mfma_f32_16x16x32_bf16(aqh, kl3, s3, 0, 0, 0);
        s3 = __builtin_amdgcn_mfma_f32_16x16x32_bf16(aql, kh3, s3, 0, 0, 0);

        s0 *= scale; s1 *= scale; s2 *= scale; s3 *= scale;

        if (jt == qt) {
            #pragma unroll
            for (int r = 0; r < 4; ++r) {
                const int q_l = g * 16 + fq * 4 + r;
                s0[r] = (fr      <= q_l) ? s0[r] : MASKVAL;
                s1[r] = (16 + fr <= q_l) ? s1[r] : MASKVAL;
                s2[r] = (32 + fr <= q_l) ? s2[r] : MASKVAL;
                s3[r] = (48 + fr <= q_l) ? s3[r] : MASKVAL;
            }
        }

        float al[4];
        #pragma unroll
        for (int r = 0; r < 4; ++r) {
            float mt = fmaxf(fmaxf(s0[r], s1[r]), fmaxf(s2[r], s3[r]));
            mt = fmaxf(mt, __shfl_xor(mt, 1));
            mt = fmaxf(mt, __shfl_xor(mt, 2));
            mt = fmaxf(mt, __shfl_xor(mt, 4));
            mt = fmaxf(mt, __shfl_xor(mt, 8));
            const float mnew = fmaxf(m_[r], mt);
            al[r] = __expf(m_[r] - mnew);
            m_[r] = mnew;
            s0[r] = __expf(s0[r] - mnew);
            s1[r] = __expf(s1[r] - mnew);
            s2[r] = __expf(s2[r] - mnew);
            s3[r] = __expf(s3[r] - mnew);
            float ps = s0[r] + s1[r] + s2[r] + s3[r];
            ps += __shfl_xor(ps, 1);
            ps += __shfl_xor(ps, 2);
            ps += __shfl_xor(ps, 4);
            ps += __shfl_xor(ps, 8);
            l_[r] = l_[r] * al[r] + ps;
        }

        #pragma unroll
        for (int r = 0; r < 4; ++r) {
            const int prow = fq * 4 + r;
            Pw[prow * P_LD +      fr] = (short)f2bf_rn(s0[r]);
            Pw[prow * P_LD + 16 + fr] = (short)f2bf_rn(s1[r]);
            Pw[prow * P_LD + 32 + fr] = (short)f2bf_rn(s2[r]);
            Pw[prow * P_LD + 48 + fr] = (short)f2bf_rn(s3[r]);
        }
        #pragma unroll
        for (int r = 0; r < 4; ++r) {
            acc0[r] *= al[r]; acc1[r] *= al[r];
            acc2[r] *= al[r]; acc3[r] *= al[r];
        }
        short8v pa0 = *(const short8v*)&Pw[fr * P_LD + fq * 8];
        short8v pa1 = *(const short8v*)&Pw[fr * P_LD + 32 + fq * 8];

        acc0 = __builtin_amdgcn_mfma_f32_16x16x32_bf16(pa0, v00, acc0, 0, 0, 0);
        acc0 = __builtin_amdgcn_mfma_f32_16x16x32_bf16(pa1, v01, acc0, 0, 0, 0);
        acc1 = __builtin_amdgcn_mfma_f32_16x16x32_bf16(pa0, v10, acc1, 0, 0, 0);
        acc1 = __builtin_amdgcn_mfma_f32_16x16x32_bf16(pa1, v11, acc1, 0, 0, 0);
        acc2 = __builtin_amdgcn_mfma_f32_16x16x32_bf16(pa0, v20, acc2, 0, 0, 0);
        acc2 = __builtin_amdgcn_mfma_f32_16x16x32_bf16(pa1, v21, acc2, 0, 0, 0);
        acc3 = __builtin_amdgcn_mfma_f32_16x16x32_bf16(pa0, v30, acc3, 0, 0, 0);
        acc3 = __builtin_amdgcn_mfma_f32_16x16x32_bf16(pa1, v31, acc3, 0, 0, 0);
    }

    // ---- parity merge: p=1 publishes (accs as bf16), p=0 combines ----
    char* e = exraw + (size_t)(((g << 6) + lane) * 80);
    if (p == 1) {
        short8v a01, a23;
        a01[0] = (short)f2bf_rn(acc0[0]); a01[1] = (short)f2bf_rn(acc0[1]);
        a01[2] = (short)f2bf_rn(acc0[2]); a01[3] = (short)f2bf_rn(acc0[3]);
        a01[4] = (short)f2bf_rn(acc1[0]); a01[5] = (short)f2bf_rn(acc1[1]);
        a01[6] = (short)f2bf_rn(acc1[2]); a01[7] = (short)f2bf_rn(acc1[3]);
        a23[0] = (short)f2bf_rn(acc2[0]); a23[1] = (short)f2bf_rn(acc2[1]);
        a23[2] = (short)f2bf_rn(acc2[2]); a23[3] = (short)f2bf_rn(acc2[3]);
        a23[4] = (short)f2bf_rn(acc3[0]); a23[5] = (short)f2bf_rn(acc3[1]);
        a23[6] = (short)f2bf_rn(acc3[2]); a23[7] = (short)f2bf_rn(acc3[3]);
        *(short8v*)(e)      = a01;
        *(short8v*)(e + 16) = a23;
        *(f32x4*)(e + 32) = (f32x4){m_[0], m_[1], m_[2], m_[3]};
        *(f32x4*)(e + 48) = (f32x4){l_[0], l_[1], l_[2], l_[3]};
    }
    __syncthreads();
    if (p == 0) {
        short8v a01 = *(const short8v*)(e);
        short8v a23 = *(const short8v*)(e + 16);
        f32x4 m1 = *(const f32x4*)(e + 32);
        f32x4 l1 = *(const f32x4*)(e + 48);
        #pragma unroll
        for (int r = 0; r < 4; ++r) {
            const float mm = fmaxf(m_[r], m1[r]);
            const float a0 = __expf(m_[r] - mm);
            const float a1 = __expf(m1[r] - mm);
            const float inv = 1.f / (l_[r] * a0 + l1[r] * a1);
            const float b0 = bff((ushort)a01[r]);
            const float b1 = bff((ushort)a01[4 + r]);
            const float b2 = bff((ushort)a23[r]);
            const float b3 = bff((ushort)a23[4 + r]);
            const int trow = qt * 64 + g * 16 + fq * 4 + r;
            ushort* op = Obf + (size_t)(b * SEQ + trow) * 1024 + h * 64;
            op[     fr] = f2bf_rn((acc0[r] * a0 + b0 * a1) * inv);
            op[16 + fr] = f2bf_rn((acc1[r] * a0 + b1 * a1) * inv);
            op[32 + fr] = f2bf_rn((acc2[r] * a0 + b2 * a1) * inv);
            op[48 + fr] = f2bf_rn((acc3[r] * a0 + b3 * a1) * inv);
        }
    }
}

// ---------------------------------------------------------------------------
extern "C" void kernel_launch(void* const* d_in, const int* in_sizes, int n_in,
                              void* d_out, int out_size, void* d_ws, size_t ws_size,
                              hipStream_t stream)
{
    const float* x      = (const float*)d_in[0];
    const float* Wq     = (const float*)d_in[1];
    const float* bq     = (const float*)d_in[2];
    const float* Wk     = (const float*)d_in[3];
    const float* bk     = (const float*)d_in[4];
    const float* Wv     = (const float*)d_in[5];
    const float* bv     = (const float*)d_in[6];
    const float* Wo     = (const float*)d_in[7];
    const float* bo     = (const float*)d_in[8];
    const float* Wq_lsr = (const float*)d_in[9];
    const float* Wk_lsr = (const float*)d_in[10];
    float* out = (float*)d_out;

    float* ws     = (float*)d_ws;
    float* Wcat_t = ws;
    float* bcat   = Wcat_t + (size_t)2048 * 1024;
    float* Yqk    = bcat + 2048;
    float* Weff_tmp = Yqk;
    short* Kth    = (short*)(Yqk + (size_t)M_TOT * 1024);
    short* Ktl    = Kth + (size_t)32 * 2048 * 32;
    short* Vbf    = Ktl + (size_t)32 * 2048 * 32;
    ushort* Obf   = (ushort*)(Vbf + (size_t)32 * 64 * 2048);
    ushort* Wot   = (ushort*)Wcat_t;

    eff_weight2<<<dim3(2048, 2), 256, 0, stream>>>(Wq, Wq_lsr, Wk, Wk_lsr, Weff_tmp);
    eff_bias_kernel<<<8, 256, 0, stream>>>(bq, Wq_lsr, bk, Wk_lsr, bv, bcat);

    transpose2<<<dim3(16, 16, 2), 256, 0, stream>>>(
        Weff_tmp, Wcat_t, Wv, Wcat_t + (size_t)1024 * 1024);

    gemm_proj_fused<<<dim3(16, 32), 256, 0, stream>>>(
        x, Wcat_t, bcat, Yqk, Kth, Ktl, Vbf);

    tsplit_rn1024<<<dim3(16, 16), 256, 0, stream>>>(Wo, Wot);

    flash_mfma<<<1024, 512, 0, stream>>>(Yqk, Kth, Ktl, Vbf, Obf);

    gemm_out_bf<<<dim3(8, 32), 256, 0, stream>>>(Obf, Wot, bo, out);
}

// Round 25
// 186.836 us; speedup vs baseline: 1.4635x; 1.1541x over previous
//
#include <hip/hip_runtime.h>
#include <math.h>

#define D_MODEL 1024
#define N_HEADS 16
#define D_HEAD  64
#define LSR_RANK 32
#define BATCH 2
#define SEQ 2048
#define M_TOT (BATCH*SEQ)

typedef __attribute__((ext_vector_type(8))) short short8v;
typedef __attribute__((ext_vector_type(4))) short short4v;
typedef __attribute__((ext_vector_type(4))) float f32x4;

static __device__ __forceinline__ ushort bfhi(float f) {
    union { float f; unsigned u; } c; c.f = f;
    return (ushort)(c.u >> 16);
}
static __device__ __forceinline__ float bff(ushort h) {
    union { unsigned u; float f; } c; c.u = ((unsigned)h) << 16;
    return c.f;
}
static __device__ __forceinline__ ushort f2bf_rn(float f) {
    union { float f; unsigned u; } c; c.f = f;
    unsigned r = c.u + 0x7FFF + ((c.u >> 16) & 1);
    return (ushort)(r >> 16);
}
static __device__ __forceinline__ void split8(const float4 a, const float4 b,
                                              short8v& h, short8v& l) {
    ushort h0 = bfhi(a.x), h1 = bfhi(a.y), h2 = bfhi(a.z), h3 = bfhi(a.w);
    ushort h4 = bfhi(b.x), h5 = bfhi(b.y), h6 = bfhi(b.z), h7 = bfhi(b.w);
    h[0] = (short)h0; h[1] = (short)h1; h[2] = (short)h2; h[3] = (short)h3;
    h[4] = (short)h4; h[5] = (short)h5; h[6] = (short)h6; h[7] = (short)h7;
    l[0] = (short)bfhi(a.x - bff(h0)); l[1] = (short)bfhi(a.y - bff(h1));
    l[2] = (short)bfhi(a.z - bff(h2)); l[3] = (short)bfhi(a.w - bff(h3));
    l[4] = (short)bfhi(b.x - bff(h4)); l[5] = (short)bfhi(b.y - bff(h5));
    l[6] = (short)bfhi(b.z - bff(h6)); l[7] = (short)bfhi(b.w - bff(h7));
}
static __device__ __forceinline__ void trunc8(const float4 a, const float4 b,
                                              short8v& h) {
    h[0] = (short)bfhi(a.x); h[1] = (short)bfhi(a.y);
    h[2] = (short)bfhi(a.z); h[3] = (short)bfhi(a.w);
    h[4] = (short)bfhi(b.x); h[5] = (short)bfhi(b.y);
    h[6] = (short)bfhi(b.z); h[7] = (short)bfhi(b.w);
}

// ---------------------------------------------------------------------------
// Weff_tmp[k][z*512+c] = sum_d W[k, h*64+d] * Wlsr[h, d, r]  (z=0:Wq, 1:Wk)
// ---------------------------------------------------------------------------
__global__ __launch_bounds__(256) void eff_weight2(
    const float* __restrict__ Wq, const float* __restrict__ Wq_lsr,
    const float* __restrict__ Wk, const float* __restrict__ Wk_lsr,
    float* __restrict__ Weff_tmp)
{
    const int z = blockIdx.y;
    const float* W    = z ? Wk : Wq;
    const float* Wlsr = z ? Wk_lsr : Wq_lsr;
    const int base = z << 9;
    int idx = blockIdx.x * 256 + threadIdx.x;
    int k = idx >> 9;
    int c = idx & 511;
    int h = c >> 5;
    int r = c & 31;
    const float* wrow = W + (size_t)k * D_MODEL + h * D_HEAD;
    const float* lsr  = Wlsr + (size_t)h * D_HEAD * LSR_RANK + r;
    float acc = 0.f;
    #pragma unroll
    for (int d = 0; d < D_HEAD; ++d)
        acc = fmaf(wrow[d], lsr[d * LSR_RANK], acc);
    Weff_tmp[(size_t)k * 1024 + base + c] = acc;
}

__global__ __launch_bounds__(256) void eff_bias_kernel(
    const float* __restrict__ bq, const float* __restrict__ Wq_lsr,
    const float* __restrict__ bk, const float* __restrict__ Wk_lsr,
    const float* __restrict__ bv, float* __restrict__ bcat)
{
    int c = blockIdx.x * 256 + threadIdx.x;
    if (c < 1024) {
        const float* bias = (c < 512) ? bq : bk;
        const float* lsr  = (c < 512) ? Wq_lsr : Wk_lsr;
        int cc = c & 511;
        int h = cc >> 5, r = cc & 31;
        float acc = 0.f;
        #pragma unroll
        for (int d = 0; d < D_HEAD; ++d)
            acc = fmaf(bias[h * D_HEAD + d],
                       lsr[(size_t)h * D_HEAD * LSR_RANK + d * LSR_RANK + r], acc);
        bcat[c] = acc;
    } else {
        bcat[c] = bv[c - 1024];
    }
}

// ---------------------------------------------------------------------------
// Dual 1024x1024 fp32 transpose: z=0: in0->out0, z=1: in1->out1.
// ---------------------------------------------------------------------------
__global__ __launch_bounds__(256) void transpose2(
    const float* __restrict__ in0, float* __restrict__ out0,
    const float* __restrict__ in1, float* __restrict__ out1)
{
    const float* in  = blockIdx.z ? in1 : in0;
    float* out       = blockIdx.z ? out1 : out0;
    __shared__ float t[64][65];
    const int tid = threadIdx.x;
    const int r0 = blockIdx.y * 64, c0 = blockIdx.x * 64;
    const int tr = tid >> 4, tc = tid & 15;
    #pragma unroll
    for (int i = 0; i < 4; ++i) {
        float4 v = *(const float4*)&in[(size_t)(r0 + tr + i * 16) * 1024 + c0 + tc * 4];
        t[tr + i * 16][tc * 4 + 0] = v.x;
        t[tr + i * 16][tc * 4 + 1] = v.y;
        t[tr + i * 16][tc * 4 + 2] = v.z;
        t[tr + i * 16][tc * 4 + 3] = v.w;
    }
    __syncthreads();
    #pragma unroll
    for (int i = 0; i < 4; ++i) {
        float4 v;
        v.x = t[tc * 4 + 0][tr + i * 16];
        v.y = t[tc * 4 + 1][tr + i * 16];
        v.z = t[tc * 4 + 2][tr + i * 16];
        v.w = t[tc * 4 + 3][tr + i * 16];
        *(float4*)&out[(size_t)(c0 + tr + i * 16) * 1024 + r0 + tc * 4] = v;
    }
}

// ---------------------------------------------------------------------------
// Transpose + bf16-rn: Wo[1024][1024] fp32 -> Wot transposed bf16.
// ---------------------------------------------------------------------------
__global__ __launch_bounds__(256) void tsplit_rn1024(
    const float* __restrict__ in, ushort* __restrict__ out)
{
    __shared__ float t[64][65];
    const int tid = threadIdx.x;
    const int r0 = blockIdx.y * 64, c0 = blockIdx.x * 64;
    const int tr = tid >> 4, tc = tid & 15;
    #pragma unroll
    for (int i = 0; i < 4; ++i) {
        float4 v = *(const float4*)&in[(size_t)(r0 + tr + i * 16) * 1024 + c0 + tc * 4];
        t[tr + i * 16][tc * 4 + 0] = v.x;
        t[tr + i * 16][tc * 4 + 1] = v.y;
        t[tr + i * 16][tc * 4 + 2] = v.z;
        t[tr + i * 16][tc * 4 + 3] = v.w;
    }
    __syncthreads();
    #pragma unroll
    for (int i = 0; i < 4; ++i) {
        short4v hv = {(short)f2bf_rn(t[tc * 4 + 0][tr + i * 16]),
                      (short)f2bf_rn(t[tc * 4 + 1][tr + i * 16]),
                      (short)f2bf_rn(t[tc * 4 + 2][tr + i * 16]),
                      (short)f2bf_rn(t[tc * 4 + 3][tr + i * 16])};
        *(short4v*)&out[(size_t)(c0 + tr + i * 16) * 1024 + r0 + tc * 4] = hv;
    }
}

// ---------------------------------------------------------------------------
// Fused projection GEMM (r22-measured-good) — UNCHANGED.
// ---------------------------------------------------------------------------
__global__ __launch_bounds__(256) void gemm_proj_fused(
    const float* __restrict__ x,
    const float* __restrict__ Wcat_t,
    const float* __restrict__ bcat,
    float* __restrict__ Yqk,
    short* __restrict__ Kth, short* __restrict__ Ktl,
    short* __restrict__ Vbf)
{
    __shared__ __align__(16) short Ah[128 * 40], Al[128 * 40];
    __shared__ __align__(16) short Bh[128 * 40], Bl[128 * 40];

    const int tid = threadIdx.x;
    const int bx = blockIdx.x;
    const int m0 = blockIdx.y * 128, n0 = bx * 128;
    const bool vhalf = (bx >= 8);
    const int wid = tid >> 6, wr = wid >> 1, wc = wid & 1;
    const int lane = tid & 63, fr = lane & 15, fq = lane >> 4;
    const int srow = tid >> 1;
    const int skq  = (tid & 1) << 4;

    f32x4 acc[4][4];
    #pragma unroll
    for (int i = 0; i < 4; ++i)
        #pragma unroll
        for (int j = 0; j < 4; ++j)
            acc[i][j] = (f32x4){0.f, 0.f, 0.f, 0.f};

    const float* Ag = x + (size_t)(m0 + srow) * 1024 + skq;
    const float* Bg = Wcat_t + (size_t)(n0 + srow) * 1024 + skq;
    short* pAh = &Ah[srow * 40 + skq];
    short* pAl = &Al[srow * 40 + skq];
    short* pBh = &Bh[srow * 40 + skq];
    short* pBl = &Bl[srow * 40 + skq];

    for (int k0 = 0; k0 < 1024; k0 += 32) {
        float4 a0 = *(const float4*)(Ag + k0);
        float4 a1 = *(const float4*)(Ag + k0 + 4);
        float4 a2 = *(const float4*)(Ag + k0 + 8);
        float4 a3 = *(const float4*)(Ag + k0 + 12);
        float4 b0 = *(const float4*)(Bg + k0);
        float4 b1 = *(const float4*)(Bg + k0 + 4);
        float4 b2 = *(const float4*)(Bg + k0 + 8);
        float4 b3 = *(const float4*)(Bg + k0 + 12);
        if (vhalf) {
            short8v h;
            trunc8(a0, a1, h); *(short8v*)pAh = h;
            trunc8(a2, a3, h); *(short8v*)(pAh + 8) = h;
            trunc8(b0, b1, h); *(short8v*)pBh = h;
            trunc8(b2, b3, h); *(short8v*)(pBh + 8) = h;
        } else {
            short8v h, l;
            split8(a0, a1, h, l);
            *(short8v*)pAh = h;  *(short8v*)pAl = l;
            split8(a2, a3, h, l);
            *(short8v*)(pAh + 8) = h;  *(short8v*)(pAl + 8) = l;
            split8(b0, b1, h, l);
            *(short8v*)pBh = h;  *(short8v*)pBl = l;
            split8(b2, b3, h, l);
            *(short8v*)(pBh + 8) = h;  *(short8v*)(pBl + 8) = l;
        }
        __syncthreads();

        short8v afh[4], bfh[4];
        #pragma unroll
        for (int fi = 0; fi < 4; ++fi)
            afh[fi] = *(const short8v*)&Ah[(wr * 64 + fi * 16 + fr) * 40 + fq * 8];
        #pragma unroll
        for (int bj = 0; bj < 4; ++bj)
            bfh[bj] = *(const short8v*)&Bh[(wc * 64 + bj * 16 + fr) * 40 + fq * 8];

        if (vhalf) {
            #pragma unroll
            for (int fi = 0; fi < 4; ++fi)
                #pragma unroll
                for (int bj = 0; bj < 4; ++bj)
                    acc[fi][bj] = __builtin_amdgcn_mfma_f32_16x16x32_bf16(
                        afh[fi], bfh[bj], acc[fi][bj], 0, 0, 0);
        } else {
            short8v afl[4], bfl[4];
            #pragma unroll
            for (int fi = 0; fi < 4; ++fi)
                afl[fi] = *(const short8v*)&Al[(wr * 64 + fi * 16 + fr) * 40 + fq * 8];
            #pragma unroll
            for (int bj = 0; bj < 4; ++bj)
                bfl[bj] = *(const short8v*)&Bl[(wc * 64 + bj * 16 + fr) * 40 + fq * 8];
            #pragma unroll
            for (int fi = 0; fi < 4; ++fi) {
                #pragma unroll
                for (int bj = 0; bj < 4; ++bj) {
                    acc[fi][bj] = __builtin_amdgcn_mfma_f32_16x16x32_bf16(
                        afh[fi], bfh[bj], acc[fi][bj], 0, 0, 0);
                    acc[fi][bj] = __builtin_amdgcn_mfma_f32_16x16x32_bf16(
                        afh[fi], bfl[bj], acc[fi][bj], 0, 0, 0);
                    acc[fi][bj] = __builtin_amdgcn_mfma_f32_16x16x32_bf16(
                        afl[fi], bfh[bj], acc[fi][bj], 0, 0, 0);
                }
            }
        }
        __syncthreads();
    }

    const int b = m0 >> 11;
    #pragma unroll
    for (int fi = 0; fi < 4; ++fi) {
        #pragma unroll
        for (int bj = 0; bj < 4; ++bj) {
            const int r = m0 + wr * 64 + fi * 16 + fq * 4;
            const int gcol = n0 + wc * 64 + bj * 16 + fr;
            const float bv_ = bcat[gcol];
            if (bx < 4) {
                #pragma unroll
                for (int j = 0; j < 4; ++j)
                    Yqk[(size_t)(r + j) * 1024 + gcol] = acc[fi][bj][j] + bv_;
            } else if (bx < 8) {
                const int kc = gcol - 512;
                const int h = kc >> 5, rr = kc & 31;
                short* oh = Kth + (((size_t)(b * 16 + h) * 2048) + (r & 2047)) * 32 + rr;
                short* ol = Ktl + (((size_t)(b * 16 + h) * 2048) + (r & 2047)) * 32 + rr;
                #pragma unroll
                for (int j = 0; j < 4; ++j) {
                    const float v = acc[fi][bj][j] + bv_;
                    const ushort vh = bfhi(v);
                    oh[j * 32] = (short)vh;
                    ol[j * 32] = (short)bfhi(v - bff(vh));
                }
            } else {
                const int vc = gcol - 1024;
                const int h = vc >> 6, d = vc & 63;
                short4v o = {(short)f2bf_rn(acc[fi][bj][0] + bv_),
                             (short)f2bf_rn(acc[fi][bj][1] + bv_),
                             (short)f2bf_rn(acc[fi][bj][2] + bv_),
                             (short)f2bf_rn(acc[fi][bj][3] + bv_)};
                *(short4v*)&Vbf[((size_t)(b * 16 + h) * 64 + d) * 2048 + (r & 2047)] = o;
            }
        }
    }
}

// ---------------------------------------------------------------------------
// Out-proj GEMM, 1-term bf16 (r19-validated) — UNCHANGED.
// ---------------------------------------------------------------------------
__global__ __launch_bounds__(256) void gemm_out_bf(
    const ushort* __restrict__ Obf,
    const ushort* __restrict__ Wot,
    const float* __restrict__ bo,
    float* __restrict__ out)
{
    __shared__ __align__(16) short Ah[128 * 40];
    __shared__ __align__(16) short Bh[128 * 40];

    const int tid = threadIdx.x;
    const int m0 = blockIdx.y * 128, n0 = blockIdx.x * 128;
    const int wid = tid >> 6, wr = wid >> 1, wc = wid & 1;
    const int lane = tid & 63, fr = lane & 15, fq = lane >> 4;
    const int srow = tid >> 1;
    const int skq  = (tid & 1) << 4;

    f32x4 acc[4][4];
    #pragma unroll
    for (int i = 0; i < 4; ++i)
        #pragma unroll
        for (int j = 0; j < 4; ++j)
            acc[i][j] = (f32x4){0.f, 0.f, 0.f, 0.f};

    const ushort* AgH = Obf + (size_t)(m0 + srow) * 1024 + skq;
    const ushort* BgH = Wot + (size_t)(n0 + srow) * 1024 + skq;
    short* pAh = &Ah[srow * 40 + skq];
    short* pBh = &Bh[srow * 40 + skq];

    for (int k0 = 0; k0 < 1024; k0 += 32) {
        *(short8v*)pAh       = *(const short8v*)(AgH + k0);
        *(short8v*)(pAh + 8) = *(const short8v*)(AgH + k0 + 8);
        *(short8v*)pBh       = *(const short8v*)(BgH + k0);
        *(short8v*)(pBh + 8) = *(const short8v*)(BgH + k0 + 8);
        __syncthreads();

        short8v afh[4], bfh[4];
        #pragma unroll
        for (int fi = 0; fi < 4; ++fi)
            afh[fi] = *(const short8v*)&Ah[(wr * 64 + fi * 16 + fr) * 40 + fq * 8];
        #pragma unroll
        for (int bj = 0; bj < 4; ++bj)
            bfh[bj] = *(const short8v*)&Bh[(wc * 64 + bj * 16 + fr) * 40 + fq * 8];
        #pragma unroll
        for (int fi = 0; fi < 4; ++fi)
            #pragma unroll
            for (int bj = 0; bj < 4; ++bj)
                acc[fi][bj] = __builtin_amdgcn_mfma_f32_16x16x32_bf16(
                    afh[fi], bfh[bj], acc[fi][bj], 0, 0, 0);
        __syncthreads();
    }

    #pragma unroll
    for (int fi = 0; fi < 4; ++fi) {
        #pragma unroll
        for (int bj = 0; bj < 4; ++bj) {
            const int r = m0 + wr * 64 + fi * 16 + fq * 4;
            const int c = n0 + wc * 64 + bj * 16 + fr;
            const float bv_ = bo[c];
            #pragma unroll
            for (int j = 0; j < 4; ++j)
                out[(size_t)(r + j) * 1024 + c] = acc[fi][bj][j] + bv_;
        }
    }
}

// ---------------------------------------------------------------------------
// MFMA flash attention v10: DUAL-Q amortization.
// r24 conclusion: 4 scheduling interventions all null (VGPR pinned at 60 by
// the compiler); only structural changes have ever moved this kernel. Fix
// the load:compute ratio structurally: each block covers TWO q-tiles
// (qtA=2qp, qtB=2qp+1); every iteration's 16 K/V fragment loads feed BOTH
// tiles (2x QK+softmax+PV per fetch). Wave-iterations halve (67.6K->34.6K).
// Tile A is skipped wave-uniformly when jt > qtA (avoids all-masked softmax
// corrupting l with exp(0)=1). Grid 512 (2 blocks/CU), LPT order.
// Epilogue: two merge rounds through the same 20KB ex buffer.
// ---------------------------------------------------------------------------
#define P_LD  68
#define MASKVAL (-1e30f)

__global__ __launch_bounds__(512) void flash_mfma(
    const float* __restrict__ Yqk,
    const short* __restrict__ Kth, const short* __restrict__ Ktl,
    const short* __restrict__ Vbf,
    ushort* __restrict__ Obf)
{
    const float scale = 0.1767766952966369f;  // 1/sqrt(32)
    const int L = blockIdx.x;
    const int bh = L & 31;
    const int qp = 15 - (L >> 5);              // LPT: big pairs first
    const int qtA = 2 * qp, qtB = 2 * qp + 1;
    const int b = bh >> 4, h = bh & 15;
    const int tid = threadIdx.x;
    const int w = tid >> 6;
    const int g = w & 3;
    const int p = w >> 2;
    const int lane = tid & 63;
    const int fr = lane & 15, fq = lane >> 4;

    __shared__ __align__(16) short Pall[8][16 * P_LD];        // 17408 B
    __shared__ __align__(16) char exraw[4 * 64 * 80];         // 20480 B
    short* Pw = &Pall[w][0];

    short8v aqhA, aqlA, aqhB, aqlB;
    {
        const float* qpA = Yqk + (size_t)(b * SEQ + qtA * 64 + g * 16 + fr) * 1024
                           + h * 32 + fq * 8;
        split8(*(const float4*)qpA, *(const float4*)(qpA + 4), aqhA, aqlA);
        const float* qpB = Yqk + (size_t)(b * SEQ + qtB * 64 + g * 16 + fr) * 1024
                           + h * 32 + fq * 8;
        split8(*(const float4*)qpB, *(const float4*)(qpB + 4), aqhB, aqlB);
    }

    f32x4 accA0 = {0,0,0,0}, accA1 = {0,0,0,0}, accA2 = {0,0,0,0}, accA3 = {0,0,0,0};
    f32x4 accB0 = {0,0,0,0}, accB1 = {0,0,0,0}, accB2 = {0,0,0,0}, accB3 = {0,0,0,0};
    float mA[4], lA[4], mB[4], lB[4];
    #pragma unroll
    for (int r = 0; r < 4; ++r) {
        mA[r] = MASKVAL; lA[r] = 0.f;
        mB[r] = MASKVAL; lB[r] = 0.f;
    }

    const short* kb_h = Kth + (size_t)bh * 2048 * 32;
    const short* kb_l = Ktl + (size_t)bh * 2048 * 32;
    const short* vb   = Vbf + (size_t)bh * 64 * 2048;
    const int kidx = fr * 32 + fq * 8;
    const int vrow = fr * 2048 + fq * 8;

    for (int jt = p; jt <= qtB; jt += 2) {
        // ---- shared load cluster (feeds BOTH tiles) ----
        const short* kp_h = kb_h + (size_t)jt * 64 * 32;
        const short* kp_l = kb_l + (size_t)jt * 64 * 32;
        short8v kh0 = *(const short8v*)&kp_h[kidx];
        short8v kh1 = *(const short8v*)&kp_h[kidx + 512];
        short8v kh2 = *(const short8v*)&kp_h[kidx + 1024];
        short8v kh3 = *(const short8v*)&kp_h[kidx + 1536];
        short8v kl0 = *(const short8v*)&kp_l[kidx];
        short8v kl1 = *(const short8v*)&kp_l[kidx + 512];
        short8v kl2 = *(const short8v*)&kp_l[kidx + 1024];
        short8v kl3 = *(const short8v*)&kp_l[kidx + 1536];
        const short* vp = vb + vrow + jt * 64;
        short8v v00 = *(const short8v*)&vp[0];
        short8v v01 = *(const short8v*)&vp[32];
        short8v v10 = *(const short8v*)&vp[16 * 2048];
        short8v v11 = *(const short8v*)&vp[16 * 2048 + 32];
        short8v v20 = *(const short8v*)&vp[32 * 2048];
        short8v v21 = *(const short8v*)&vp[32 * 2048 + 32];
        short8v v30 = *(const short8v*)&vp[48 * 2048];
        short8v v31 = *(const short8v*)&vp[48 * 2048 + 32];

        // ================= tile A (skip wave-uniformly if past causal) ====
        if (jt <= qtA) {
            f32x4 s0 = {0,0,0,0}, s1 = {0,0,0,0}, s2 = {0,0,0,0}, s3 = {0,0,0,0};
            s0 = __builtin_amdgcn_mfma_f32_16x16x32_bf16(aqhA, kh0, s0, 0, 0, 0);
            s0 = __builtin_amdgcn_mfma_f32_16x16x32_bf16(aqhA, kl0, s0, 0, 0, 0);
            s0 = __builtin_amdgcn_mfma_f32_16x16x32_bf16(aqlA, kh0, s0, 0, 0, 0);
            s1 = __builtin_amdgcn_mfma_f32_16x16x32_bf16(aqhA, kh1, s1, 0, 0, 0);
            s1 = __builtin_amdgcn_mfma_f32_16x16x32_bf16(aqhA, kl1, s1, 0, 0, 0);
            s1 = __builtin_amdgcn_mfma_f32_16x16x32_bf16(aqlA, kh1, s1, 0, 0, 0);
            s2 = __builtin_amdgcn_mfma_f32_16x16x32_bf16(aqhA, kh2, s2, 0, 0, 0);
            s2 = __builtin_amdgcn_mfma_f32_16x16x32_bf16(aqhA, kl2, s2, 0, 0, 0);
            s2 = __builtin_amdgcn_mfma_f32_16x16x32_bf16(aqlA, kh2, s2, 0, 0, 0);
            s3 = __builtin_amdgcn_mfma_f32_16x16x32_bf16(aqhA, kh3, s3, 0, 0, 0);
            s3 = __builtin_amdgcn_mfma_f32_16x16x32_bf16(aqhA, kl3, s3, 0, 0, 0);
            s3 = __builtin_amdgcn_mfma_f32_16x16x32_bf16(aqlA, kh3, s3, 0, 0, 0);

            s0 *= scale; s1 *= scale; s2 *= scale; s3 *= scale;

            if (jt == qtA) {
                #pragma unroll
                for (int r = 0; r < 4; ++r) {
                    const int q_l = g * 16 + fq * 4 + r;
                    s0[r] = (fr      <= q_l) ? s0[r] : MASKVAL;
                    s1[r] = (16 + fr <= q_l) ? s1[r] : MASKVAL;
                    s2[r] = (32 + fr <= q_l) ? s2[r] : MASKVAL;
                    s3[r] = (48 + fr <= q_l) ? s3[r] : MASKVAL;
                }
            }

            float al[4];
            #pragma unroll
            for (int r = 0; r < 4; ++r) {
                float mt = fmaxf(fmaxf(s0[r], s1[r]), fmaxf(s2[r], s3[r]));
                mt = fmaxf(mt, __shfl_xor(mt, 1));
                mt = fmaxf(mt, __shfl_xor(mt, 2));
                mt = fmaxf(mt, __shfl_xor(mt, 4));
                mt = fmaxf(mt, __shfl_xor(mt, 8));
                const float mnew = fmaxf(mA[r], mt);
                al[r] = __expf(mA[r] - mnew);
                mA[r] = mnew;
                s0[r] = __expf(s0[r] - mnew);
                s1[r] = __expf(s1[r] - mnew);
                s2[r] = __expf(s2[r] - mnew);
                s3[r] = __expf(s3[r] - mnew);
                float ps = s0[r] + s1[r] + s2[r] + s3[r];
                ps += __shfl_xor(ps, 1);
                ps += __shfl_xor(ps, 2);
                ps += __shfl_xor(ps, 4);
                ps += __shfl_xor(ps, 8);
                lA[r] = lA[r] * al[r] + ps;
            }

            #pragma unroll
            for (int r = 0; r < 4; ++r) {
                const int prow = fq * 4 + r;
                Pw[prow * P_LD +      fr] = (short)f2bf_rn(s0[r]);
                Pw[prow * P_LD + 16 + fr] = (short)f2bf_rn(s1[r]);
                Pw[prow * P_LD + 32 + fr] = (short)f2bf_rn(s2[r]);
                Pw[prow * P_LD + 48 + fr] = (short)f2bf_rn(s3[r]);
            }
            #pragma unroll
            for (int r = 0; r < 4; ++r) {
                accA0[r] *= al[r]; accA1[r] *= al[r];
                accA2[r] *= al[r]; accA3[r] *= al[r];
            }
            short8v pa0 = *(const short8v*)&Pw[fr * P_LD + fq * 8];
            short8v pa1 = *(const short8v*)&Pw[fr * P_LD + 32 + fq * 8];

            accA0 = __builtin_amdgcn_mfma_f32_16x16x32_bf16(pa0, v00, accA0, 0, 0, 0);
            accA0 = __builtin_amdgcn_mfma_f32_16x16x32_bf16(pa1, v01, accA0, 0, 0, 0);
            accA1 = __builtin_amdgcn_mfma_f32_16x16x32_bf16(pa0, v10, accA1, 0, 0, 0);
            accA1 = __builtin_amdgcn_mfma_f32_16x16x32_bf16(pa1, v11, accA1, 0, 0, 0);
            accA2 = __builtin_amdgcn_mfma_f32_16x16x32_bf16(pa0, v20, accA2, 0, 0, 0);
            accA2 = __builtin_amdgcn_mfma_f32_16x16x32_bf16(pa1, v21, accA2, 0, 0, 0);
            accA3 = __builtin_amdgcn_mfma_f32_16x16x32_bf16(pa0, v30, accA3, 0, 0, 0);
            accA3 = __builtin_amdgcn_mfma_f32_16x16x32_bf16(pa1, v31, accA3, 0, 0, 0);
        }

        // ================= tile B (always active: jt <= qtB by loop) ======
        {
            f32x4 s0 = {0,0,0,0}, s1 = {0,0,0,0}, s2 = {0,0,0,0}, s3 = {0,0,0,0};
            s0 = __builtin_amdgcn_mfma_f32_16x16x32_bf16(aqhB, kh0, s0, 0, 0, 0);
            s0 = __builtin_amdgcn_mfma_f32_16x16x32_bf16(aqhB, kl0, s0, 0, 0, 0);
            s0 = __builtin_amdgcn_mfma_f32_16x16x32_bf16(aqlB, kh0, s0, 0, 0, 0);
            s1 = __builtin_amdgcn_mfma_f32_16x16x32_bf16(aqhB, kh1, s1, 0, 0, 0);
            s1 = __builtin_amdgcn_mfma_f32_16x16x32_bf16(aqhB, kl1, s1, 0, 0, 0);
            s1 = __builtin_amdgcn_mfma_f32_16x16x32_bf16(aqlB, kh1, s1, 0, 0, 0);
            s2 = __builtin_amdgcn_mfma_f32_16x16x32_bf16(aqhB, kh2, s2, 0, 0, 0);
            s2 = __builtin_amdgcn_mfma_f32_16x16x32_bf16(aqhB, kl2, s2, 0, 0, 0);
            s2 = __builtin_amdgcn_mfma_f32_16x16x32_bf16(aqlB, kh2, s2, 0, 0, 0);
            s3 = __builtin_amdgcn_mfma_f32_16x16x32_bf16(aqhB, kh3, s3, 0, 0, 0);
            s3 = __builtin_amdgcn_mfma_f32_16x16x32_bf16(aqhB, kl3, s3, 0, 0, 0);
            s3 = __builtin_amdgcn_mfma_f32_16x16x32_bf16(aqlB, kh3, s3, 0, 0, 0);

            s0 *= scale; s1 *= scale; s2 *= scale; s3 *= scale;

            if (jt == qtB) {
                #pragma unroll
                for (int r = 0; r < 4; ++r) {
                    const int q_l = g * 16 + fq * 4 + r;
                    s0[r] = (fr      <= q_l) ? s0[r] : MASKVAL;
                    s1[r] = (16 + fr <= q_l) ? s1[r] : MASKVAL;
                    s2[r] = (32 + fr <= q_l) ? s2[r] : MASKVAL;
                    s3[r] = (48 + fr <= q_l) ? s3[r] : MASKVAL;
                }
            }

            float al[4];
            #pragma unroll
            for (int r = 0; r < 4; ++r) {
                float mt = fmaxf(fmaxf(s0[r], s1[r]), fmaxf(s2[r], s3[r]));
                mt = fmaxf(mt, __shfl_xor(mt, 1));
                mt = fmaxf(mt, __shfl_xor(mt, 2));
                mt = fmaxf(mt, __shfl_xor(mt, 4));
                mt = fmaxf(mt, __shfl_xor(mt, 8));
                const float mnew = fmaxf(mB[r], mt);
                al[r] = __expf(mB[r] - mnew);
                mB[r] = mnew;
                s0[r] = __expf(s0[r] - mnew);
                s1[r] = __expf(s1[r] - mnew);
                s2[r] = __expf(s2[r] - mnew);
                s3[r] = __expf(s3[r] - mnew);
                float ps = s0[r] + s1[r] + s2[r] + s3[r];
                ps += __shfl_xor(ps, 1);
                ps += __shfl_xor(ps, 2);
                ps += __shfl_xor(ps, 4);
                ps += __shfl_xor(ps, 8);
                lB[r] = lB[r] * al[r] + ps;
            }

            #pragma unroll
            for (int r = 0; r < 4; ++r) {
                const int prow = fq * 4 + r;
                Pw[prow * P_LD +      fr] = (short)f2bf_rn(s0[r]);
                Pw[prow * P_LD + 16 + fr] = (short)f2bf_rn(s1[r]);
                Pw[prow * P_LD + 32 + fr] = (short)f2bf_rn(s2[r]);
                Pw[prow * P_LD + 48 + fr] = (short)f2bf_rn(s3[r]);
            }
            #pragma unroll
            for (int r = 0; r < 4; ++r) {
                accB0[r] *= al[r]; accB1[r] *= al[r];
                accB2[r] *= al[r]; accB3[r] *= al[r];
            }
            short8v pa0 = *(const short8v*)&Pw[fr * P_LD + fq * 8];
            short8v pa1 = *(const short8v*)&Pw[fr * P_LD + 32 + fq * 8];

            accB0 = __builtin_amdgcn_mfma_f32_16x16x32_bf16(pa0, v00, accB0, 0, 0, 0);
            accB0 = __builtin_amdgcn_mfma_f32_16x16x32_bf16(pa1, v01, accB0, 0, 0, 0);
            accB1 = __builtin_amdgcn_mfma_f32_16x16x32_bf16(pa0, v10, accB1, 0, 0, 0);
            accB1 = __builtin_amdgcn_mfma_f32_16x16x32_bf16(pa1, v11, accB1, 0, 0, 0);
            accB2 = __builtin_amdgcn_mfma_f32_16x16x32_bf16(pa0, v20, accB2, 0, 0, 0);
            accB2 = __builtin_amdgcn_mfma_f32_16x16x32_bf16(pa1, v21, accB2, 0, 0, 0);
            accB3 = __builtin_amdgcn_mfma_f32_16x16x32_bf16(pa0, v30, accB3, 0, 0, 0);
            accB3 = __builtin_amdgcn_mfma_f32_16x16x32_bf16(pa1, v31, accB3, 0, 0, 0);
        }
    }

    // ---- epilogue: two merge rounds through the shared ex buffer ----
    char* e = exraw + (size_t)(((g << 6) + lane) * 80);

    // round 1: tile A
    if (p == 1) {
        short8v a01, a23;
        a01[0] = (short)f2bf_rn(accA0[0]); a01[1] = (short)f2bf_rn(accA0[1]);
        a01[2] = (short)f2bf_rn(accA0[2]); a01[3] = (short)f2bf_rn(accA0[3]);
        a01[4] = (short)f2bf_rn(accA1[0]); a01[5] = (short)f2bf_rn(accA1[1]);
        a01[6] = (short)f2bf_rn(accA1[2]); a01[7] = (short)f2bf_rn(accA1[3]);
        a23[0] = (short)f2bf_rn(accA2[0]); a23[1] = (short)f2bf_rn(accA2[1]);
        a23[2] = (short)f2bf_rn(accA2[2]); a23[3] = (short)f2bf_rn(accA2[3]);
        a23[4] = (short)f2bf_rn(accA3[0]); a23[5] = (short)f2bf_rn(accA3[1]);
        a23[6] = (short)f2bf_rn(accA3[2]); a23[7] = (short)f2bf_rn(accA3[3]);
        *(short8v*)(e)      = a01;
        *(short8v*)(e + 16) = a23;
        *(f32x4*)(e + 32) = (f32x4){mA[0], mA[1], mA[2], mA[3]};
        *(f32x4*)(e + 48) = (f32x4){lA[0], lA[1], lA[2], lA[3]};
    }
    __syncthreads();
    if (p == 0) {
        short8v a01 = *(const short8v*)(e);
        short8v a23 = *(const short8v*)(e + 16);
        f32x4 m1 = *(const f32x4*)(e + 32);
        f32x4 l1 = *(const f32x4*)(e + 48);
        #pragma unroll
        for (int r = 0; r < 4; ++r) {
            const float mm = fmaxf(mA[r], m1[r]);
            const float a0 = __expf(mA[r] - mm);
            const float a1 = __expf(m1[r] - mm);
            const float inv = 1.f / (lA[r] * a0 + l1[r] * a1);
            const float b0 = bff((ushort)a01[r]);
            const float b1 = bff((ushort)a01[4 + r]);
            const float b2 = bff((ushort)a23[r]);
            const float b3 = bff((ushort)a23[4 + r]);
            const int trow = qtA * 64 + g * 16 + fq * 4 + r;
            ushort* op = Obf + (size_t)(b * SEQ + trow) * 1024 + h * 64;
            op[     fr] = f2bf_rn((accA0[r] * a0 + b0 * a1) * inv);
            op[16 + fr] = f2bf_rn((accA1[r] * a0 + b1 * a1) * inv);
            op[32 + fr] = f2bf_rn((accA2[r] * a0 + b2 * a1) * inv);
            op[48 + fr] = f2bf_rn((accA3[r] * a0 + b3 * a1) * inv);
        }
    }
    __syncthreads();

    // round 2: tile B
    if (p == 1) {
        short8v a01, a23;
        a01[0] = (short)f2bf_rn(accB0[0]); a01[1] = (short)f2bf_rn(accB0[1]);
        a01[2] = (short)f2bf_rn(accB0[2]); a01[3] = (short)f2bf_rn(accB0[3]);
        a01[4] = (short)f2bf_rn(accB1[0]); a01[5] = (short)f2bf_rn(accB1[1]);
        a01[6] = (short)f2bf_rn(accB1[2]); a01[7] = (short)f2bf_rn(accB1[3]);
        a23[0] = (short)f2bf_rn(accB2[0]); a23[1] = (short)f2bf_rn(accB2[1]);
        a23[2] = (short)f2bf_rn(accB2[2]); a23[3] = (short)f2bf_rn(accB2[3]);
        a23[4] = (short)f2bf_rn(accB3[0]); a23[5] = (short)f2bf_rn(accB3[1]);
        a23[6] = (short)f2bf_rn(accB3[2]); a23[7] = (short)f2bf_rn(accB3[3]);
        *(short8v*)(e)      = a01;
        *(short8v*)(e + 16) = a23;
        *(f32x4*)(e + 32) = (f32x4){mB[0], mB[1], mB[2], mB[3]};
        *(f32x4*)(e + 48) = (f32x4){lB[0], lB[1], lB[2], lB[3]};
    }
    __syncthreads();
    if (p == 0) {
        short8v a01 = *(const short8v*)(e);
        short8v a23 = *(const short8v*)(e + 16);
        f32x4 m1 = *(const f32x4*)(e + 32);
        f32x4 l1 = *(const f32x4*)(e + 48);
        #pragma unroll
        for (int r = 0; r < 4; ++r) {
            const float mm = fmaxf(mB[r], m1[r]);
            const float a0 = __expf(mB[r] - mm);
            const float a1 = __expf(m1[r] - mm);
            const float inv = 1.f / (lB[r] * a0 + l1[r] * a1);
            const float b0 = bff((ushort)a01[r]);
            const float b1 = bff((ushort)a01[4 + r]);
            const float b2 = bff((ushort)a23[r]);
            const float b3 = bff((ushort)a23[4 + r]);
            const int trow = qtB * 64 + g * 16 + fq * 4 + r;
            ushort* op = Obf + (size_t)(b * SEQ + trow) * 1024 + h * 64;
            op[     fr] = f2bf_rn((accB0[r] * a0 + b0 * a1) * inv);
            op[16 + fr] = f2bf_rn((accB1[r] * a0 + b1 * a1) * inv);
            op[32 + fr] = f2bf_rn((accB2[r] * a0 + b2 * a1) * inv);
            op[48 + fr] = f2bf_rn((accB3[r] * a0 + b3 * a1) * inv);
        }
    }
}

// ---------------------------------------------------------------------------
extern "C" void kernel_launch(void* const* d_in, const int* in_sizes, int n_in,
                              void* d_out, int out_size, void* d_ws, size_t ws_size,
                              hipStream_t stream)
{
    const float* x      = (const float*)d_in[0];
    const float* Wq     = (const float*)d_in[1];
    const float* bq     = (const float*)d_in[2];
    const float* Wk     = (const float*)d_in[3];
    const float* bk     = (const float*)d_in[4];
    const float* Wv     = (const float*)d_in[5];
    const float* bv     = (const float*)d_in[6];
    const float* Wo     = (const float*)d_in[7];
    const float* bo     = (const float*)d_in[8];
    const float* Wq_lsr = (const float*)d_in[9];
    const float* Wk_lsr = (const float*)d_in[10];
    float* out = (float*)d_out;

    float* ws     = (float*)d_ws;
    float* Wcat_t = ws;
    float* bcat   = Wcat_t + (size_t)2048 * 1024;
    float* Yqk    = bcat + 2048;
    float* Weff_tmp = Yqk;
    short* Kth    = (short*)(Yqk + (size_t)M_TOT * 1024);
    short* Ktl    = Kth + (size_t)32 * 2048 * 32;
    short* Vbf    = Ktl + (size_t)32 * 2048 * 32;
    ushort* Obf   = (ushort*)(Vbf + (size_t)32 * 64 * 2048);
    ushort* Wot   = (ushort*)Wcat_t;

    eff_weight2<<<dim3(2048, 2), 256, 0, stream>>>(Wq, Wq_lsr, Wk, Wk_lsr, Weff_tmp);
    eff_bias_kernel<<<8, 256, 0, stream>>>(bq, Wq_lsr, bk, Wk_lsr, bv, bcat);

    transpose2<<<dim3(16, 16, 2), 256, 0, stream>>>(
        Weff_tmp, Wcat_t, Wv, Wcat_t + (size_t)1024 * 1024);

    gemm_proj_fused<<<dim3(16, 32), 256, 0, stream>>>(
        x, Wcat_t, bcat, Yqk, Kth, Ktl, Vbf);

    tsplit_rn1024<<<dim3(16, 16), 256, 0, stream>>>(Wo, Wot);

    flash_mfma<<<512, 512, 0, stream>>>(Yqk, Kth, Ktl, Vbf, Obf);

    gemm_out_bf<<<dim3(8, 32), 256, 0, stream>>>(Obf, Wot, bo, out);
}